// Round 5
// baseline (348.669 us; speedup 1.0000x reference)
//
#include <hip/hip_runtime.h>
#include <hip/hip_fp16.h>
#include <float.h>
#include <math.h>

#define BB 8
#define LL 2048
#define NN 2048
#define DD 512
#define HH 8
#define DEPTH 64
#define TOPK 15
#define PIF 3.14159265358979323846f

// padded index for zr/zi: +1 float per 32 -> breaks power-of-2 bank aliasing
#define PD(i) ((i) + ((i) >> 5))

using f16x8 = __attribute__((ext_vector_type(8))) _Float16;
typedef __attribute__((ext_vector_type(4))) float f32x4;
typedef __attribute__((ext_vector_type(8))) unsigned short us8;
typedef __attribute__((ext_vector_type(4))) unsigned short us4;

__device__ __forceinline__ unsigned short f2h(float f) {
    return __half_as_ushort(__float2half(f));  // RNE
}
__device__ __forceinline__ float2 cmul(float2 a, float2 b) {
    return make_float2(a.x * b.x - a.y * b.y, a.x * b.y + a.y * b.x);
}
__device__ __forceinline__ float2 cmulc(float2 a, float2 b) {  // a * conj(b)
    return make_float2(a.x * b.x + a.y * b.y, a.y * b.x - a.x * b.y);
}
__device__ __forceinline__ float2 cadd(float2 a, float2 b) { return make_float2(a.x + b.x, a.y + b.y); }
__device__ __forceinline__ float2 csub(float2 a, float2 b) { return make_float2(a.x - b.x, a.y - b.y); }

// ---------------- W transpose + fp32->fp16 convert (once per call) ----------------
__global__ __launch_bounds__(256) void wt_convert(const float* __restrict__ Wq,
                                                  const float* __restrict__ Wk,
                                                  const float* __restrict__ Wo,
                                                  unsigned short* __restrict__ Tq,
                                                  unsigned short* __restrict__ Tk,
                                                  unsigned short* __restrict__ To) {
    __shared__ float T[64][65];
    const float* src = blockIdx.z == 0 ? Wq : (blockIdx.z == 1 ? Wk : Wo);
    unsigned short* dst = blockIdx.z == 0 ? Tq : (blockIdx.z == 1 ? Tk : To);
    const int tid = threadIdx.x;
    const int r0 = blockIdx.y * 64, c0 = blockIdx.x * 64;
#pragma unroll
    for (int p = 0; p < 4; ++p) {
        int idx = tid + 256 * p;
        int row = idx >> 4, c4 = idx & 15;
        float4 v = *reinterpret_cast<const float4*>(&src[(size_t)(r0 + row) * DD + c0 + c4 * 4]);
        T[row][c4 * 4 + 0] = v.x;
        T[row][c4 * 4 + 1] = v.y;
        T[row][c4 * 4 + 2] = v.z;
        T[row][c4 * 4 + 3] = v.w;
    }
    __syncthreads();
#pragma unroll
    for (int p = 0; p < 4; ++p) {
        int idx = tid + 256 * p;
        int orow = idx >> 4, oc4 = idx & 15;
        us4 o;
#pragma unroll
        for (int j = 0; j < 4; ++j) o[j] = f2h(T[oc4 * 4 + j][orow]);
        *reinterpret_cast<us4*>(&dst[(size_t)(c0 + orow) * DD + r0 + oc4 * 4]) = o;
    }
}

// ---------------- projection GEMM, fp16 MFMA, fp16 transposed output [B,H,DEPTH,L] ----------------
__global__ __launch_bounds__(256) void proj_gemm_mfma(const float* __restrict__ X,
                                                      const unsigned short* __restrict__ Wt,
                                                      const float* __restrict__ bias,
                                                      unsigned short* __restrict__ outT) {
    __shared__ unsigned short Asm[128][40];  // [m(row)][k] padded
    __shared__ unsigned short Bsm[128][40];  // [n(col)][k] padded
    const int tid = threadIdx.x;
    const int lane = tid & 63, wid = tid >> 6;
    const int wr = wid >> 1, wc = wid & 1;  // 2x2 wave grid
    const int g = lane >> 4, rl = lane & 15;
    const int r0 = blockIdx.y * 128, c0 = blockIdx.x * 128;
    f32x4 acc[4][4];
#pragma unroll
    for (int m = 0; m < 4; ++m)
#pragma unroll
        for (int n = 0; n < 4; ++n) acc[m][n] = (f32x4){0.f, 0.f, 0.f, 0.f};

    for (int k0 = 0; k0 < DD; k0 += 32) {
        float4 av[4];
#pragma unroll
        for (int p = 0; p < 4; ++p) {
            int idx = tid + 256 * p;
            int row = idx >> 3, kq = idx & 7;
            av[p] = *reinterpret_cast<const float4*>(&X[(size_t)(r0 + row) * DD + k0 + kq * 4]);
        }
        us8 bv[2];
#pragma unroll
        for (int p = 0; p < 2; ++p) {
            int idx = tid + 256 * p;
            int row = idx >> 2, kq = idx & 3;
            bv[p] = *reinterpret_cast<const us8*>(&Wt[(size_t)(c0 + row) * DD + k0 + kq * 8]);
        }
        __syncthreads();  // previous iteration's fragment reads done
#pragma unroll
        for (int p = 0; p < 4; ++p) {
            int idx = tid + 256 * p;
            int row = idx >> 3, kq = idx & 7;
            us4 w;
            w[0] = f2h(av[p].x); w[1] = f2h(av[p].y); w[2] = f2h(av[p].z); w[3] = f2h(av[p].w);
            *reinterpret_cast<us4*>(&Asm[row][kq * 4]) = w;
        }
#pragma unroll
        for (int p = 0; p < 2; ++p) {
            int idx = tid + 256 * p;
            int row = idx >> 2, kq = idx & 3;
            *reinterpret_cast<us8*>(&Bsm[row][kq * 8]) = bv[p];
        }
        __syncthreads();
        f16x8 af[4], bfr[4];
#pragma unroll
        for (int m = 0; m < 4; ++m)
            af[m] = *reinterpret_cast<const f16x8*>(&Asm[wr * 64 + m * 16 + rl][g * 8]);
#pragma unroll
        for (int n = 0; n < 4; ++n)
            bfr[n] = *reinterpret_cast<const f16x8*>(&Bsm[wc * 64 + n * 16 + rl][g * 8]);
#pragma unroll
        for (int m = 0; m < 4; ++m)
#pragma unroll
            for (int n = 0; n < 4; ++n)
                acc[m][n] = __builtin_amdgcn_mfma_f32_16x16x32_f16(af[m], bfr[n], acc[m][n], 0, 0, 0);
    }

    // epilogue: fp16 transposed write outT[((b*8+h)*64+dd)*2048 + l]
    const int b = r0 >> 11, l0 = r0 & (LL - 1);
#pragma unroll
    for (int m = 0; m < 4; ++m) {
#pragma unroll
        for (int n = 0; n < 4; ++n) {
            int c = c0 + wc * 64 + n * 16 + rl;
            int h = c >> 6, dd = c & 63;
            float bvv = bias[c];
            int lb = l0 + wr * 64 + m * 16 + g * 4;
            us4 o;
#pragma unroll
            for (int j = 0; j < 4; ++j) o[j] = f2h(acc[m][n][j] + bvv);
            *reinterpret_cast<us4*>(&outT[((size_t)(b * HH + h) * DEPTH + dd) * LL + lb]) = o;
        }
    }
}

// ---------------- correlation via FFT, padded SoA LDS + b128 aggregation ----------------
// reads qt,kt fp16 rows; writes fp16 delays in-place over the kt row
__global__ __launch_bounds__(256) void corr_fft_v3(const unsigned short* __restrict__ qt,
                                                   unsigned short* __restrict__ kt) {
    __shared__ float zr[2112], zi[2112];  // 2048 + 64 pad
    __shared__ float q_s[NN];
    __shared__ float cand_v[64];
    __shared__ int cand_i[64];
    __shared__ float corr_s[TOPK];
    __shared__ int topi_s[TOPK];
    const int tid = threadIdx.x;
    const int lane = tid & 63, wid = tid >> 6;
    const size_t base = (size_t)blockIdx.x * NN;

#define LD2(i) make_float2(zr[i], zi[i])
#define ST2(i, v) do { zr[i] = (v).x; zi[i] = (v).y; } while (0)

    // ---- load 8 consecutive fp16 q,k per thread; cvt; q_s natural; bit-reversed scatter ----
    {
        us8 qa = *reinterpret_cast<const us8*>(qt + base + 8 * tid);
        us8 ka = *reinterpret_cast<const us8*>(kt + base + 8 * tid);
        f16x8 qh = __builtin_bit_cast(f16x8, qa);
        f16x8 kh = __builtin_bit_cast(f16x8, ka);
        float qv[8], kv[8];
#pragma unroll
        for (int u = 0; u < 8; ++u) { qv[u] = (float)qh[u]; kv[u] = (float)kh[u]; }
        *reinterpret_cast<float4*>(&q_s[8 * tid]) = make_float4(qv[0], qv[1], qv[2], qv[3]);
        *reinterpret_cast<float4*>(&q_s[8 * tid + 4]) = make_float4(qv[4], qv[5], qv[6], qv[7]);
        int pb = (int)(__brev((unsigned)tid) >> 24);  // brev8(tid)
        const int b3[8] = {0, 4, 2, 6, 1, 5, 3, 7};   // brev3(u)
#pragma unroll
        for (int u = 0; u < 8; ++u) {
            int pf = b3[u] * 256 + pb;  // = brev11(8*tid + u)
            zr[PD(pf)] = qv[u];
            zi[PD(pf)] = kv[u];
        }
    }
    __syncthreads();

    // ---- forward DIT (bit-reversed in -> natural out), quad passes (h, 2h) ----
#pragma unroll
    for (int hh = 1; hh <= 256; hh <<= 2) {
#pragma unroll
        for (int i2 = 0; i2 < 2; ++i2) {
            int q = tid + 256 * i2;
            int p = q & (hh - 1);
            int i0 = ((q ^ p) << 2) | p;
            int e0 = PD(i0), e1 = PD(i0 + hh), e2 = PD(i0 + 2 * hh), e3 = PD(i0 + 3 * hh);
            float2 a = LD2(e0), b = LD2(e1), c = LD2(e2), d = LD2(e3);
            float ang = -PIF * (float)p / (float)(2 * hh);
            float sn, cs;
            __sincosf(ang, &sn, &cs);
            float2 w2 = make_float2(cs, sn);
            float2 w1 = make_float2(cs * cs - sn * sn, 2.f * cs * sn);
            float2 bp = cmul(b, w1), dp = cmul(d, w1);
            float2 A0 = cadd(a, bp), A1 = csub(a, bp);
            float2 A2 = cadd(c, dp), A3 = csub(c, dp);
            float2 t2 = cmul(A2, w2);
            float2 u3 = cmul(A3, w2);
            float2 t3 = make_float2(u3.y, -u3.x);  // -i * u3
            ST2(e0, cadd(A0, t2));
            ST2(e2, csub(A0, t2));
            ST2(e1, cadd(A1, t3));
            ST2(e3, csub(A1, t3));
        }
        __syncthreads();
    }
    // single DIT stage h=1024
#pragma unroll
    for (int u = 0; u < 4; ++u) {
        int b4 = tid + 256 * u;
        int e0 = PD(b4), e1 = PD(b4 + 1024);
        float2 a = LD2(e0), c = LD2(e1);
        float ang = -PIF * (float)b4 * (1.f / 1024.f);
        float sn, cs;
        __sincosf(ang, &sn, &cs);
        float2 t = cmul(c, make_float2(cs, sn));
        ST2(e0, cadd(a, t));
        ST2(e1, csub(a, t));
    }
    __syncthreads();

    // ---- Hermitian unpack + S = Q*conj(K), NATURAL order ----
    {
        float2 S[8];
#pragma unroll
        for (int u = 0; u < 8; ++u) {
            int f = tid + 256 * u;
            int mf = (NN - f) & (NN - 1);
            float2 Zf = LD2(PD(f)), Zm = LD2(PD(mf));
            float2 Qf = make_float2(0.5f * (Zf.x + Zm.x), 0.5f * (Zf.y - Zm.y));
            float2 Dm = make_float2(Zf.x - Zm.x, Zf.y + Zm.y);   // Zf - conj(Zm)
            float2 Kf = make_float2(0.5f * Dm.y, -0.5f * Dm.x);  // -0.5i * Dm
            S[u] = cmulc(Qf, Kf);
        }
        __syncthreads();
#pragma unroll
        for (int u = 0; u < 8; ++u) ST2(PD(tid + 256 * u), S[u]);
        __syncthreads();
    }

    // ---- inverse DIF (natural in -> bit-reversed out), quad passes (2h, h) ----
#pragma unroll
    for (int hh = 512; hh >= 2; hh >>= 2) {
#pragma unroll
        for (int i2 = 0; i2 < 2; ++i2) {
            int q = tid + 256 * i2;
            int p = q & (hh - 1);
            int i0 = ((q ^ p) << 2) | p;
            int e0 = PD(i0), e1 = PD(i0 + hh), e2 = PD(i0 + 2 * hh), e3 = PD(i0 + 3 * hh);
            float2 a = LD2(e0), b = LD2(e1), c = LD2(e2), d = LD2(e3);
            float ang = PIF * (float)p / (float)(2 * hh);
            float sn, cs;
            __sincosf(ang, &sn, &cs);
            float2 w = make_float2(cs, sn);
            float2 w2 = make_float2(cs * cs - sn * sn, 2.f * cs * sn);
            float2 S0 = cadd(a, c);
            float2 D0 = cmul(csub(a, c), w);
            float2 S1 = cadd(b, d);
            float2 f2 = cmul(csub(b, d), w);
            float2 D1 = make_float2(-f2.y, f2.x);  // i * f2
            ST2(e0, cadd(S0, S1));
            ST2(e1, cmul(csub(S0, S1), w2));
            ST2(e2, cadd(D0, D1));
            ST2(e3, cmul(csub(D0, D1), w2));
        }
        __syncthreads();
    }
    // final DIF stage h=1 into registers; real part only.  tau = brev of storage idx.
    float r[8];
    int tau[8];
#pragma unroll
    for (int u = 0; u < 4; ++u) {
        int b4 = tid + 256 * u;
        float x0 = zr[PD(2 * b4)], x1 = zr[PD(2 * b4 + 1)];
        r[u] = (x0 + x1) * (1.0f / NN);
        r[u + 4] = (x0 - x1) * (1.0f / NN);
        int t0 = (int)(__brev((unsigned)b4) >> 22);  // brev10
        tau[u] = t0;
        tau[u + 4] = t0 + 1024;
    }

    // ---- per-wave top-15 (shfl only), then single merge ----
    for (int it = 0; it < TOPK; ++it) {
        float best = -FLT_MAX;
        int bi = 0x7fffffff;
#pragma unroll
        for (int w = 0; w < 8; ++w) {
            if (r[w] > best || (r[w] == best && tau[w] < bi)) { best = r[w]; bi = tau[w]; }
        }
#pragma unroll
        for (int off = 32; off >= 1; off >>= 1) {
            float ov = __shfl_xor(best, off);
            int oi = __shfl_xor(bi, off);
            if (ov > best || (ov == best && oi < bi)) { best = ov; bi = oi; }
        }
        if (lane == 0) { cand_v[wid * 16 + it] = best; cand_i[wid * 16 + it] = bi; }
#pragma unroll
        for (int w = 0; w < 8; ++w)
            if (tau[w] == bi) r[w] = -FLT_MAX;
    }
    __syncthreads();
    if (tid == 0) {
        int head[4] = {0, 0, 0, 0};
        float w15[TOPK];
        int i15[TOPK];
        for (int it = 0; it < TOPK; ++it) {
            float bw = -FLT_MAX;
            int bi = 0x7fffffff, bs = 0;
            for (int s = 0; s < 4; ++s) {
                if (head[s] < TOPK) {
                    float v = cand_v[s * 16 + head[s]];
                    int ii = cand_i[s * 16 + head[s]];
                    if (v > bw || (v == bw && ii < bi)) { bw = v; bi = ii; bs = s; }
                }
            }
            head[bs]++;
            w15[it] = bw;
            i15[it] = bi;
        }
        float m = w15[0];
        for (int i = 1; i < TOPK; ++i) m = fmaxf(m, w15[i]);
        float ssum = 0.f;
        for (int i = 0; i < TOPK; ++i) {
            float e = expf(w15[i] - m);
            corr_s[i] = e;
            ssum += e;
        }
        float inv = 1.f / ssum;
        for (int i = 0; i < TOPK; ++i) { corr_s[i] *= inv; topi_s[i] = i15[i]; }
    }
    __syncthreads();

    // ---- aggregation: thread owns 8 consecutive t; 3 aligned float4 reads per tap;
    //      uniform switch on (d&3) keeps all indexing static (no scratch) ----
    {
        const int t0 = tid << 3;
        float acc8[8] = {0.f, 0.f, 0.f, 0.f, 0.f, 0.f, 0.f, 0.f};
        for (int i = 0; i < TOPK; ++i) {
            const float w = corr_s[i];
            const int d = topi_s[i];
            const int off = d & 3;                       // wave-uniform
            const int bb = (t0 + d - off) & (NN - 1);    // 4-aligned block start
            float4 B0 = *reinterpret_cast<const float4*>(&q_s[bb]);
            float4 B1 = *reinterpret_cast<const float4*>(&q_s[(bb + 4) & (NN - 1)]);
            float4 B2 = *reinterpret_cast<const float4*>(&q_s[(bb + 8) & (NN - 1)]);
            const float bf[12] = {B0.x, B0.y, B0.z, B0.w, B1.x, B1.y, B1.z, B1.w,
                                  B2.x, B2.y, B2.z, B2.w};
            switch (off) {
                case 0: {
#pragma unroll
                    for (int j = 0; j < 8; ++j) acc8[j] += w * bf[0 + j];
                } break;
                case 1: {
#pragma unroll
                    for (int j = 0; j < 8; ++j) acc8[j] += w * bf[1 + j];
                } break;
                case 2: {
#pragma unroll
                    for (int j = 0; j < 8; ++j) acc8[j] += w * bf[2 + j];
                } break;
                default: {
#pragma unroll
                    for (int j = 0; j < 8; ++j) acc8[j] += w * bf[3 + j];
                } break;
            }
        }
        us8 o8;
#pragma unroll
        for (int j = 0; j < 8; ++j) o8[j] = f2h(acc8[j]);
        *reinterpret_cast<us8*>(kt + base + t0) = o8;
    }
#undef LD2
#undef ST2
}

// ---------------- output GEMM, fp16 MFMA: out[r,c] = sum_k delays[b,k,l]*Wo[k,c] + bo[c] ----------------
// delays fp16 rows at kt + (b*512+k)*2048;  WtO[c][k] = Wo[k][c]
__global__ __launch_bounds__(256) void out_gemm_mfma(const unsigned short* __restrict__ db,
                                                     const unsigned short* __restrict__ WtO,
                                                     const float* __restrict__ bias,
                                                     float* __restrict__ out) {
    __shared__ unsigned short Asm[32][132];  // [k][l], stride 132 -> 4-way max on u16 extract
    __shared__ unsigned short Bsm[128][40];  // [c][k] padded
    const int tid = threadIdx.x;
    const int lane = tid & 63, wid = tid >> 6;
    const int wr = wid >> 1, wc = wid & 1;
    const int g = lane >> 4, rl = lane & 15;
    const int r0 = blockIdx.y * 128, c0 = blockIdx.x * 128;
    const int b = r0 >> 11, l0 = r0 & (LL - 1);
    f32x4 acc[4][4];
#pragma unroll
    for (int m = 0; m < 4; ++m)
#pragma unroll
        for (int n = 0; n < 4; ++n) acc[m][n] = (f32x4){0.f, 0.f, 0.f, 0.f};

    for (int k0 = 0; k0 < DD; k0 += 32) {
        us8 avv[2], bvv[2];
#pragma unroll
        for (int p = 0; p < 2; ++p) {
            int idx = tid + 256 * p;
            int kr = idx >> 4, dc = idx & 15;
            avv[p] = *reinterpret_cast<const us8*>(
                &db[(size_t)(b * DD + k0 + kr) * 2048 + l0 + dc * 8]);
        }
#pragma unroll
        for (int p = 0; p < 2; ++p) {
            int idx = tid + 256 * p;
            int row = idx >> 2, kq = idx & 3;
            bvv[p] = *reinterpret_cast<const us8*>(&WtO[(size_t)(c0 + row) * DD + k0 + kq * 8]);
        }
        __syncthreads();
#pragma unroll
        for (int p = 0; p < 2; ++p) {
            int idx = tid + 256 * p;
            int kr = idx >> 4, dc = idx & 15;
            us4 lo, hi;
#pragma unroll
            for (int j = 0; j < 4; ++j) { lo[j] = avv[p][j]; hi[j] = avv[p][j + 4]; }
            *reinterpret_cast<us4*>(&Asm[kr][dc * 8]) = lo;
            *reinterpret_cast<us4*>(&Asm[kr][dc * 8 + 4]) = hi;
        }
#pragma unroll
        for (int p = 0; p < 2; ++p) {
            int idx = tid + 256 * p;
            int row = idx >> 2, kq = idx & 3;
            *reinterpret_cast<us8*>(&Bsm[row][kq * 8]) = bvv[p];
        }
        __syncthreads();
        f16x8 af[4], bfr[4];
#pragma unroll
        for (int m = 0; m < 4; ++m) {
            int l = wr * 64 + m * 16 + rl;
            us8 t;
#pragma unroll
            for (int j = 0; j < 8; ++j) t[j] = Asm[g * 8 + j][l];
            af[m] = __builtin_bit_cast(f16x8, t);
        }
#pragma unroll
        for (int n = 0; n < 4; ++n)
            bfr[n] = *reinterpret_cast<const f16x8*>(&Bsm[wc * 64 + n * 16 + rl][g * 8]);
#pragma unroll
        for (int m = 0; m < 4; ++m)
#pragma unroll
            for (int n = 0; n < 4; ++n)
                acc[m][n] = __builtin_amdgcn_mfma_f32_16x16x32_f16(af[m], bfr[n], acc[m][n], 0, 0, 0);
    }

#pragma unroll
    for (int m = 0; m < 4; ++m) {
#pragma unroll
        for (int n = 0; n < 4; ++n) {
            int c = c0 + wc * 64 + n * 16 + rl;
            float bvv = bias[c];
            int rbase = r0 + wr * 64 + m * 16 + g * 4;
#pragma unroll
            for (int j = 0; j < 4; ++j)
                out[(size_t)(rbase + j) * DD + c] = acc[m][n][j] + bvv;
        }
    }
}

extern "C" void kernel_launch(void* const* d_in, const int* in_sizes, int n_in,
                              void* d_out, int out_size, void* d_ws, size_t ws_size,
                              hipStream_t stream) {
    const float* q = (const float*)d_in[0];
    const float* k = (const float*)d_in[1];
    const float* Wq = (const float*)d_in[3];
    const float* bq = (const float*)d_in[4];
    const float* Wk = (const float*)d_in[5];
    const float* bk = (const float*)d_in[6];
    const float* Wo = (const float*)d_in[9];
    const float* bo = (const float*)d_in[10];
    float* out = (float*)d_out;

    unsigned short* qt = (unsigned short*)d_ws;                 // [B,H,DEPTH,L] fp16, 16.8MB
    unsigned short* kt = qt + (size_t)BB * HH * DEPTH * LL;     // [B,H,DEPTH,L] fp16; delays in-place
    unsigned short* Tq = kt + (size_t)BB * HH * DEPTH * LL;
    unsigned short* Tk = Tq + (size_t)DD * DD;
    unsigned short* To = Tk + (size_t)DD * DD;

    dim3 blk(256);
    wt_convert<<<dim3(8, 8, 3), blk, 0, stream>>>(Wq, Wk, Wo, Tq, Tk, To);
    proj_gemm_mfma<<<dim3(4, 128), blk, 0, stream>>>(q, Tq, bq, qt);
    proj_gemm_mfma<<<dim3(4, 128), blk, 0, stream>>>(k, Tk, bk, kt);
    corr_fft_v3<<<dim3(BB * HH * DEPTH), blk, 0, stream>>>(qt, kt);
    out_gemm_mfma<<<dim3(4, 128), blk, 0, stream>>>(kt, To, bo, out);
}

// Round 6
// 193.172 us; speedup vs baseline: 1.8050x; 1.8050x over previous
//
#include <hip/hip_runtime.h>
#include <hip/hip_fp16.h>
#include <float.h>
#include <math.h>

#define BB 8
#define LL 2048
#define NN 2048
#define DD 512
#define HH 8
#define DEPTH 64
#define TOPK 15
#define PIF 3.14159265358979323846f

// padded index for zr/zi: +1 float per 32 -> breaks power-of-2 bank aliasing
#define PD(i) ((i) + ((i) >> 5))

using f16x8 = __attribute__((ext_vector_type(8))) _Float16;
typedef __attribute__((ext_vector_type(4))) float f32x4;
typedef __attribute__((ext_vector_type(8))) unsigned short us8;
typedef __attribute__((ext_vector_type(4))) unsigned short us4;

__device__ __forceinline__ unsigned short f2h(float f) {
    return __half_as_ushort(__float2half(f));  // RNE
}
__device__ __forceinline__ float2 cmul(float2 a, float2 b) {
    return make_float2(a.x * b.x - a.y * b.y, a.x * b.y + a.y * b.x);
}
__device__ __forceinline__ float2 cmulc(float2 a, float2 b) {  // a * conj(b)
    return make_float2(a.x * b.x + a.y * b.y, a.y * b.x - a.x * b.y);
}
__device__ __forceinline__ float2 cadd(float2 a, float2 b) { return make_float2(a.x + b.x, a.y + b.y); }
__device__ __forceinline__ float2 csub(float2 a, float2 b) { return make_float2(a.x - b.x, a.y - b.y); }

// ---------------- W transpose + fp32->fp16 convert (once per call) ----------------
__global__ __launch_bounds__(256) void wt_convert(const float* __restrict__ Wq,
                                                  const float* __restrict__ Wk,
                                                  const float* __restrict__ Wo,
                                                  unsigned short* __restrict__ Tq,
                                                  unsigned short* __restrict__ Tk,
                                                  unsigned short* __restrict__ To) {
    __shared__ float T[64][65];
    const float* src = blockIdx.z == 0 ? Wq : (blockIdx.z == 1 ? Wk : Wo);
    unsigned short* dst = blockIdx.z == 0 ? Tq : (blockIdx.z == 1 ? Tk : To);
    const int tid = threadIdx.x;
    const int r0 = blockIdx.y * 64, c0 = blockIdx.x * 64;
#pragma unroll
    for (int p = 0; p < 4; ++p) {
        int idx = tid + 256 * p;
        int row = idx >> 4, c4 = idx & 15;
        float4 v = *reinterpret_cast<const float4*>(&src[(size_t)(r0 + row) * DD + c0 + c4 * 4]);
        T[row][c4 * 4 + 0] = v.x;
        T[row][c4 * 4 + 1] = v.y;
        T[row][c4 * 4 + 2] = v.z;
        T[row][c4 * 4 + 3] = v.w;
    }
    __syncthreads();
#pragma unroll
    for (int p = 0; p < 4; ++p) {
        int idx = tid + 256 * p;
        int orow = idx >> 4, oc4 = idx & 15;
        us4 o;
#pragma unroll
        for (int j = 0; j < 4; ++j) o[j] = f2h(T[oc4 * 4 + j][orow]);
        *reinterpret_cast<us4*>(&dst[(size_t)(c0 + orow) * DD + r0 + oc4 * 4]) = o;
    }
}

// ---------------- projection GEMM, fp16 MFMA, fp16 transposed output [B,H,DEPTH,L] ----------------
__global__ __launch_bounds__(256) void proj_gemm_mfma(const float* __restrict__ X,
                                                      const unsigned short* __restrict__ Wt,
                                                      const float* __restrict__ bias,
                                                      unsigned short* __restrict__ outT) {
    __shared__ unsigned short Asm[128][40];  // [m(row)][k] padded
    __shared__ unsigned short Bsm[128][40];  // [n(col)][k] padded
    const int tid = threadIdx.x;
    const int lane = tid & 63, wid = tid >> 6;
    const int wr = wid >> 1, wc = wid & 1;  // 2x2 wave grid
    const int g = lane >> 4, rl = lane & 15;
    const int r0 = blockIdx.y * 128, c0 = blockIdx.x * 128;
    f32x4 acc[4][4];
#pragma unroll
    for (int m = 0; m < 4; ++m)
#pragma unroll
        for (int n = 0; n < 4; ++n) acc[m][n] = (f32x4){0.f, 0.f, 0.f, 0.f};

    for (int k0 = 0; k0 < DD; k0 += 32) {
        float4 av[4];
#pragma unroll
        for (int p = 0; p < 4; ++p) {
            int idx = tid + 256 * p;
            int row = idx >> 3, kq = idx & 7;
            av[p] = *reinterpret_cast<const float4*>(&X[(size_t)(r0 + row) * DD + k0 + kq * 4]);
        }
        us8 bv[2];
#pragma unroll
        for (int p = 0; p < 2; ++p) {
            int idx = tid + 256 * p;
            int row = idx >> 2, kq = idx & 3;
            bv[p] = *reinterpret_cast<const us8*>(&Wt[(size_t)(c0 + row) * DD + k0 + kq * 8]);
        }
        __syncthreads();  // previous iteration's fragment reads done
#pragma unroll
        for (int p = 0; p < 4; ++p) {
            int idx = tid + 256 * p;
            int row = idx >> 3, kq = idx & 7;
            us4 w;
            w[0] = f2h(av[p].x); w[1] = f2h(av[p].y); w[2] = f2h(av[p].z); w[3] = f2h(av[p].w);
            *reinterpret_cast<us4*>(&Asm[row][kq * 4]) = w;
        }
#pragma unroll
        for (int p = 0; p < 2; ++p) {
            int idx = tid + 256 * p;
            int row = idx >> 2, kq = idx & 3;
            *reinterpret_cast<us8*>(&Bsm[row][kq * 8]) = bv[p];
        }
        __syncthreads();
        f16x8 af[4], bfr[4];
#pragma unroll
        for (int m = 0; m < 4; ++m)
            af[m] = *reinterpret_cast<const f16x8*>(&Asm[wr * 64 + m * 16 + rl][g * 8]);
#pragma unroll
        for (int n = 0; n < 4; ++n)
            bfr[n] = *reinterpret_cast<const f16x8*>(&Bsm[wc * 64 + n * 16 + rl][g * 8]);
#pragma unroll
        for (int m = 0; m < 4; ++m)
#pragma unroll
            for (int n = 0; n < 4; ++n)
                acc[m][n] = __builtin_amdgcn_mfma_f32_16x16x32_f16(af[m], bfr[n], acc[m][n], 0, 0, 0);
    }

    // epilogue: fp16 transposed write outT[((b*8+h)*64+dd)*2048 + l]
    const int b = r0 >> 11, l0 = r0 & (LL - 1);
#pragma unroll
    for (int m = 0; m < 4; ++m) {
#pragma unroll
        for (int n = 0; n < 4; ++n) {
            int c = c0 + wc * 64 + n * 16 + rl;
            int h = c >> 6, dd = c & 63;
            float bvv = bias[c];
            int lb = l0 + wr * 64 + m * 16 + g * 4;
            us4 o;
#pragma unroll
            for (int j = 0; j < 4; ++j) o[j] = f2h(acc[m][n][j] + bvv);
            *reinterpret_cast<us4*>(&outT[((size_t)(b * HH + h) * DEPTH + dd) * LL + lb]) = o;
        }
    }
}

// ---------------- correlation via FFT: padded SoA LDS, fp16 I/O, scalar aggregation ----------------
// reads qt,kt fp16 rows; writes fp16 delays in-place over the kt row
__global__ __launch_bounds__(256) void corr_fft_v4(const unsigned short* __restrict__ qt,
                                                   unsigned short* __restrict__ kt) {
    __shared__ float zr[2112], zi[2112];  // 2048 + 64 pad
    __shared__ float q_s[NN];
    __shared__ float cand_v[64];
    __shared__ int cand_i[64];
    __shared__ float corr_s[TOPK];
    __shared__ int topi_s[TOPK];
    const int tid = threadIdx.x;
    const int lane = tid & 63, wid = tid >> 6;
    const size_t base = (size_t)blockIdx.x * NN;

#define LD2(i) make_float2(zr[i], zi[i])
#define ST2(i, v) do { zr[i] = (v).x; zi[i] = (v).y; } while (0)

    // ---- load 8 consecutive fp16 q,k per thread; cvt; q_s natural; bit-reversed scatter ----
    {
        us8 qa = *reinterpret_cast<const us8*>(qt + base + 8 * tid);
        us8 ka = *reinterpret_cast<const us8*>(kt + base + 8 * tid);
        f16x8 qh = __builtin_bit_cast(f16x8, qa);
        f16x8 kh = __builtin_bit_cast(f16x8, ka);
        float qv[8], kv[8];
#pragma unroll
        for (int u = 0; u < 8; ++u) { qv[u] = (float)qh[u]; kv[u] = (float)kh[u]; }
        *reinterpret_cast<float4*>(&q_s[8 * tid]) = make_float4(qv[0], qv[1], qv[2], qv[3]);
        *reinterpret_cast<float4*>(&q_s[8 * tid + 4]) = make_float4(qv[4], qv[5], qv[6], qv[7]);
        int pb = (int)(__brev((unsigned)tid) >> 24);  // brev8(tid)
        const int b3[8] = {0, 4, 2, 6, 1, 5, 3, 7};   // brev3(u)
#pragma unroll
        for (int u = 0; u < 8; ++u) {
            int pf = b3[u] * 256 + pb;  // = brev11(8*tid + u)
            zr[PD(pf)] = qv[u];
            zi[PD(pf)] = kv[u];
        }
    }
    __syncthreads();

    // ---- forward DIT (bit-reversed in -> natural out), quad passes (h, 2h) ----
#pragma unroll
    for (int hh = 1; hh <= 256; hh <<= 2) {
#pragma unroll
        for (int i2 = 0; i2 < 2; ++i2) {
            int q = tid + 256 * i2;
            int p = q & (hh - 1);
            int i0 = ((q ^ p) << 2) | p;
            int e0 = PD(i0), e1 = PD(i0 + hh), e2 = PD(i0 + 2 * hh), e3 = PD(i0 + 3 * hh);
            float2 a = LD2(e0), b = LD2(e1), c = LD2(e2), d = LD2(e3);
            float ang = -PIF * (float)p / (float)(2 * hh);
            float sn, cs;
            __sincosf(ang, &sn, &cs);
            float2 w2 = make_float2(cs, sn);
            float2 w1 = make_float2(cs * cs - sn * sn, 2.f * cs * sn);
            float2 bp = cmul(b, w1), dp = cmul(d, w1);
            float2 A0 = cadd(a, bp), A1 = csub(a, bp);
            float2 A2 = cadd(c, dp), A3 = csub(c, dp);
            float2 t2 = cmul(A2, w2);
            float2 u3 = cmul(A3, w2);
            float2 t3 = make_float2(u3.y, -u3.x);  // -i * u3
            ST2(e0, cadd(A0, t2));
            ST2(e2, csub(A0, t2));
            ST2(e1, cadd(A1, t3));
            ST2(e3, csub(A1, t3));
        }
        __syncthreads();
    }
    // single DIT stage h=1024
#pragma unroll
    for (int u = 0; u < 4; ++u) {
        int b4 = tid + 256 * u;
        int e0 = PD(b4), e1 = PD(b4 + 1024);
        float2 a = LD2(e0), c = LD2(e1);
        float ang = -PIF * (float)b4 * (1.f / 1024.f);
        float sn, cs;
        __sincosf(ang, &sn, &cs);
        float2 t = cmul(c, make_float2(cs, sn));
        ST2(e0, cadd(a, t));
        ST2(e1, csub(a, t));
    }
    __syncthreads();

    // ---- Hermitian unpack + S = Q*conj(K), NATURAL order ----
    {
        float2 S[8];
#pragma unroll
        for (int u = 0; u < 8; ++u) {
            int f = tid + 256 * u;
            int mf = (NN - f) & (NN - 1);
            float2 Zf = LD2(PD(f)), Zm = LD2(PD(mf));
            float2 Qf = make_float2(0.5f * (Zf.x + Zm.x), 0.5f * (Zf.y - Zm.y));
            float2 Dm = make_float2(Zf.x - Zm.x, Zf.y + Zm.y);   // Zf - conj(Zm)
            float2 Kf = make_float2(0.5f * Dm.y, -0.5f * Dm.x);  // -0.5i * Dm
            S[u] = cmulc(Qf, Kf);
        }
        __syncthreads();
#pragma unroll
        for (int u = 0; u < 8; ++u) ST2(PD(tid + 256 * u), S[u]);
        __syncthreads();
    }

    // ---- inverse DIF (natural in -> bit-reversed out), quad passes (2h, h) ----
#pragma unroll
    for (int hh = 512; hh >= 2; hh >>= 2) {
#pragma unroll
        for (int i2 = 0; i2 < 2; ++i2) {
            int q = tid + 256 * i2;
            int p = q & (hh - 1);
            int i0 = ((q ^ p) << 2) | p;
            int e0 = PD(i0), e1 = PD(i0 + hh), e2 = PD(i0 + 2 * hh), e3 = PD(i0 + 3 * hh);
            float2 a = LD2(e0), b = LD2(e1), c = LD2(e2), d = LD2(e3);
            float ang = PIF * (float)p / (float)(2 * hh);
            float sn, cs;
            __sincosf(ang, &sn, &cs);
            float2 w = make_float2(cs, sn);
            float2 w2 = make_float2(cs * cs - sn * sn, 2.f * cs * sn);
            float2 S0 = cadd(a, c);
            float2 D0 = cmul(csub(a, c), w);
            float2 S1 = cadd(b, d);
            float2 f2 = cmul(csub(b, d), w);
            float2 D1 = make_float2(-f2.y, f2.x);  // i * f2
            ST2(e0, cadd(S0, S1));
            ST2(e1, cmul(csub(S0, S1), w2));
            ST2(e2, cadd(D0, D1));
            ST2(e3, cmul(csub(D0, D1), w2));
        }
        __syncthreads();
    }
    // final DIF stage h=1 into registers; real part only.  tau = brev of storage idx.
    float r[8];
    int tau[8];
#pragma unroll
    for (int u = 0; u < 4; ++u) {
        int b4 = tid + 256 * u;
        float x0 = zr[PD(2 * b4)], x1 = zr[PD(2 * b4 + 1)];
        r[u] = (x0 + x1) * (1.0f / NN);
        r[u + 4] = (x0 - x1) * (1.0f / NN);
        int t0 = (int)(__brev((unsigned)b4) >> 22);  // brev10
        tau[u] = t0;
        tau[u + 4] = t0 + 1024;
    }

    // ---- per-wave top-15 (shfl only), then single merge ----
    for (int it = 0; it < TOPK; ++it) {
        float best = -FLT_MAX;
        int bi = 0x7fffffff;
#pragma unroll
        for (int w = 0; w < 8; ++w) {
            if (r[w] > best || (r[w] == best && tau[w] < bi)) { best = r[w]; bi = tau[w]; }
        }
#pragma unroll
        for (int off = 32; off >= 1; off >>= 1) {
            float ov = __shfl_xor(best, off);
            int oi = __shfl_xor(bi, off);
            if (ov > best || (ov == best && oi < bi)) { best = ov; bi = oi; }
        }
        if (lane == 0) { cand_v[wid * 16 + it] = best; cand_i[wid * 16 + it] = bi; }
#pragma unroll
        for (int w = 0; w < 8; ++w)
            if (tau[w] == bi) r[w] = -FLT_MAX;
    }
    __syncthreads();
    if (tid == 0) {
        int head[4] = {0, 0, 0, 0};
        float w15[TOPK];
        int i15[TOPK];
        for (int it = 0; it < TOPK; ++it) {
            float bw = -FLT_MAX;
            int bi = 0x7fffffff, bs = 0;
            for (int s = 0; s < 4; ++s) {
                if (head[s] < TOPK) {
                    float v = cand_v[s * 16 + head[s]];
                    int ii = cand_i[s * 16 + head[s]];
                    if (v > bw || (v == bw && ii < bi)) { bw = v; bi = ii; bs = s; }
                }
            }
            head[bs]++;
            w15[it] = bw;
            i15[it] = bi;
        }
        float m = w15[0];
        for (int i = 1; i < TOPK; ++i) m = fmaxf(m, w15[i]);
        float ssum = 0.f;
        for (int i = 0; i < TOPK; ++i) {
            float e = expf(w15[i] - m);
            corr_s[i] = e;
            ssum += e;
        }
        float inv = 1.f / ssum;
        for (int i = 0; i < TOPK; ++i) { corr_s[i] *= inv; topi_s[i] = i15[i]; }
    }
    __syncthreads();

    // ---- aggregation: lane-consecutive scalar reads (conflict-free), fp16 scalar stores ----
    {
        float cw[TOPK];
        int ci[TOPK];
#pragma unroll
        for (int i = 0; i < TOPK; ++i) { cw[i] = corr_s[i]; ci[i] = topi_s[i]; }
#pragma unroll
        for (int u = 0; u < 8; ++u) {
            int t = tid + 256 * u;
            float acc = 0.f;
#pragma unroll
            for (int i = 0; i < TOPK; ++i) acc += cw[i] * q_s[(t + ci[i]) & (NN - 1)];
            kt[base + t] = f2h(acc);
        }
    }
#undef LD2
#undef ST2
}

// ---------------- output GEMM, fp16 MFMA: out[r,c] = sum_k delays[b,k,l]*Wo[k,c] + bo[c] ----------------
// delays fp16 rows at kt + (b*512+k)*2048;  WtO[c][k] = Wo[k][c]
__global__ __launch_bounds__(256) void out_gemm_mfma(const unsigned short* __restrict__ db,
                                                     const unsigned short* __restrict__ WtO,
                                                     const float* __restrict__ bias,
                                                     float* __restrict__ out) {
    __shared__ unsigned short Asm[32][132];  // [k][l], stride 132 -> 4-way max on u16 extract
    __shared__ unsigned short Bsm[128][40];  // [c][k] padded
    const int tid = threadIdx.x;
    const int lane = tid & 63, wid = tid >> 6;
    const int wr = wid >> 1, wc = wid & 1;
    const int g = lane >> 4, rl = lane & 15;
    const int r0 = blockIdx.y * 128, c0 = blockIdx.x * 128;
    const int b = r0 >> 11, l0 = r0 & (LL - 1);
    f32x4 acc[4][4];
#pragma unroll
    for (int m = 0; m < 4; ++m)
#pragma unroll
        for (int n = 0; n < 4; ++n) acc[m][n] = (f32x4){0.f, 0.f, 0.f, 0.f};

    for (int k0 = 0; k0 < DD; k0 += 32) {
        us8 avv[2], bvv[2];
#pragma unroll
        for (int p = 0; p < 2; ++p) {
            int idx = tid + 256 * p;
            int kr = idx >> 4, dc = idx & 15;
            avv[p] = *reinterpret_cast<const us8*>(
                &db[(size_t)(b * DD + k0 + kr) * 2048 + l0 + dc * 8]);
        }
#pragma unroll
        for (int p = 0; p < 2; ++p) {
            int idx = tid + 256 * p;
            int row = idx >> 2, kq = idx & 3;
            bvv[p] = *reinterpret_cast<const us8*>(&WtO[(size_t)(c0 + row) * DD + k0 + kq * 8]);
        }
        __syncthreads();
#pragma unroll
        for (int p = 0; p < 2; ++p) {
            int idx = tid + 256 * p;
            int kr = idx >> 4, dc = idx & 15;
            us4 lo, hi;
#pragma unroll
            for (int j = 0; j < 4; ++j) { lo[j] = avv[p][j]; hi[j] = avv[p][j + 4]; }
            *reinterpret_cast<us4*>(&Asm[kr][dc * 8]) = lo;
            *reinterpret_cast<us4*>(&Asm[kr][dc * 8 + 4]) = hi;
        }
#pragma unroll
        for (int p = 0; p < 2; ++p) {
            int idx = tid + 256 * p;
            int row = idx >> 2, kq = idx & 3;
            *reinterpret_cast<us8*>(&Bsm[row][kq * 8]) = bvv[p];
        }
        __syncthreads();
        f16x8 af[4], bfr[4];
#pragma unroll
        for (int m = 0; m < 4; ++m) {
            int l = wr * 64 + m * 16 + rl;
            us8 t;
#pragma unroll
            for (int j = 0; j < 8; ++j) t[j] = Asm[g * 8 + j][l];
            af[m] = __builtin_bit_cast(f16x8, t);
        }
#pragma unroll
        for (int n = 0; n < 4; ++n)
            bfr[n] = *reinterpret_cast<const f16x8*>(&Bsm[wc * 64 + n * 16 + rl][g * 8]);
#pragma unroll
        for (int m = 0; m < 4; ++m)
#pragma unroll
            for (int n = 0; n < 4; ++n)
                acc[m][n] = __builtin_amdgcn_mfma_f32_16x16x32_f16(af[m], bfr[n], acc[m][n], 0, 0, 0);
    }

#pragma unroll
    for (int m = 0; m < 4; ++m) {
#pragma unroll
        for (int n = 0; n < 4; ++n) {
            int c = c0 + wc * 64 + n * 16 + rl;
            float bvv = bias[c];
            int rbase = r0 + wr * 64 + m * 16 + g * 4;
#pragma unroll
            for (int j = 0; j < 4; ++j)
                out[(size_t)(rbase + j) * DD + c] = acc[m][n][j] + bvv;
        }
    }
}

extern "C" void kernel_launch(void* const* d_in, const int* in_sizes, int n_in,
                              void* d_out, int out_size, void* d_ws, size_t ws_size,
                              hipStream_t stream) {
    const float* q = (const float*)d_in[0];
    const float* k = (const float*)d_in[1];
    const float* Wq = (const float*)d_in[3];
    const float* bq = (const float*)d_in[4];
    const float* Wk = (const float*)d_in[5];
    const float* bk = (const float*)d_in[6];
    const float* Wo = (const float*)d_in[9];
    const float* bo = (const float*)d_in[10];
    float* out = (float*)d_out;

    unsigned short* qt = (unsigned short*)d_ws;                 // [B,H,DEPTH,L] fp16, 16.8MB
    unsigned short* kt = qt + (size_t)BB * HH * DEPTH * LL;     // [B,H,DEPTH,L] fp16; delays in-place
    unsigned short* Tq = kt + (size_t)BB * HH * DEPTH * LL;
    unsigned short* Tk = Tq + (size_t)DD * DD;
    unsigned short* To = Tk + (size_t)DD * DD;

    dim3 blk(256);
    wt_convert<<<dim3(8, 8, 3), blk, 0, stream>>>(Wq, Wk, Wo, Tq, Tk, To);
    proj_gemm_mfma<<<dim3(4, 128), blk, 0, stream>>>(q, Tq, bq, qt);
    proj_gemm_mfma<<<dim3(4, 128), blk, 0, stream>>>(k, Tk, bk, kt);
    corr_fft_v4<<<dim3(BB * HH * DEPTH), blk, 0, stream>>>(qt, kt);
    out_gemm_mfma<<<dim3(4, 128), blk, 0, stream>>>(kt, To, bo, out);
}

// Round 7
// 182.587 us; speedup vs baseline: 1.9096x; 1.0580x over previous
//
#include <hip/hip_runtime.h>
#include <hip/hip_fp16.h>
#include <float.h>
#include <math.h>

#define BB 8
#define LL 2048
#define NN 2048
#define MM 1024
#define DD 512
#define HH 8
#define DEPTH 64
#define TOPK 15
#define PIF 3.14159265358979323846f

// padded index for zr/zi: +1 float per 32 -> breaks power-of-2 bank aliasing
#define PD(i) ((i) + ((i) >> 5))

using f16x8 = __attribute__((ext_vector_type(8))) _Float16;
typedef __attribute__((ext_vector_type(4))) float f32x4;
typedef __attribute__((ext_vector_type(8))) unsigned short us8;
typedef __attribute__((ext_vector_type(4))) unsigned short us4;

__device__ __forceinline__ unsigned short f2h(float f) {
    return __half_as_ushort(__float2half(f));  // RNE
}
__device__ __forceinline__ float2 cmul(float2 a, float2 b) {
    return make_float2(a.x * b.x - a.y * b.y, a.x * b.y + a.y * b.x);
}
__device__ __forceinline__ float2 cmulc(float2 a, float2 b) {  // a * conj(b)
    return make_float2(a.x * b.x + a.y * b.y, a.y * b.x - a.x * b.y);
}
__device__ __forceinline__ float2 cadd(float2 a, float2 b) { return make_float2(a.x + b.x, a.y + b.y); }
__device__ __forceinline__ float2 csub(float2 a, float2 b) { return make_float2(a.x - b.x, a.y - b.y); }

// ---------------- W transpose + fp32->fp16 convert (once per call) ----------------
__global__ __launch_bounds__(256) void wt_convert(const float* __restrict__ Wq,
                                                  const float* __restrict__ Wk,
                                                  const float* __restrict__ Wo,
                                                  unsigned short* __restrict__ Tq,
                                                  unsigned short* __restrict__ Tk,
                                                  unsigned short* __restrict__ To) {
    __shared__ float T[64][65];
    const float* src = blockIdx.z == 0 ? Wq : (blockIdx.z == 1 ? Wk : Wo);
    unsigned short* dst = blockIdx.z == 0 ? Tq : (blockIdx.z == 1 ? Tk : To);
    const int tid = threadIdx.x;
    const int r0 = blockIdx.y * 64, c0 = blockIdx.x * 64;
#pragma unroll
    for (int p = 0; p < 4; ++p) {
        int idx = tid + 256 * p;
        int row = idx >> 4, c4 = idx & 15;
        float4 v = *reinterpret_cast<const float4*>(&src[(size_t)(r0 + row) * DD + c0 + c4 * 4]);
        T[row][c4 * 4 + 0] = v.x;
        T[row][c4 * 4 + 1] = v.y;
        T[row][c4 * 4 + 2] = v.z;
        T[row][c4 * 4 + 3] = v.w;
    }
    __syncthreads();
#pragma unroll
    for (int p = 0; p < 4; ++p) {
        int idx = tid + 256 * p;
        int orow = idx >> 4, oc4 = idx & 15;
        us4 o;
#pragma unroll
        for (int j = 0; j < 4; ++j) o[j] = f2h(T[oc4 * 4 + j][orow]);
        *reinterpret_cast<us4*>(&dst[(size_t)(c0 + orow) * DD + r0 + oc4 * 4]) = o;
    }
}

// ---------------- projection GEMM, fp16 MFMA, OPERAND-SWAPPED so the transposed
// [B,H,DEPTH,L] fp16 store is l-contiguous (32B segments, not 8B scatter) ----------------
// M-dim = c (Wt rows), N-dim = l (X rows): C[c][l] = sum_k Wt[c,k] X[l,k]
__global__ __launch_bounds__(256) void proj_gemm_mfma(const float* __restrict__ X,
                                                      const unsigned short* __restrict__ Wt,
                                                      const float* __restrict__ bias,
                                                      unsigned short* __restrict__ outT) {
    __shared__ unsigned short Asm[128][40];  // X tile: [l(row)][k]
    __shared__ unsigned short Bsm[128][40];  // Wt tile: [c(row)][k]
    const int tid = threadIdx.x;
    const int lane = tid & 63, wid = tid >> 6;
    const int wM = wid & 1, wN = wid >> 1;  // c-half, l-half
    const int g = lane >> 4, rl = lane & 15;
    const int r0 = blockIdx.y * 128, c0 = blockIdx.x * 128;
    f32x4 acc[4][4];
#pragma unroll
    for (int m = 0; m < 4; ++m)
#pragma unroll
        for (int n = 0; n < 4; ++n) acc[m][n] = (f32x4){0.f, 0.f, 0.f, 0.f};

    for (int k0 = 0; k0 < DD; k0 += 32) {
        float4 av[4];
#pragma unroll
        for (int p = 0; p < 4; ++p) {
            int idx = tid + 256 * p;
            int row = idx >> 3, kq = idx & 7;
            av[p] = *reinterpret_cast<const float4*>(&X[(size_t)(r0 + row) * DD + k0 + kq * 4]);
        }
        us8 bv[2];
#pragma unroll
        for (int p = 0; p < 2; ++p) {
            int idx = tid + 256 * p;
            int row = idx >> 2, kq = idx & 3;
            bv[p] = *reinterpret_cast<const us8*>(&Wt[(size_t)(c0 + row) * DD + k0 + kq * 8]);
        }
        __syncthreads();  // previous iteration's fragment reads done
#pragma unroll
        for (int p = 0; p < 4; ++p) {
            int idx = tid + 256 * p;
            int row = idx >> 3, kq = idx & 7;
            us4 w;
            w[0] = f2h(av[p].x); w[1] = f2h(av[p].y); w[2] = f2h(av[p].z); w[3] = f2h(av[p].w);
            *reinterpret_cast<us4*>(&Asm[row][kq * 4]) = w;
        }
#pragma unroll
        for (int p = 0; p < 2; ++p) {
            int idx = tid + 256 * p;
            int row = idx >> 2, kq = idx & 3;
            *reinterpret_cast<us8*>(&Bsm[row][kq * 8]) = bv[p];
        }
        __syncthreads();
        f16x8 af[4], bfr[4];
#pragma unroll
        for (int m = 0; m < 4; ++m)  // M = c from Wt tile
            af[m] = *reinterpret_cast<const f16x8*>(&Bsm[wM * 64 + m * 16 + rl][g * 8]);
#pragma unroll
        for (int n = 0; n < 4; ++n)  // N = l from X tile
            bfr[n] = *reinterpret_cast<const f16x8*>(&Asm[wN * 64 + n * 16 + rl][g * 8]);
#pragma unroll
        for (int m = 0; m < 4; ++m)
#pragma unroll
            for (int n = 0; n < 4; ++n)
                acc[m][n] = __builtin_amdgcn_mfma_f32_16x16x32_f16(af[m], bfr[n], acc[m][n], 0, 0, 0);
    }

    // epilogue: C row = c (M), col = l (N). Store scalar fp16; 16 consecutive rl
    // lanes cover 16 consecutive l -> 32B contiguous segments.
    const int b = r0 >> 11, l0 = r0 & (LL - 1);
#pragma unroll
    for (int m = 0; m < 4; ++m) {
        int cb = c0 + wM * 64 + m * 16 + g * 4;
        float4 bv4 = *reinterpret_cast<const float4*>(&bias[cb]);
        const float bja[4] = {bv4.x, bv4.y, bv4.z, bv4.w};
#pragma unroll
        for (int j = 0; j < 4; ++j) {
            int c = cb + j;
            int h = c >> 6, dd = c & 63;
            unsigned short* orow = &outT[((size_t)(b * HH + h) * DEPTH + dd) * LL];
#pragma unroll
            for (int n = 0; n < 4; ++n) {
                int l = l0 + wN * 64 + n * 16 + rl;
                orow[l] = f2h(acc[m][n][j] + bja[j]);
            }
        }
    }
}

// ---------------- correlation via FFT: fwd 2048 (packed q+ik), Hermitian combine,
// HALF-SIZE (1024) inverse via irfft packing; top-15; aggregation ----------------
// reads qt,kt fp16 rows; writes fp16 delays in-place over the kt row
__global__ __launch_bounds__(256) void corr_fft_v5(const unsigned short* __restrict__ qt,
                                                   unsigned short* __restrict__ kt) {
    __shared__ float zr[2112], zi[2112];  // 2048 + 64 pad
    __shared__ float q_s[NN];
    __shared__ float cand_v[64];
    __shared__ int cand_i[64];
    __shared__ float corr_s[TOPK];
    __shared__ int topi_s[TOPK];
    const int tid = threadIdx.x;
    const int lane = tid & 63, wid = tid >> 6;
    const size_t base = (size_t)blockIdx.x * NN;

#define LD2(i) make_float2(zr[i], zi[i])
#define ST2(i, v) do { zr[i] = (v).x; zi[i] = (v).y; } while (0)

    // ---- load 8 consecutive fp16 q,k per thread; cvt; q_s natural; bit-reversed scatter ----
    {
        us8 qa = *reinterpret_cast<const us8*>(qt + base + 8 * tid);
        us8 ka = *reinterpret_cast<const us8*>(kt + base + 8 * tid);
        f16x8 qh = __builtin_bit_cast(f16x8, qa);
        f16x8 kh = __builtin_bit_cast(f16x8, ka);
        float qv[8], kv[8];
#pragma unroll
        for (int u = 0; u < 8; ++u) { qv[u] = (float)qh[u]; kv[u] = (float)kh[u]; }
        *reinterpret_cast<float4*>(&q_s[8 * tid]) = make_float4(qv[0], qv[1], qv[2], qv[3]);
        *reinterpret_cast<float4*>(&q_s[8 * tid + 4]) = make_float4(qv[4], qv[5], qv[6], qv[7]);
        int pb = (int)(__brev((unsigned)tid) >> 24);  // brev8(tid)
        const int b3[8] = {0, 4, 2, 6, 1, 5, 3, 7};   // brev3(u)
#pragma unroll
        for (int u = 0; u < 8; ++u) {
            int pf = b3[u] * 256 + pb;  // = brev11(8*tid + u)
            zr[PD(pf)] = qv[u];
            zi[PD(pf)] = kv[u];
        }
    }
    __syncthreads();

    // ---- forward DIT (bit-reversed in -> natural out), quad passes (h, 2h) ----
#pragma unroll
    for (int hh = 1; hh <= 256; hh <<= 2) {
#pragma unroll
        for (int i2 = 0; i2 < 2; ++i2) {
            int q = tid + 256 * i2;
            int p = q & (hh - 1);
            int i0 = ((q ^ p) << 2) | p;
            int e0 = PD(i0), e1 = PD(i0 + hh), e2 = PD(i0 + 2 * hh), e3 = PD(i0 + 3 * hh);
            float2 a = LD2(e0), b = LD2(e1), c = LD2(e2), d = LD2(e3);
            float ang = -PIF * (float)p / (float)(2 * hh);
            float sn, cs;
            __sincosf(ang, &sn, &cs);
            float2 w2 = make_float2(cs, sn);
            float2 w1 = make_float2(cs * cs - sn * sn, 2.f * cs * sn);
            float2 bp = cmul(b, w1), dp = cmul(d, w1);
            float2 A0 = cadd(a, bp), A1 = csub(a, bp);
            float2 A2 = cadd(c, dp), A3 = csub(c, dp);
            float2 t2 = cmul(A2, w2);
            float2 u3 = cmul(A3, w2);
            float2 t3 = make_float2(u3.y, -u3.x);  // -i * u3
            ST2(e0, cadd(A0, t2));
            ST2(e2, csub(A0, t2));
            ST2(e1, cadd(A1, t3));
            ST2(e3, csub(A1, t3));
        }
        __syncthreads();
    }
    // single DIT stage h=1024 -> Z_f natural order
#pragma unroll
    for (int u = 0; u < 4; ++u) {
        int b4 = tid + 256 * u;
        int e0 = PD(b4), e1 = PD(b4 + 1024);
        float2 a = LD2(e0), c = LD2(e1);
        float ang = -PIF * (float)b4 * (1.f / 1024.f);
        float sn, cs;
        __sincosf(ang, &sn, &cs);
        float2 t = cmul(c, make_float2(cs, sn));
        ST2(e0, cadd(a, t));
        ST2(e1, csub(a, t));
    }
    __syncthreads();

    // ---- fused Hermitian unpack + S=Q*conj(K) + irfft E/O combine ----
    // W[m] = (S[m]+S[m+M]) + i*e^{+2pi i m/N}*(S[m]-S[m+M]);  R = IDFT_M(W)/(2N/2)... final scale 1/2048
    {
        float2 Wreg[4];
#pragma unroll
        for (int u = 0; u < 4; ++u) {
            int m = tid + 256 * u;
            // S[m]
            float2 S1, S2;
            {
                int f = m, mf = (NN - m) & (NN - 1);
                float2 Zf = LD2(PD(f)), Zm = LD2(PD(mf));
                float2 Qf = make_float2(0.5f * (Zf.x + Zm.x), 0.5f * (Zf.y - Zm.y));
                float2 Dm = make_float2(Zf.x - Zm.x, Zf.y + Zm.y);
                float2 Kf = make_float2(0.5f * Dm.y, -0.5f * Dm.x);
                S1 = cmulc(Qf, Kf);
            }
            // S[m + M]
            {
                int f = m + MM, mf = MM - m;  // (2048-(m+1024)) & 2047, m=0 -> 1024
                float2 Zf = LD2(PD(f)), Zm = LD2(PD(mf));
                float2 Qf = make_float2(0.5f * (Zf.x + Zm.x), 0.5f * (Zf.y - Zm.y));
                float2 Dm = make_float2(Zf.x - Zm.x, Zf.y + Zm.y);
                float2 Kf = make_float2(0.5f * Dm.y, -0.5f * Dm.x);
                S2 = cmulc(Qf, Kf);
            }
            float2 E = cadd(S1, S2);
            float2 Od = csub(S1, S2);
            float ang = PIF * (float)m * (1.f / 1024.f);  // +2*pi*m/N
            float sn, cs;
            __sincosf(ang, &sn, &cs);
            float2 T = cmul(make_float2(cs, sn), Od);
            Wreg[u] = make_float2(E.x - T.y, E.y + T.x);  // E + i*T
        }
        __syncthreads();
#pragma unroll
        for (int u = 0; u < 4; ++u) ST2(PD(tid + 256 * u), Wreg[u]);
        __syncthreads();
    }

    // ---- inverse DIF, 1024-point (natural in -> bit-reversed out), quad passes.
    // hh = 256,64,16,4 in LDS; hh=1 (radix-4, no twiddle) lands in registers. ----
#pragma unroll
    for (int hh = 256; hh >= 4; hh >>= 2) {
        int q = tid;
        int p = q & (hh - 1);
        int i0 = ((q ^ p) << 2) | p;
        int e0 = PD(i0), e1 = PD(i0 + hh), e2 = PD(i0 + 2 * hh), e3 = PD(i0 + 3 * hh);
        float2 a = LD2(e0), b = LD2(e1), c = LD2(e2), d = LD2(e3);
        float ang = PIF * (float)p / (float)(2 * hh);
        float sn, cs;
        __sincosf(ang, &sn, &cs);
        float2 w = make_float2(cs, sn);
        float2 w2 = make_float2(cs * cs - sn * sn, 2.f * cs * sn);
        float2 S0 = cadd(a, c);
        float2 D0 = cmul(csub(a, c), w);
        float2 S1 = cadd(b, d);
        float2 f2 = cmul(csub(b, d), w);
        float2 D1 = make_float2(-f2.y, f2.x);  // i * f2
        ST2(e0, cadd(S0, S1));
        ST2(e1, cmul(csub(S0, S1), w2));
        ST2(e2, cadd(D0, D1));
        ST2(e3, cmul(csub(D0, D1), w2));
        __syncthreads();
    }
    // hh=1: slots 4*tid..4*tid+3, pure radix-4, keep in registers.
    // slot s holds z[brev10(s)]; z[m] = R[2m] + i*R[2m+1] (after 1/2048 scale)
    float r[8];
    int tau[8];
    {
        float2 a = LD2(PD(4 * tid)), b = LD2(PD(4 * tid + 1));
        float2 c = LD2(PD(4 * tid + 2)), d = LD2(PD(4 * tid + 3));
        float2 S0 = cadd(a, c), D0 = csub(a, c);
        float2 S1 = cadd(b, d);
        float2 bd = csub(b, d);
        float2 D1 = make_float2(-bd.y, bd.x);  // i*(b-d)
        float2 z[4];
        z[0] = cadd(S0, S1);   // s = 4t+0
        z[1] = csub(S0, S1);   // s = 4t+1
        z[2] = cadd(D0, D1);   // s = 4t+2
        z[3] = csub(D0, D1);   // s = 4t+3
        const int pb = (int)(__brev((unsigned)tid) >> 24);  // brev8(tid)
        const int b2[4] = {0, 2, 1, 3};                     // brev2(v)
        const float sc = 1.0f / (float)NN;
#pragma unroll
        for (int v = 0; v < 4; ++v) {
            int m = b2[v] * 256 + pb;  // brev10(4*tid+v)
            r[2 * v] = z[v].x * sc;
            tau[2 * v] = 2 * m;
            r[2 * v + 1] = z[v].y * sc;
            tau[2 * v + 1] = 2 * m + 1;
        }
    }

    // ---- per-wave top-15 (shfl only), then single merge ----
    for (int it = 0; it < TOPK; ++it) {
        float best = -FLT_MAX;
        int bi = 0x7fffffff;
#pragma unroll
        for (int w = 0; w < 8; ++w) {
            if (r[w] > best || (r[w] == best && tau[w] < bi)) { best = r[w]; bi = tau[w]; }
        }
#pragma unroll
        for (int off = 32; off >= 1; off >>= 1) {
            float ov = __shfl_xor(best, off);
            int oi = __shfl_xor(bi, off);
            if (ov > best || (ov == best && oi < bi)) { best = ov; bi = oi; }
        }
        if (lane == 0) { cand_v[wid * 16 + it] = best; cand_i[wid * 16 + it] = bi; }
#pragma unroll
        for (int w = 0; w < 8; ++w)
            if (tau[w] == bi) r[w] = -FLT_MAX;
    }
    __syncthreads();
    if (tid == 0) {
        int head[4] = {0, 0, 0, 0};
        float w15[TOPK];
        int i15[TOPK];
        for (int it = 0; it < TOPK; ++it) {
            float bw = -FLT_MAX;
            int bi = 0x7fffffff, bs = 0;
            for (int s = 0; s < 4; ++s) {
                if (head[s] < TOPK) {
                    float v = cand_v[s * 16 + head[s]];
                    int ii = cand_i[s * 16 + head[s]];
                    if (v > bw || (v == bw && ii < bi)) { bw = v; bi = ii; bs = s; }
                }
            }
            head[bs]++;
            w15[it] = bw;
            i15[it] = bi;
        }
        float m = w15[0];
        for (int i = 1; i < TOPK; ++i) m = fmaxf(m, w15[i]);
        float ssum = 0.f;
        for (int i = 0; i < TOPK; ++i) {
            float e = expf(w15[i] - m);
            corr_s[i] = e;
            ssum += e;
        }
        float inv = 1.f / ssum;
        for (int i = 0; i < TOPK; ++i) { corr_s[i] *= inv; topi_s[i] = i15[i]; }
    }
    __syncthreads();

    // ---- aggregation: lane-consecutive scalar reads (conflict-free), fp16 scalar stores ----
    {
        float cw[TOPK];
        int ci[TOPK];
#pragma unroll
        for (int i = 0; i < TOPK; ++i) { cw[i] = corr_s[i]; ci[i] = topi_s[i]; }
#pragma unroll
        for (int u = 0; u < 8; ++u) {
            int t = tid + 256 * u;
            float acc = 0.f;
#pragma unroll
            for (int i = 0; i < TOPK; ++i) acc += cw[i] * q_s[(t + ci[i]) & (NN - 1)];
            kt[base + t] = f2h(acc);
        }
    }
#undef LD2
#undef ST2
}

// ---------------- output GEMM, fp16 MFMA: out[r,c] = sum_k delays[b,k,l]*Wo[k,c] + bo[c] ----------------
// delays fp16 rows at kt + (b*512+k)*2048;  WtO[c][k] = Wo[k][c]
__global__ __launch_bounds__(256) void out_gemm_mfma(const unsigned short* __restrict__ db,
                                                     const unsigned short* __restrict__ WtO,
                                                     const float* __restrict__ bias,
                                                     float* __restrict__ out) {
    __shared__ unsigned short Asm[32][132];  // [k][l], stride 132 -> 4-way max on u16 extract
    __shared__ unsigned short Bsm[128][40];  // [c][k] padded
    const int tid = threadIdx.x;
    const int lane = tid & 63, wid = tid >> 6;
    const int wr = wid >> 1, wc = wid & 1;
    const int g = lane >> 4, rl = lane & 15;
    const int r0 = blockIdx.y * 128, c0 = blockIdx.x * 128;
    const int b = r0 >> 11, l0 = r0 & (LL - 1);
    f32x4 acc[4][4];
#pragma unroll
    for (int m = 0; m < 4; ++m)
#pragma unroll
        for (int n = 0; n < 4; ++n) acc[m][n] = (f32x4){0.f, 0.f, 0.f, 0.f};

    for (int k0 = 0; k0 < DD; k0 += 32) {
        us8 avv[2], bvv[2];
#pragma unroll
        for (int p = 0; p < 2; ++p) {
            int idx = tid + 256 * p;
            int kr = idx >> 4, dc = idx & 15;
            avv[p] = *reinterpret_cast<const us8*>(
                &db[(size_t)(b * DD + k0 + kr) * 2048 + l0 + dc * 8]);
        }
#pragma unroll
        for (int p = 0; p < 2; ++p) {
            int idx = tid + 256 * p;
            int row = idx >> 2, kq = idx & 3;
            bvv[p] = *reinterpret_cast<const us8*>(&WtO[(size_t)(c0 + row) * DD + k0 + kq * 8]);
        }
        __syncthreads();
#pragma unroll
        for (int p = 0; p < 2; ++p) {
            int idx = tid + 256 * p;
            int kr = idx >> 4, dc = idx & 15;
            us4 lo, hi;
#pragma unroll
            for (int j = 0; j < 4; ++j) { lo[j] = avv[p][j]; hi[j] = avv[p][j + 4]; }
            *reinterpret_cast<us4*>(&Asm[kr][dc * 8]) = lo;
            *reinterpret_cast<us4*>(&Asm[kr][dc * 8 + 4]) = hi;
        }
#pragma unroll
        for (int p = 0; p < 2; ++p) {
            int idx = tid + 256 * p;
            int row = idx >> 2, kq = idx & 3;
            *reinterpret_cast<us8*>(&Bsm[row][kq * 8]) = bvv[p];
        }
        __syncthreads();
        f16x8 af[4], bfr[4];
#pragma unroll
        for (int m = 0; m < 4; ++m) {
            int l = wr * 64 + m * 16 + rl;
            us8 t;
#pragma unroll
            for (int j = 0; j < 8; ++j) t[j] = Asm[g * 8 + j][l];
            af[m] = __builtin_bit_cast(f16x8, t);
        }
#pragma unroll
        for (int n = 0; n < 4; ++n)
            bfr[n] = *reinterpret_cast<const f16x8*>(&Bsm[wc * 64 + n * 16 + rl][g * 8]);
#pragma unroll
        for (int m = 0; m < 4; ++m)
#pragma unroll
            for (int n = 0; n < 4; ++n)
                acc[m][n] = __builtin_amdgcn_mfma_f32_16x16x32_f16(af[m], bfr[n], acc[m][n], 0, 0, 0);
    }

#pragma unroll
    for (int m = 0; m < 4; ++m) {
#pragma unroll
        for (int n = 0; n < 4; ++n) {
            int c = c0 + wc * 64 + n * 16 + rl;
            float bvv = bias[c];
            int rbase = r0 + wr * 64 + m * 16 + g * 4;
#pragma unroll
            for (int j = 0; j < 4; ++j)
                out[(size_t)(rbase + j) * DD + c] = acc[m][n][j] + bvv;
        }
    }
}

extern "C" void kernel_launch(void* const* d_in, const int* in_sizes, int n_in,
                              void* d_out, int out_size, void* d_ws, size_t ws_size,
                              hipStream_t stream) {
    const float* q = (const float*)d_in[0];
    const float* k = (const float*)d_in[1];
    const float* Wq = (const float*)d_in[3];
    const float* bq = (const float*)d_in[4];
    const float* Wk = (const float*)d_in[5];
    const float* bk = (const float*)d_in[6];
    const float* Wo = (const float*)d_in[9];
    const float* bo = (const float*)d_in[10];
    float* out = (float*)d_out;

    unsigned short* qt = (unsigned short*)d_ws;                 // [B,H,DEPTH,L] fp16, 16.8MB
    unsigned short* kt = qt + (size_t)BB * HH * DEPTH * LL;     // [B,H,DEPTH,L] fp16; delays in-place
    unsigned short* Tq = kt + (size_t)BB * HH * DEPTH * LL;
    unsigned short* Tk = Tq + (size_t)DD * DD;
    unsigned short* To = Tk + (size_t)DD * DD;

    dim3 blk(256);
    wt_convert<<<dim3(8, 8, 3), blk, 0, stream>>>(Wq, Wk, Wo, Tq, Tk, To);
    proj_gemm_mfma<<<dim3(4, 128), blk, 0, stream>>>(q, Tq, bq, qt);
    proj_gemm_mfma<<<dim3(4, 128), blk, 0, stream>>>(k, Tk, bk, kt);
    corr_fft_v5<<<dim3(BB * HH * DEPTH), blk, 0, stream>>>(qt, kt);
    out_gemm_mfma<<<dim3(4, 128), blk, 0, stream>>>(kt, To, bo, out);
}

// Round 8
// 179.711 us; speedup vs baseline: 1.9402x; 1.0160x over previous
//
#include <hip/hip_runtime.h>
#include <hip/hip_fp16.h>
#include <float.h>
#include <math.h>

#define BB 8
#define LL 2048
#define NN 2048
#define MM 1024
#define DD 512
#define HH 8
#define DEPTH 64
#define TOPK 15
#define PIF 3.14159265358979323846f

// padded index for zr/zi/twr/twi: +1 float per 32 -> breaks power-of-2 bank aliasing
#define PD(i) ((i) + ((i) >> 5))

using f16x8 = __attribute__((ext_vector_type(8))) _Float16;
typedef __attribute__((ext_vector_type(4))) float f32x4;
typedef __attribute__((ext_vector_type(8))) unsigned short us8;
typedef __attribute__((ext_vector_type(4))) unsigned short us4;

__device__ __forceinline__ unsigned short f2h(float f) {
    return __half_as_ushort(__float2half(f));  // RNE
}
__device__ __forceinline__ float h2f(unsigned short u) {
    return (float)__builtin_bit_cast(_Float16, u);
}
__device__ __forceinline__ float2 cmul(float2 a, float2 b) {
    return make_float2(a.x * b.x - a.y * b.y, a.x * b.y + a.y * b.x);
}
__device__ __forceinline__ float2 cmulc(float2 a, float2 b) {  // a * conj(b)
    return make_float2(a.x * b.x + a.y * b.y, a.y * b.x - a.x * b.y);
}
__device__ __forceinline__ float2 cadd(float2 a, float2 b) { return make_float2(a.x + b.x, a.y + b.y); }
__device__ __forceinline__ float2 csub(float2 a, float2 b) { return make_float2(a.x - b.x, a.y - b.y); }

// ---------------- W transpose + fp32->fp16 convert (once per call) ----------------
__global__ __launch_bounds__(256) void wt_convert(const float* __restrict__ Wq,
                                                  const float* __restrict__ Wk,
                                                  const float* __restrict__ Wo,
                                                  unsigned short* __restrict__ Tq,
                                                  unsigned short* __restrict__ Tk,
                                                  unsigned short* __restrict__ To) {
    __shared__ float T[64][65];
    const float* src = blockIdx.z == 0 ? Wq : (blockIdx.z == 1 ? Wk : Wo);
    unsigned short* dst = blockIdx.z == 0 ? Tq : (blockIdx.z == 1 ? Tk : To);
    const int tid = threadIdx.x;
    const int r0 = blockIdx.y * 64, c0 = blockIdx.x * 64;
#pragma unroll
    for (int p = 0; p < 4; ++p) {
        int idx = tid + 256 * p;
        int row = idx >> 4, c4 = idx & 15;
        float4 v = *reinterpret_cast<const float4*>(&src[(size_t)(r0 + row) * DD + c0 + c4 * 4]);
        T[row][c4 * 4 + 0] = v.x;
        T[row][c4 * 4 + 1] = v.y;
        T[row][c4 * 4 + 2] = v.z;
        T[row][c4 * 4 + 3] = v.w;
    }
    __syncthreads();
#pragma unroll
    for (int p = 0; p < 4; ++p) {
        int idx = tid + 256 * p;
        int orow = idx >> 4, oc4 = idx & 15;
        us4 o;
#pragma unroll
        for (int j = 0; j < 4; ++j) o[j] = f2h(T[oc4 * 4 + j][orow]);
        *reinterpret_cast<us4*>(&dst[(size_t)(c0 + orow) * DD + r0 + oc4 * 4]) = o;
    }
}

// ---------------- projection GEMM, fp16 MFMA, OPERAND-SWAPPED (l-contiguous stores) ----------------
__global__ __launch_bounds__(256) void proj_gemm_mfma(const float* __restrict__ X,
                                                      const unsigned short* __restrict__ Wt,
                                                      const float* __restrict__ bias,
                                                      unsigned short* __restrict__ outT) {
    __shared__ unsigned short Asm[128][40];  // X tile: [l(row)][k]
    __shared__ unsigned short Bsm[128][40];  // Wt tile: [c(row)][k]
    const int tid = threadIdx.x;
    const int lane = tid & 63, wid = tid >> 6;
    const int wM = wid & 1, wN = wid >> 1;  // c-half, l-half
    const int g = lane >> 4, rl = lane & 15;
    const int r0 = blockIdx.y * 128, c0 = blockIdx.x * 128;
    f32x4 acc[4][4];
#pragma unroll
    for (int m = 0; m < 4; ++m)
#pragma unroll
        for (int n = 0; n < 4; ++n) acc[m][n] = (f32x4){0.f, 0.f, 0.f, 0.f};

    for (int k0 = 0; k0 < DD; k0 += 32) {
        float4 av[4];
#pragma unroll
        for (int p = 0; p < 4; ++p) {
            int idx = tid + 256 * p;
            int row = idx >> 3, kq = idx & 7;
            av[p] = *reinterpret_cast<const float4*>(&X[(size_t)(r0 + row) * DD + k0 + kq * 4]);
        }
        us8 bv[2];
#pragma unroll
        for (int p = 0; p < 2; ++p) {
            int idx = tid + 256 * p;
            int row = idx >> 2, kq = idx & 3;
            bv[p] = *reinterpret_cast<const us8*>(&Wt[(size_t)(c0 + row) * DD + k0 + kq * 8]);
        }
        __syncthreads();
#pragma unroll
        for (int p = 0; p < 4; ++p) {
            int idx = tid + 256 * p;
            int row = idx >> 3, kq = idx & 7;
            us4 w;
            w[0] = f2h(av[p].x); w[1] = f2h(av[p].y); w[2] = f2h(av[p].z); w[3] = f2h(av[p].w);
            *reinterpret_cast<us4*>(&Asm[row][kq * 4]) = w;
        }
#pragma unroll
        for (int p = 0; p < 2; ++p) {
            int idx = tid + 256 * p;
            int row = idx >> 2, kq = idx & 3;
            *reinterpret_cast<us8*>(&Bsm[row][kq * 8]) = bv[p];
        }
        __syncthreads();
        f16x8 af[4], bfr[4];
#pragma unroll
        for (int m = 0; m < 4; ++m)  // M = c from Wt tile
            af[m] = *reinterpret_cast<const f16x8*>(&Bsm[wM * 64 + m * 16 + rl][g * 8]);
#pragma unroll
        for (int n = 0; n < 4; ++n)  // N = l from X tile
            bfr[n] = *reinterpret_cast<const f16x8*>(&Asm[wN * 64 + n * 16 + rl][g * 8]);
#pragma unroll
        for (int m = 0; m < 4; ++m)
#pragma unroll
            for (int n = 0; n < 4; ++n)
                acc[m][n] = __builtin_amdgcn_mfma_f32_16x16x32_f16(af[m], bfr[n], acc[m][n], 0, 0, 0);
    }

    const int b = r0 >> 11, l0 = r0 & (LL - 1);
#pragma unroll
    for (int m = 0; m < 4; ++m) {
        int cb = c0 + wM * 64 + m * 16 + g * 4;
        float4 bv4 = *reinterpret_cast<const float4*>(&bias[cb]);
        const float bja[4] = {bv4.x, bv4.y, bv4.z, bv4.w};
#pragma unroll
        for (int j = 0; j < 4; ++j) {
            int c = cb + j;
            int h = c >> 6, dd = c & 63;
            unsigned short* orow = &outT[((size_t)(b * HH + h) * DEPTH + dd) * LL];
#pragma unroll
            for (int n = 0; n < 4; ++n) {
                int l = l0 + wN * 64 + n * 16 + rl;
                orow[l] = f2h(acc[m][n][j] + bja[j]);
            }
        }
    }
}

// ---------------- correlation via FFT v6: LDS twiddle table, register radix-8 fwd tail,
// fused combine+first-inverse-quad, half-size inverse, global-read aggregation ----------------
__global__ __launch_bounds__(256) void corr_fft_v6(const unsigned short* __restrict__ qt,
                                                   unsigned short* __restrict__ kt) {
    __shared__ float zr[2112], zi[2112];   // 2048 + pad
    __shared__ float twr[1056], twi[1056]; // tw[j] = exp(-i*pi*j/1024), PD-padded
    __shared__ float cand_v[64];
    __shared__ int cand_i[64];
    __shared__ float corr_s[TOPK];
    __shared__ int topi_s[TOPK];
    const int tid = threadIdx.x;
    const int lane = tid & 63, wid = tid >> 6;
    const size_t base = (size_t)blockIdx.x * NN;

#define LD2(i) make_float2(zr[i], zi[i])
#define ST2(i, v) do { zr[i] = (v).x; zi[i] = (v).y; } while (0)

    // ---- load 8 consecutive fp16 q,k; bit-reversed scatter; twiddle table init ----
    {
        us8 qa = *reinterpret_cast<const us8*>(qt + base + 8 * tid);
        us8 ka = *reinterpret_cast<const us8*>(kt + base + 8 * tid);
        f16x8 qh = __builtin_bit_cast(f16x8, qa);
        f16x8 kh = __builtin_bit_cast(f16x8, ka);
        int pb = (int)(__brev((unsigned)tid) >> 24);  // brev8(tid)
        const int b3[8] = {0, 4, 2, 6, 1, 5, 3, 7};   // brev3(u)
#pragma unroll
        for (int u = 0; u < 8; ++u) {
            int pf = b3[u] * 256 + pb;  // = brev11(8*tid + u)
            zr[PD(pf)] = (float)qh[u];
            zi[PD(pf)] = (float)kh[u];
        }
#pragma unroll
        for (int v = 0; v < 4; ++v) {
            int j = tid + 256 * v;
            float sn, cs;
            __sincosf(-PIF * (float)j * (1.f / 1024.f), &sn, &cs);
            twr[PD(j)] = cs;
            twi[PD(j)] = sn;
        }
    }
    __syncthreads();

    // ---- forward DIT: hh=1 quad (twiddle-free), hh=4,16,64 quads (table), reg radix-8 tail ----
#pragma unroll
    for (int i2 = 0; i2 < 2; ++i2) {  // stages 1,2: w1=w2=1
        int q = tid + 256 * i2;
        int i0 = q << 2;
        int e0 = PD(i0), e1 = PD(i0 + 1), e2 = PD(i0 + 2), e3 = PD(i0 + 3);
        float2 a = LD2(e0), b = LD2(e1), c = LD2(e2), d = LD2(e3);
        float2 A0 = cadd(a, b), A1 = csub(a, b), A2 = cadd(c, d), A3 = csub(c, d);
        float2 t3 = make_float2(A3.y, -A3.x);  // -i*A3
        ST2(e0, cadd(A0, A2));
        ST2(e2, csub(A0, A2));
        ST2(e1, cadd(A1, t3));
        ST2(e3, csub(A1, t3));
    }
    __syncthreads();
#pragma unroll
    for (int hh = 4; hh <= 64; hh <<= 2) {
        const int step = 512 / hh;  // 128, 32, 8
#pragma unroll
        for (int i2 = 0; i2 < 2; ++i2) {
            int q = tid + 256 * i2;
            int p = q & (hh - 1);
            int i0 = ((q ^ p) << 2) | p;
            int e0 = PD(i0), e1 = PD(i0 + hh), e2 = PD(i0 + 2 * hh), e3 = PD(i0 + 3 * hh);
            float2 a = LD2(e0), b = LD2(e1), c = LD2(e2), d = LD2(e3);
            int jt = PD(p * step);
            float2 w2 = make_float2(twr[jt], twi[jt]);
            float2 w1 = make_float2(w2.x * w2.x - w2.y * w2.y, 2.f * w2.x * w2.y);
            float2 bp = cmul(b, w1), dp = cmul(d, w1);
            float2 A0 = cadd(a, bp), A1 = csub(a, bp);
            float2 A2 = cadd(c, dp), A3 = csub(c, dp);
            float2 t2 = cmul(A2, w2);
            float2 u3 = cmul(A3, w2);
            float2 t3 = make_float2(u3.y, -u3.x);  // -i*u3
            ST2(e0, cadd(A0, t2));
            ST2(e2, csub(A0, t2));
            ST2(e1, cadd(A1, t3));
            ST2(e3, csub(A1, t3));
        }
        __syncthreads();
    }
    // register radix-8 tail: stages 256,512,1024 on the closed set {tid+256u}
    {
        float2 z[8];
#pragma unroll
        for (int u = 0; u < 8; ++u) z[u] = LD2(PD(tid + 256 * u));
        {  // stage h=256: pairs (2a,2a+1), w = tw[4*tid]
            int j = PD(4 * tid);
            float2 wa = make_float2(twr[j], twi[j]);
#pragma unroll
            for (int a2 = 0; a2 < 4; ++a2) {
                float2 tv = cmul(z[2 * a2 + 1], wa);
                z[2 * a2 + 1] = csub(z[2 * a2], tv);
                z[2 * a2] = cadd(z[2 * a2], tv);
            }
        }
        {  // stage h=512: pairs (0,2),(1,3),(4,6),(5,7); odd-u pairs get extra *(-i)
            int j = PD(2 * tid);
            float2 wb = make_float2(twr[j], twi[j]);
            float2 wbn = make_float2(wb.y, -wb.x);  // -i*wb
#pragma unroll
            for (int kk = 0; kk < 4; ++kk) {
                const int u0a[4] = {0, 1, 4, 5};
                int u0 = u0a[kk];
                float2 w = (kk & 1) ? wbn : wb;
                float2 tv = cmul(z[u0 + 2], w);
                z[u0 + 2] = csub(z[u0], tv);
                z[u0] = cadd(z[u0], tv);
            }
        }
        {  // stage h=1024: pairs (u,u+4), w = tw[tid]*omega^u, omega=e^{-i*pi/4}
            int j = PD(tid);
            float2 wc = make_float2(twr[j], twi[j]);
            const float R2 = 0.70710678118654752f;
            float2 wt0 = wc;
            float2 wt1 = cmul(wc, make_float2(R2, -R2));
            float2 wt2 = make_float2(wc.y, -wc.x);  // wc*(-i)
            float2 wt3 = cmul(wc, make_float2(-R2, -R2));
            float2 tv;
            tv = cmul(z[4], wt0); z[4] = csub(z[0], tv); z[0] = cadd(z[0], tv);
            tv = cmul(z[5], wt1); z[5] = csub(z[1], tv); z[1] = cadd(z[1], tv);
            tv = cmul(z[6], wt2); z[6] = csub(z[2], tv); z[2] = cadd(z[2], tv);
            tv = cmul(z[7], wt3); z[7] = csub(z[3], tv); z[3] = cadd(z[3], tv);
        }
#pragma unroll
        for (int u = 0; u < 8; ++u) ST2(PD(tid + 256 * u), z[u]);
    }
    __syncthreads();

    // ---- FUSED: Hermitian unpack + S=Q*conj(K) + irfft E/O combine + inverse quad hh=256 ----
    {
        float2 W[4];
#pragma unroll
        for (int u = 0; u < 4; ++u) {
            int m = tid + 256 * u;
            int mf1 = (NN - m) & (NN - 1);
            float2 Zf = LD2(PD(m)), Zm = LD2(PD(mf1));
            float2 Qf = make_float2(0.5f * (Zf.x + Zm.x), 0.5f * (Zf.y - Zm.y));
            float2 Dm = make_float2(Zf.x - Zm.x, Zf.y + Zm.y);
            float2 Kf = make_float2(0.5f * Dm.y, -0.5f * Dm.x);
            float2 S1 = cmulc(Qf, Kf);
            float2 Zf2 = LD2(PD(m + MM)), Zm2 = LD2(PD(MM - m));
            float2 Qf2 = make_float2(0.5f * (Zf2.x + Zm2.x), 0.5f * (Zf2.y - Zm2.y));
            float2 Dm2 = make_float2(Zf2.x - Zm2.x, Zf2.y + Zm2.y);
            float2 Kf2 = make_float2(0.5f * Dm2.y, -0.5f * Dm2.x);
            float2 S2 = cmulc(Qf2, Kf2);
            float2 E = cadd(S1, S2), Od = csub(S1, S2);
            int jm = PD(m);
            float2 ph = make_float2(twr[jm], -twi[jm]);  // e^{+i*pi*m/1024}
            float2 T = cmul(ph, Od);
            W[u] = make_float2(E.x - T.y, E.y + T.x);  // E + i*T
        }
        // inverse DIF quad hh=256 on W (p = tid): w = conj(tw[2*tid]), w2 = w*w
        int j = PD(2 * tid);
        float2 w = make_float2(twr[j], -twi[j]);
        float2 w2 = make_float2(w.x * w.x - w.y * w.y, 2.f * w.x * w.y);
        float2 S0 = cadd(W[0], W[2]);
        float2 D0 = cmul(csub(W[0], W[2]), w);
        float2 S1q = cadd(W[1], W[3]);
        float2 ff = cmul(csub(W[1], W[3]), w);
        float2 D1 = make_float2(-ff.y, ff.x);  // i*ff
        float2 o0 = cadd(S0, S1q);
        float2 o1 = cmul(csub(S0, S1q), w2);
        float2 o2 = cadd(D0, D1);
        float2 o3 = cmul(csub(D0, D1), w2);
        __syncthreads();  // all Z reads done before overwriting
        ST2(PD(tid), o0);
        ST2(PD(tid + 256), o1);
        ST2(PD(tid + 512), o2);
        ST2(PD(tid + 768), o3);
    }
    __syncthreads();

    // ---- inverse DIF quads hh=64,16,4 (1024-pt, table twiddles) ----
#pragma unroll
    for (int hh = 64; hh >= 4; hh >>= 2) {
        const int step = 512 / hh;  // 8, 32, 128
        int q = tid;
        int p = q & (hh - 1);
        int i0 = ((q ^ p) << 2) | p;
        int e0 = PD(i0), e1 = PD(i0 + hh), e2 = PD(i0 + 2 * hh), e3 = PD(i0 + 3 * hh);
        float2 a = LD2(e0), b = LD2(e1), c = LD2(e2), d = LD2(e3);
        int jt = PD(p * step);
        float2 w = make_float2(twr[jt], -twi[jt]);
        float2 w2 = make_float2(w.x * w.x - w.y * w.y, 2.f * w.x * w.y);
        float2 S0 = cadd(a, c);
        float2 D0 = cmul(csub(a, c), w);
        float2 S1 = cadd(b, d);
        float2 ff = cmul(csub(b, d), w);
        float2 D1 = make_float2(-ff.y, ff.x);
        ST2(e0, cadd(S0, S1));
        ST2(e1, cmul(csub(S0, S1), w2));
        ST2(e2, cadd(D0, D1));
        ST2(e3, cmul(csub(D0, D1), w2));
        __syncthreads();
    }
    // hh=1: slots 4*tid..4*tid+3, pure radix-4 in registers.
    float r[8];
    int tau[8];
    {
        float2 a = LD2(PD(4 * tid)), b = LD2(PD(4 * tid + 1));
        float2 c = LD2(PD(4 * tid + 2)), d = LD2(PD(4 * tid + 3));
        float2 S0 = cadd(a, c), D0 = csub(a, c);
        float2 S1 = cadd(b, d);
        float2 bd = csub(b, d);
        float2 D1 = make_float2(-bd.y, bd.x);  // i*(b-d)
        float2 z0 = cadd(S0, S1);
        float2 z1 = csub(S0, S1);
        float2 z2 = cadd(D0, D1);
        float2 z3 = csub(D0, D1);
        const int pb = (int)(__brev((unsigned)tid) >> 24);  // brev8(tid)
        const float sc = 1.0f / (float)NN;
        int m0 = pb;         // brev2(0)=0
        int m1 = 512 + pb;   // brev2(1)=2
        int m2 = 256 + pb;   // brev2(2)=1
        int m3 = 768 + pb;   // brev2(3)=3
        r[0] = z0.x * sc; tau[0] = 2 * m0;
        r[1] = z0.y * sc; tau[1] = 2 * m0 + 1;
        r[2] = z1.x * sc; tau[2] = 2 * m1;
        r[3] = z1.y * sc; tau[3] = 2 * m1 + 1;
        r[4] = z2.x * sc; tau[4] = 2 * m2;
        r[5] = z2.y * sc; tau[5] = 2 * m2 + 1;
        r[6] = z3.x * sc; tau[6] = 2 * m3;
        r[7] = z3.y * sc; tau[7] = 2 * m3 + 1;
    }

    // ---- per-wave top-15 (shfl only), then single merge ----
    for (int it = 0; it < TOPK; ++it) {
        float best = -FLT_MAX;
        int bi = 0x7fffffff;
#pragma unroll
        for (int w = 0; w < 8; ++w) {
            if (r[w] > best || (r[w] == best && tau[w] < bi)) { best = r[w]; bi = tau[w]; }
        }
#pragma unroll
        for (int off = 32; off >= 1; off >>= 1) {
            float ov = __shfl_xor(best, off);
            int oi = __shfl_xor(bi, off);
            if (ov > best || (ov == best && oi < bi)) { best = ov; bi = oi; }
        }
        if (lane == 0) { cand_v[wid * 16 + it] = best; cand_i[wid * 16 + it] = bi; }
#pragma unroll
        for (int w = 0; w < 8; ++w)
            if (tau[w] == bi) r[w] = -FLT_MAX;
    }
    __syncthreads();
    if (tid == 0) {
        int head[4] = {0, 0, 0, 0};
        float w15[TOPK];
        int i15[TOPK];
        for (int it = 0; it < TOPK; ++it) {
            float bw = -FLT_MAX;
            int bi = 0x7fffffff, bs = 0;
            for (int s = 0; s < 4; ++s) {
                if (head[s] < TOPK) {
                    float v = cand_v[s * 16 + head[s]];
                    int ii = cand_i[s * 16 + head[s]];
                    if (v > bw || (v == bw && ii < bi)) { bw = v; bi = ii; bs = s; }
                }
            }
            head[bs]++;
            w15[it] = bw;
            i15[it] = bi;
        }
        float m = w15[0];
        for (int i = 1; i < TOPK; ++i) m = fmaxf(m, w15[i]);
        float ssum = 0.f;
        for (int i = 0; i < TOPK; ++i) {
            float e = expf(w15[i] - m);
            corr_s[i] = e;
            ssum += e;
        }
        float inv = 1.f / ssum;
        for (int i = 0; i < TOPK; ++i) { corr_s[i] *= inv; topi_s[i] = i15[i]; }
    }
    __syncthreads();

    // ---- aggregation: re-read the 4KB qt row from global (L1/L2-resident, coalesced) ----
    {
        float cw[TOPK];
        int ci[TOPK];
#pragma unroll
        for (int i = 0; i < TOPK; ++i) { cw[i] = corr_s[i]; ci[i] = topi_s[i]; }
        const unsigned short* qrow = qt + base;
#pragma unroll
        for (int u = 0; u < 8; ++u) {
            int t = tid + 256 * u;
            float acc = 0.f;
#pragma unroll
            for (int i = 0; i < TOPK; ++i)
                acc += cw[i] * h2f(qrow[(t + ci[i]) & (NN - 1)]);
            kt[base + t] = f2h(acc);
        }
    }
#undef LD2
#undef ST2
}

// ---------------- output GEMM, fp16 MFMA (unchanged from R7) ----------------
__global__ __launch_bounds__(256) void out_gemm_mfma(const unsigned short* __restrict__ db,
                                                     const unsigned short* __restrict__ WtO,
                                                     const float* __restrict__ bias,
                                                     float* __restrict__ out) {
    __shared__ unsigned short Asm[32][132];
    __shared__ unsigned short Bsm[128][40];
    const int tid = threadIdx.x;
    const int lane = tid & 63, wid = tid >> 6;
    const int wr = wid >> 1, wc = wid & 1;
    const int g = lane >> 4, rl = lane & 15;
    const int r0 = blockIdx.y * 128, c0 = blockIdx.x * 128;
    const int b = r0 >> 11, l0 = r0 & (LL - 1);
    f32x4 acc[4][4];
#pragma unroll
    for (int m = 0; m < 4; ++m)
#pragma unroll
        for (int n = 0; n < 4; ++n) acc[m][n] = (f32x4){0.f, 0.f, 0.f, 0.f};

    for (int k0 = 0; k0 < DD; k0 += 32) {
        us8 avv[2], bvv[2];
#pragma unroll
        for (int p = 0; p < 2; ++p) {
            int idx = tid + 256 * p;
            int kr = idx >> 4, dc = idx & 15;
            avv[p] = *reinterpret_cast<const us8*>(
                &db[(size_t)(b * DD + k0 + kr) * 2048 + l0 + dc * 8]);
        }
#pragma unroll
        for (int p = 0; p < 2; ++p) {
            int idx = tid + 256 * p;
            int row = idx >> 2, kq = idx & 3;
            bvv[p] = *reinterpret_cast<const us8*>(&WtO[(size_t)(c0 + row) * DD + k0 + kq * 8]);
        }
        __syncthreads();
#pragma unroll
        for (int p = 0; p < 2; ++p) {
            int idx = tid + 256 * p;
            int kr = idx >> 4, dc = idx & 15;
            us4 lo, hi;
#pragma unroll
            for (int j = 0; j < 4; ++j) { lo[j] = avv[p][j]; hi[j] = avv[p][j + 4]; }
            *reinterpret_cast<us4*>(&Asm[kr][dc * 8]) = lo;
            *reinterpret_cast<us4*>(&Asm[kr][dc * 8 + 4]) = hi;
        }
#pragma unroll
        for (int p = 0; p < 2; ++p) {
            int idx = tid + 256 * p;
            int row = idx >> 2, kq = idx & 3;
            *reinterpret_cast<us8*>(&Bsm[row][kq * 8]) = bvv[p];
        }
        __syncthreads();
        f16x8 af[4], bfr[4];
#pragma unroll
        for (int m = 0; m < 4; ++m) {
            int l = wr * 64 + m * 16 + rl;
            us8 t;
#pragma unroll
            for (int j = 0; j < 8; ++j) t[j] = Asm[g * 8 + j][l];
            af[m] = __builtin_bit_cast(f16x8, t);
        }
#pragma unroll
        for (int n = 0; n < 4; ++n)
            bfr[n] = *reinterpret_cast<const f16x8*>(&Bsm[wc * 64 + n * 16 + rl][g * 8]);
#pragma unroll
        for (int m = 0; m < 4; ++m)
#pragma unroll
            for (int n = 0; n < 4; ++n)
                acc[m][n] = __builtin_amdgcn_mfma_f32_16x16x32_f16(af[m], bfr[n], acc[m][n], 0, 0, 0);
    }

#pragma unroll
    for (int m = 0; m < 4; ++m) {
#pragma unroll
        for (int n = 0; n < 4; ++n) {
            int c = c0 + wc * 64 + n * 16 + rl;
            float bvv = bias[c];
            int rbase = r0 + wr * 64 + m * 16 + g * 4;
#pragma unroll
            for (int j = 0; j < 4; ++j)
                out[(size_t)(rbase + j) * DD + c] = acc[m][n][j] + bvv;
        }
    }
}

extern "C" void kernel_launch(void* const* d_in, const int* in_sizes, int n_in,
                              void* d_out, int out_size, void* d_ws, size_t ws_size,
                              hipStream_t stream) {
    const float* q = (const float*)d_in[0];
    const float* k = (const float*)d_in[1];
    const float* Wq = (const float*)d_in[3];
    const float* bq = (const float*)d_in[4];
    const float* Wk = (const float*)d_in[5];
    const float* bk = (const float*)d_in[6];
    const float* Wo = (const float*)d_in[9];
    const float* bo = (const float*)d_in[10];
    float* out = (float*)d_out;

    unsigned short* qt = (unsigned short*)d_ws;
    unsigned short* kt = qt + (size_t)BB * HH * DEPTH * LL;
    unsigned short* Tq = kt + (size_t)BB * HH * DEPTH * LL;
    unsigned short* Tk = Tq + (size_t)DD * DD;
    unsigned short* To = Tk + (size_t)DD * DD;

    dim3 blk(256);
    wt_convert<<<dim3(8, 8, 3), blk, 0, stream>>>(Wq, Wk, Wo, Tq, Tk, To);
    proj_gemm_mfma<<<dim3(4, 128), blk, 0, stream>>>(q, Tq, bq, qt);
    proj_gemm_mfma<<<dim3(4, 128), blk, 0, stream>>>(k, Tk, bk, kt);
    corr_fft_v6<<<dim3(BB * HH * DEPTH), blk, 0, stream>>>(qt, kt);
    out_gemm_mfma<<<dim3(4, 128), blk, 0, stream>>>(kt, To, bo, out);
}

// Round 9
// 150.226 us; speedup vs baseline: 2.3210x; 1.1963x over previous
//
#include <hip/hip_runtime.h>
#include <hip/hip_fp16.h>
#include <float.h>
#include <math.h>

#define BB 8
#define LL 2048
#define NN 2048
#define MM 1024
#define DD 512
#define HH 8
#define DEPTH 64
#define TOPK 15
#define PIF 3.14159265358979323846f

// padded index for zr/zi/twr/twi: +1 float per 32 -> breaks power-of-2 bank aliasing
#define PD(i) ((i) + ((i) >> 5))

using f16x8 = __attribute__((ext_vector_type(8))) _Float16;
typedef __attribute__((ext_vector_type(4))) float f32x4;
typedef __attribute__((ext_vector_type(8))) unsigned short us8;
typedef __attribute__((ext_vector_type(4))) unsigned short us4;

__device__ __forceinline__ unsigned short f2h(float f) {
    return __half_as_ushort(__float2half(f));  // RNE
}
__device__ __forceinline__ float h2f(unsigned short u) {
    return (float)__builtin_bit_cast(_Float16, u);
}
__device__ __forceinline__ float2 cmul(float2 a, float2 b) {
    return make_float2(a.x * b.x - a.y * b.y, a.x * b.y + a.y * b.x);
}
__device__ __forceinline__ float2 cmulc(float2 a, float2 b) {  // a * conj(b)
    return make_float2(a.x * b.x + a.y * b.y, a.y * b.x - a.x * b.y);
}
__device__ __forceinline__ float2 cadd(float2 a, float2 b) { return make_float2(a.x + b.x, a.y + b.y); }
__device__ __forceinline__ float2 csub(float2 a, float2 b) { return make_float2(a.x - b.x, a.y - b.y); }

// ---------------- W transpose + fp32->fp16 convert (once per call) ----------------
__global__ __launch_bounds__(256) void wt_convert(const float* __restrict__ Wq,
                                                  const float* __restrict__ Wk,
                                                  const float* __restrict__ Wo,
                                                  unsigned short* __restrict__ Tq,
                                                  unsigned short* __restrict__ Tk,
                                                  unsigned short* __restrict__ To) {
    __shared__ float T[64][65];
    const float* src = blockIdx.z == 0 ? Wq : (blockIdx.z == 1 ? Wk : Wo);
    unsigned short* dst = blockIdx.z == 0 ? Tq : (blockIdx.z == 1 ? Tk : To);
    const int tid = threadIdx.x;
    const int r0 = blockIdx.y * 64, c0 = blockIdx.x * 64;
#pragma unroll
    for (int p = 0; p < 4; ++p) {
        int idx = tid + 256 * p;
        int row = idx >> 4, c4 = idx & 15;
        float4 v = *reinterpret_cast<const float4*>(&src[(size_t)(r0 + row) * DD + c0 + c4 * 4]);
        T[row][c4 * 4 + 0] = v.x;
        T[row][c4 * 4 + 1] = v.y;
        T[row][c4 * 4 + 2] = v.z;
        T[row][c4 * 4 + 3] = v.w;
    }
    __syncthreads();
#pragma unroll
    for (int p = 0; p < 4; ++p) {
        int idx = tid + 256 * p;
        int orow = idx >> 4, oc4 = idx & 15;
        us4 o;
#pragma unroll
        for (int j = 0; j < 4; ++j) o[j] = f2h(T[oc4 * 4 + j][orow]);
        *reinterpret_cast<us4*>(&dst[(size_t)(c0 + orow) * DD + r0 + oc4 * 4]) = o;
    }
}

// ---------------- projection GEMM, fp16 MFMA, OPERAND-SWAPPED (l-contiguous stores) ----------------
__global__ __launch_bounds__(256) void proj_gemm_mfma(const float* __restrict__ X,
                                                      const unsigned short* __restrict__ Wt,
                                                      const float* __restrict__ bias,
                                                      unsigned short* __restrict__ outT) {
    __shared__ unsigned short Asm[128][40];  // X tile: [l(row)][k]
    __shared__ unsigned short Bsm[128][40];  // Wt tile: [c(row)][k]
    const int tid = threadIdx.x;
    const int lane = tid & 63, wid = tid >> 6;
    const int wM = wid & 1, wN = wid >> 1;  // c-half, l-half
    const int g = lane >> 4, rl = lane & 15;
    const int r0 = blockIdx.y * 128, c0 = blockIdx.x * 128;
    f32x4 acc[4][4];
#pragma unroll
    for (int m = 0; m < 4; ++m)
#pragma unroll
        for (int n = 0; n < 4; ++n) acc[m][n] = (f32x4){0.f, 0.f, 0.f, 0.f};

    for (int k0 = 0; k0 < DD; k0 += 32) {
        float4 av[4];
#pragma unroll
        for (int p = 0; p < 4; ++p) {
            int idx = tid + 256 * p;
            int row = idx >> 3, kq = idx & 7;
            av[p] = *reinterpret_cast<const float4*>(&X[(size_t)(r0 + row) * DD + k0 + kq * 4]);
        }
        us8 bv[2];
#pragma unroll
        for (int p = 0; p < 2; ++p) {
            int idx = tid + 256 * p;
            int row = idx >> 2, kq = idx & 3;
            bv[p] = *reinterpret_cast<const us8*>(&Wt[(size_t)(c0 + row) * DD + k0 + kq * 8]);
        }
        __syncthreads();
#pragma unroll
        for (int p = 0; p < 4; ++p) {
            int idx = tid + 256 * p;
            int row = idx >> 3, kq = idx & 7;
            us4 w;
            w[0] = f2h(av[p].x); w[1] = f2h(av[p].y); w[2] = f2h(av[p].z); w[3] = f2h(av[p].w);
            *reinterpret_cast<us4*>(&Asm[row][kq * 4]) = w;
        }
#pragma unroll
        for (int p = 0; p < 2; ++p) {
            int idx = tid + 256 * p;
            int row = idx >> 2, kq = idx & 3;
            *reinterpret_cast<us8*>(&Bsm[row][kq * 8]) = bv[p];
        }
        __syncthreads();
        f16x8 af[4], bfr[4];
#pragma unroll
        for (int m = 0; m < 4; ++m)  // M = c from Wt tile
            af[m] = *reinterpret_cast<const f16x8*>(&Bsm[wM * 64 + m * 16 + rl][g * 8]);
#pragma unroll
        for (int n = 0; n < 4; ++n)  // N = l from X tile
            bfr[n] = *reinterpret_cast<const f16x8*>(&Asm[wN * 64 + n * 16 + rl][g * 8]);
#pragma unroll
        for (int m = 0; m < 4; ++m)
#pragma unroll
            for (int n = 0; n < 4; ++n)
                acc[m][n] = __builtin_amdgcn_mfma_f32_16x16x32_f16(af[m], bfr[n], acc[m][n], 0, 0, 0);
    }

    const int b = r0 >> 11, l0 = r0 & (LL - 1);
#pragma unroll
    for (int m = 0; m < 4; ++m) {
        int cb = c0 + wM * 64 + m * 16 + g * 4;
        float4 bv4 = *reinterpret_cast<const float4*>(&bias[cb]);
        const float bja[4] = {bv4.x, bv4.y, bv4.z, bv4.w};
#pragma unroll
        for (int j = 0; j < 4; ++j) {
            int c = cb + j;
            int h = c >> 6, dd = c & 63;
            unsigned short* orow = &outT[((size_t)(b * HH + h) * DEPTH + dd) * LL];
#pragma unroll
            for (int n = 0; n < 4; ++n) {
                int l = l0 + wN * 64 + n * 16 + rl;
                orow[l] = f2h(acc[m][n][j] + bja[j]);
            }
        }
    }
}

// ---------------- correlation via FFT v7: as v6 but top-k = LB-prune + gather + bitonic ----------------
__global__ __launch_bounds__(256) void corr_fft_v7(const unsigned short* __restrict__ qt,
                                                   unsigned short* __restrict__ kt) {
    __shared__ float zr[2112], zi[2112];   // 2048 + pad; reused as candidate list after inverse
    __shared__ float twr[1056], twi[1056]; // tw[j] = exp(-i*pi*j/1024), PD-padded
    __shared__ float sLB[4];
    __shared__ int cnt;
    __shared__ float corr_s[TOPK];
    __shared__ int topi_s[TOPK];
    const int tid = threadIdx.x;
    const int lane = tid & 63, wid = tid >> 6;
    const size_t base = (size_t)blockIdx.x * NN;

#define LD2(i) make_float2(zr[i], zi[i])
#define ST2(i, v) do { zr[i] = (v).x; zi[i] = (v).y; } while (0)

    // ---- load 8 consecutive fp16 q,k; bit-reversed scatter; twiddle table init ----
    {
        us8 qa = *reinterpret_cast<const us8*>(qt + base + 8 * tid);
        us8 ka = *reinterpret_cast<const us8*>(kt + base + 8 * tid);
        f16x8 qh = __builtin_bit_cast(f16x8, qa);
        f16x8 kh = __builtin_bit_cast(f16x8, ka);
        int pb = (int)(__brev((unsigned)tid) >> 24);  // brev8(tid)
        const int b3[8] = {0, 4, 2, 6, 1, 5, 3, 7};   // brev3(u)
#pragma unroll
        for (int u = 0; u < 8; ++u) {
            int pf = b3[u] * 256 + pb;  // = brev11(8*tid + u)
            zr[PD(pf)] = (float)qh[u];
            zi[PD(pf)] = (float)kh[u];
        }
#pragma unroll
        for (int v = 0; v < 4; ++v) {
            int j = tid + 256 * v;
            float sn, cs;
            __sincosf(-PIF * (float)j * (1.f / 1024.f), &sn, &cs);
            twr[PD(j)] = cs;
            twi[PD(j)] = sn;
        }
    }
    __syncthreads();

    // ---- forward DIT: hh=1 quad (twiddle-free), hh=4,16,64 quads (table), reg radix-8 tail ----
#pragma unroll
    for (int i2 = 0; i2 < 2; ++i2) {  // stages 1,2: w1=w2=1
        int q = tid + 256 * i2;
        int i0 = q << 2;
        int e0 = PD(i0), e1 = PD(i0 + 1), e2 = PD(i0 + 2), e3 = PD(i0 + 3);
        float2 a = LD2(e0), b = LD2(e1), c = LD2(e2), d = LD2(e3);
        float2 A0 = cadd(a, b), A1 = csub(a, b), A2 = cadd(c, d), A3 = csub(c, d);
        float2 t3 = make_float2(A3.y, -A3.x);  // -i*A3
        ST2(e0, cadd(A0, A2));
        ST2(e2, csub(A0, A2));
        ST2(e1, cadd(A1, t3));
        ST2(e3, csub(A1, t3));
    }
    __syncthreads();
#pragma unroll
    for (int hh = 4; hh <= 64; hh <<= 2) {
        const int step = 512 / hh;  // 128, 32, 8
#pragma unroll
        for (int i2 = 0; i2 < 2; ++i2) {
            int q = tid + 256 * i2;
            int p = q & (hh - 1);
            int i0 = ((q ^ p) << 2) | p;
            int e0 = PD(i0), e1 = PD(i0 + hh), e2 = PD(i0 + 2 * hh), e3 = PD(i0 + 3 * hh);
            float2 a = LD2(e0), b = LD2(e1), c = LD2(e2), d = LD2(e3);
            int jt = PD(p * step);
            float2 w2 = make_float2(twr[jt], twi[jt]);
            float2 w1 = make_float2(w2.x * w2.x - w2.y * w2.y, 2.f * w2.x * w2.y);
            float2 bp = cmul(b, w1), dp = cmul(d, w1);
            float2 A0 = cadd(a, bp), A1 = csub(a, bp);
            float2 A2 = cadd(c, dp), A3 = csub(c, dp);
            float2 t2 = cmul(A2, w2);
            float2 u3 = cmul(A3, w2);
            float2 t3 = make_float2(u3.y, -u3.x);  // -i*u3
            ST2(e0, cadd(A0, t2));
            ST2(e2, csub(A0, t2));
            ST2(e1, cadd(A1, t3));
            ST2(e3, csub(A1, t3));
        }
        __syncthreads();
    }
    // register radix-8 tail: stages 256,512,1024 on the closed set {tid+256u}
    {
        float2 z[8];
#pragma unroll
        for (int u = 0; u < 8; ++u) z[u] = LD2(PD(tid + 256 * u));
        {  // stage h=256: pairs (2a,2a+1), w = tw[4*tid]
            int j = PD(4 * tid);
            float2 wa = make_float2(twr[j], twi[j]);
#pragma unroll
            for (int a2 = 0; a2 < 4; ++a2) {
                float2 tv = cmul(z[2 * a2 + 1], wa);
                z[2 * a2 + 1] = csub(z[2 * a2], tv);
                z[2 * a2] = cadd(z[2 * a2], tv);
            }
        }
        {  // stage h=512: pairs (0,2),(1,3),(4,6),(5,7); odd-u pairs get extra *(-i)
            int j = PD(2 * tid);
            float2 wb = make_float2(twr[j], twi[j]);
            float2 wbn = make_float2(wb.y, -wb.x);  // -i*wb
#pragma unroll
            for (int kk = 0; kk < 4; ++kk) {
                const int u0a[4] = {0, 1, 4, 5};
                int u0 = u0a[kk];
                float2 w = (kk & 1) ? wbn : wb;
                float2 tv = cmul(z[u0 + 2], w);
                z[u0 + 2] = csub(z[u0], tv);
                z[u0] = cadd(z[u0], tv);
            }
        }
        {  // stage h=1024: pairs (u,u+4), w = tw[tid]*omega^u, omega=e^{-i*pi/4}
            int j = PD(tid);
            float2 wc = make_float2(twr[j], twi[j]);
            const float R2 = 0.70710678118654752f;
            float2 wt0 = wc;
            float2 wt1 = cmul(wc, make_float2(R2, -R2));
            float2 wt2 = make_float2(wc.y, -wc.x);  // wc*(-i)
            float2 wt3 = cmul(wc, make_float2(-R2, -R2));
            float2 tv;
            tv = cmul(z[4], wt0); z[4] = csub(z[0], tv); z[0] = cadd(z[0], tv);
            tv = cmul(z[5], wt1); z[5] = csub(z[1], tv); z[1] = cadd(z[1], tv);
            tv = cmul(z[6], wt2); z[6] = csub(z[2], tv); z[2] = cadd(z[2], tv);
            tv = cmul(z[7], wt3); z[7] = csub(z[3], tv); z[3] = cadd(z[3], tv);
        }
#pragma unroll
        for (int u = 0; u < 8; ++u) ST2(PD(tid + 256 * u), z[u]);
    }
    __syncthreads();

    // ---- FUSED: Hermitian unpack + S=Q*conj(K) + irfft E/O combine + inverse quad hh=256 ----
    {
        float2 W[4];
#pragma unroll
        for (int u = 0; u < 4; ++u) {
            int m = tid + 256 * u;
            int mf1 = (NN - m) & (NN - 1);
            float2 Zf = LD2(PD(m)), Zm = LD2(PD(mf1));
            float2 Qf = make_float2(0.5f * (Zf.x + Zm.x), 0.5f * (Zf.y - Zm.y));
            float2 Dm = make_float2(Zf.x - Zm.x, Zf.y + Zm.y);
            float2 Kf = make_float2(0.5f * Dm.y, -0.5f * Dm.x);
            float2 S1 = cmulc(Qf, Kf);
            float2 Zf2 = LD2(PD(m + MM)), Zm2 = LD2(PD(MM - m));
            float2 Qf2 = make_float2(0.5f * (Zf2.x + Zm2.x), 0.5f * (Zf2.y - Zm2.y));
            float2 Dm2 = make_float2(Zf2.x - Zm2.x, Zf2.y + Zm2.y);
            float2 Kf2 = make_float2(0.5f * Dm2.y, -0.5f * Dm2.x);
            float2 S2 = cmulc(Qf2, Kf2);
            float2 E = cadd(S1, S2), Od = csub(S1, S2);
            int jm = PD(m);
            float2 ph = make_float2(twr[jm], -twi[jm]);  // e^{+i*pi*m/1024}
            float2 T = cmul(ph, Od);
            W[u] = make_float2(E.x - T.y, E.y + T.x);  // E + i*T
        }
        // inverse DIF quad hh=256 on W (p = tid): w = conj(tw[2*tid]), w2 = w*w
        int j = PD(2 * tid);
        float2 w = make_float2(twr[j], -twi[j]);
        float2 w2 = make_float2(w.x * w.x - w.y * w.y, 2.f * w.x * w.y);
        float2 S0 = cadd(W[0], W[2]);
        float2 D0 = cmul(csub(W[0], W[2]), w);
        float2 S1q = cadd(W[1], W[3]);
        float2 ff = cmul(csub(W[1], W[3]), w);
        float2 D1 = make_float2(-ff.y, ff.x);  // i*ff
        float2 o0 = cadd(S0, S1q);
        float2 o1 = cmul(csub(S0, S1q), w2);
        float2 o2 = cadd(D0, D1);
        float2 o3 = cmul(csub(D0, D1), w2);
        __syncthreads();  // all Z reads done before overwriting
        ST2(PD(tid), o0);
        ST2(PD(tid + 256), o1);
        ST2(PD(tid + 512), o2);
        ST2(PD(tid + 768), o3);
    }
    __syncthreads();

    // ---- inverse DIF quads hh=64,16,4 (1024-pt, table twiddles) ----
#pragma unroll
    for (int hh = 64; hh >= 4; hh >>= 2) {
        const int step = 512 / hh;  // 8, 32, 128
        int q = tid;
        int p = q & (hh - 1);
        int i0 = ((q ^ p) << 2) | p;
        int e0 = PD(i0), e1 = PD(i0 + hh), e2 = PD(i0 + 2 * hh), e3 = PD(i0 + 3 * hh);
        float2 a = LD2(e0), b = LD2(e1), c = LD2(e2), d = LD2(e3);
        int jt = PD(p * step);
        float2 w = make_float2(twr[jt], -twi[jt]);
        float2 w2 = make_float2(w.x * w.x - w.y * w.y, 2.f * w.x * w.y);
        float2 S0 = cadd(a, c);
        float2 D0 = cmul(csub(a, c), w);
        float2 S1 = cadd(b, d);
        float2 ff = cmul(csub(b, d), w);
        float2 D1 = make_float2(-ff.y, ff.x);
        ST2(e0, cadd(S0, S1));
        ST2(e1, cmul(csub(S0, S1), w2));
        ST2(e2, cadd(D0, D1));
        ST2(e3, cmul(csub(D0, D1), w2));
        __syncthreads();
    }
    // hh=1: slots 4*tid..4*tid+3, pure radix-4 in registers.
    float r[8];
    int tau[8];
    {
        float2 a = LD2(PD(4 * tid)), b = LD2(PD(4 * tid + 1));
        float2 c = LD2(PD(4 * tid + 2)), d = LD2(PD(4 * tid + 3));
        float2 S0 = cadd(a, c), D0 = csub(a, c);
        float2 S1 = cadd(b, d);
        float2 bd = csub(b, d);
        float2 D1 = make_float2(-bd.y, bd.x);  // i*(b-d)
        float2 z0 = cadd(S0, S1);
        float2 z1 = csub(S0, S1);
        float2 z2 = cadd(D0, D1);
        float2 z3 = csub(D0, D1);
        const int pb = (int)(__brev((unsigned)tid) >> 24);  // brev8(tid)
        const float sc = 1.0f / (float)NN;
        int m0 = pb;         // brev2(0)=0
        int m1 = 512 + pb;   // brev2(1)=2
        int m2 = 256 + pb;   // brev2(2)=1
        int m3 = 768 + pb;   // brev2(3)=3
        r[0] = z0.x * sc; tau[0] = 2 * m0;
        r[1] = z0.y * sc; tau[1] = 2 * m0 + 1;
        r[2] = z1.x * sc; tau[2] = 2 * m1;
        r[3] = z1.y * sc; tau[3] = 2 * m1 + 1;
        r[4] = z2.x * sc; tau[4] = 2 * m2;
        r[5] = z2.y * sc; tau[5] = 2 * m2 + 1;
        r[6] = z3.x * sc; tau[6] = 2 * m3;
        r[7] = z3.y * sc; tau[7] = 2 * m3 + 1;
    }

    // ---- top-15: LB prune (per-wave bitonic of lane-maxima) + gather + exact sort ----
    {
        float lmax = r[0];
#pragma unroll
        for (int u = 1; u < 8; ++u) lmax = fmaxf(lmax, r[u]);
        // per-wave bitonic sort of 64 lane-maxima, descending (values only)
        float sv = lmax;
#pragma unroll
        for (int k = 2; k <= 64; k <<= 1) {
#pragma unroll
            for (int j = k >> 1; j > 0; j >>= 1) {
                float ov = __shfl_xor(sv, j);
                bool lower = (lane & j) == 0;
                bool dirAsc = (lane & k) == 0;
                bool myMinKey = sv > ov;  // key = -v (descending v)
                bool keepMine = (dirAsc == lower) ? myMinKey : !myMinKey;
                sv = keepMine ? sv : ov;
            }
        }
        float LBw = __shfl(sv, 14);  // 15th largest lane-max of this wave
        if (lane == 0) sLB[wid] = LBw;
        if (tid == 0) cnt = 0;
    }
    __syncthreads();
    {
        // LB = max over waves: valid global lower bound on the 15th largest value
        float LB = fmaxf(fmaxf(sLB[0], sLB[1]), fmaxf(sLB[2], sLB[3]));
#pragma unroll
        for (int u = 0; u < 8; ++u) {
            if (r[u] >= LB) {
                int slot = atomicAdd(&cnt, 1);
                zr[slot] = r[u];
                zi[slot] = __int_as_float(tau[u]);
            }
        }
    }
    __syncthreads();
    const int ncand = cnt;
    if (tid < 64) {
        float cv;
        int ci;
        if (ncand <= 64) {
            cv = (lane < ncand) ? zr[lane] : -FLT_MAX;
            ci = (lane < ncand) ? __float_as_int(zi[lane]) : 0x7fffffff;
            // bitonic sort 64 by (value desc, index asc)
#pragma unroll
            for (int k = 2; k <= 64; k <<= 1) {
#pragma unroll
                for (int j = k >> 1; j > 0; j >>= 1) {
                    float ov = __shfl_xor(cv, j);
                    int oi = __shfl_xor(ci, j);
                    bool lower = (lane & j) == 0;
                    bool dirAsc = (lane & k) == 0;
                    bool myMinKey = (cv > ov) || (cv == ov && ci < oi);
                    bool keepMine = (dirAsc == lower) ? myMinKey : !myMinKey;
                    cv = keepMine ? cv : ov;
                    ci = keepMine ? ci : oi;
                }
            }
        } else {
            // exact fallback for large candidate sets (never expected on random data)
            float keep_v = -FLT_MAX;
            int keep_i = 0x7fffffff;
            for (int it = 0; it < TOPK; ++it) {
                float bv = -FLT_MAX;
                int bi = 0x7fffffff, bs = 0;
                for (int s = lane; s < ncand; s += 64) {
                    float v = zr[s];
                    int ii = __float_as_int(zi[s]);
                    if (v > bv || (v == bv && ii < bi)) { bv = v; bi = ii; bs = s; }
                }
#pragma unroll
                for (int off = 32; off >= 1; off >>= 1) {
                    float ov = __shfl_xor(bv, off);
                    int oi = __shfl_xor(bi, off);
                    int os = __shfl_xor(bs, off);
                    if (ov > bv || (ov == bv && oi < bi)) { bv = ov; bi = oi; bs = os; }
                }
                if ((bs & 63) == lane) zr[bs] = -FLT_MAX;  // owner lane masks its own slot
                if (lane == it) { keep_v = bv; keep_i = bi; }
            }
            cv = keep_v;
            ci = keep_i;
        }
        // in-wave softmax over sorted top-15 (lanes 0..14)
        float m0 = __shfl(cv, 0);
        float e = (lane < TOPK) ? expf(cv - m0) : 0.f;
        float ssum = e;
#pragma unroll
        for (int off = 32; off >= 1; off >>= 1) ssum += __shfl_xor(ssum, off);
        if (lane < TOPK) {
            corr_s[lane] = e / ssum;
            topi_s[lane] = ci;
        }
    }
    __syncthreads();

    // ---- aggregation: re-read the 4KB qt row from global (L1/L2-resident, coalesced) ----
    {
        float cw[TOPK];
        int ci[TOPK];
#pragma unroll
        for (int i = 0; i < TOPK; ++i) { cw[i] = corr_s[i]; ci[i] = topi_s[i]; }
        const unsigned short* qrow = qt + base;
#pragma unroll
        for (int u = 0; u < 8; ++u) {
            int t = tid + 256 * u;
            float acc = 0.f;
#pragma unroll
            for (int i = 0; i < TOPK; ++i)
                acc += cw[i] * h2f(qrow[(t + ci[i]) & (NN - 1)]);
            kt[base + t] = f2h(acc);
        }
    }
#undef LD2
#undef ST2
}

// ---------------- output GEMM, fp16 MFMA (unchanged) ----------------
__global__ __launch_bounds__(256) void out_gemm_mfma(const unsigned short* __restrict__ db,
                                                     const unsigned short* __restrict__ WtO,
                                                     const float* __restrict__ bias,
                                                     float* __restrict__ out) {
    __shared__ unsigned short Asm[32][132];
    __shared__ unsigned short Bsm[128][40];
    const int tid = threadIdx.x;
    const int lane = tid & 63, wid = tid >> 6;
    const int wr = wid >> 1, wc = wid & 1;
    const int g = lane >> 4, rl = lane & 15;
    const int r0 = blockIdx.y * 128, c0 = blockIdx.x * 128;
    const int b = r0 >> 11, l0 = r0 & (LL - 1);
    f32x4 acc[4][4];
#pragma unroll
    for (int m = 0; m < 4; ++m)
#pragma unroll
        for (int n = 0; n < 4; ++n) acc[m][n] = (f32x4){0.f, 0.f, 0.f, 0.f};

    for (int k0 = 0; k0 < DD; k0 += 32) {
        us8 avv[2], bvv[2];
#pragma unroll
        for (int p = 0; p < 2; ++p) {
            int idx = tid + 256 * p;
            int kr = idx >> 4, dc = idx & 15;
            avv[p] = *reinterpret_cast<const us8*>(
                &db[(size_t)(b * DD + k0 + kr) * 2048 + l0 + dc * 8]);
        }
#pragma unroll
        for (int p = 0; p < 2; ++p) {
            int idx = tid + 256 * p;
            int row = idx >> 2, kq = idx & 3;
            bvv[p] = *reinterpret_cast<const us8*>(&WtO[(size_t)(c0 + row) * DD + k0 + kq * 8]);
        }
        __syncthreads();
#pragma unroll
        for (int p = 0; p < 2; ++p) {
            int idx = tid + 256 * p;
            int kr = idx >> 4, dc = idx & 15;
            us4 lo, hi;
#pragma unroll
            for (int j = 0; j < 4; ++j) { lo[j] = avv[p][j]; hi[j] = avv[p][j + 4]; }
            *reinterpret_cast<us4*>(&Asm[kr][dc * 8]) = lo;
            *reinterpret_cast<us4*>(&Asm[kr][dc * 8 + 4]) = hi;
        }
#pragma unroll
        for (int p = 0; p < 2; ++p) {
            int idx = tid + 256 * p;
            int row = idx >> 2, kq = idx & 3;
            *reinterpret_cast<us8*>(&Bsm[row][kq * 8]) = bvv[p];
        }
        __syncthreads();
        f16x8 af[4], bfr[4];
#pragma unroll
        for (int m = 0; m < 4; ++m) {
            int l = wr * 64 + m * 16 + rl;
            us8 t;
#pragma unroll
            for (int j = 0; j < 8; ++j) t[j] = Asm[g * 8 + j][l];
            af[m] = __builtin_bit_cast(f16x8, t);
        }
#pragma unroll
        for (int n = 0; n < 4; ++n)
            bfr[n] = *reinterpret_cast<const f16x8*>(&Bsm[wc * 64 + n * 16 + rl][g * 8]);
#pragma unroll
        for (int m = 0; m < 4; ++m)
#pragma unroll
            for (int n = 0; n < 4; ++n)
                acc[m][n] = __builtin_amdgcn_mfma_f32_16x16x32_f16(af[m], bfr[n], acc[m][n], 0, 0, 0);
    }

#pragma unroll
    for (int m = 0; m < 4; ++m) {
#pragma unroll
        for (int n = 0; n < 4; ++n) {
            int c = c0 + wc * 64 + n * 16 + rl;
            float bvv = bias[c];
            int rbase = r0 + wr * 64 + m * 16 + g * 4;
#pragma unroll
            for (int j = 0; j < 4; ++j)
                out[(size_t)(rbase + j) * DD + c] = acc[m][n][j] + bvv;
        }
    }
}

extern "C" void kernel_launch(void* const* d_in, const int* in_sizes, int n_in,
                              void* d_out, int out_size, void* d_ws, size_t ws_size,
                              hipStream_t stream) {
    const float* q = (const float*)d_in[0];
    const float* k = (const float*)d_in[1];
    const float* Wq = (const float*)d_in[3];
    const float* bq = (const float*)d_in[4];
    const float* Wk = (const float*)d_in[5];
    const float* bk = (const float*)d_in[6];
    const float* Wo = (const float*)d_in[9];
    const float* bo = (const float*)d_in[10];
    float* out = (float*)d_out;

    unsigned short* qt = (unsigned short*)d_ws;
    unsigned short* kt = qt + (size_t)BB * HH * DEPTH * LL;
    unsigned short* Tq = kt + (size_t)BB * HH * DEPTH * LL;
    unsigned short* Tk = Tq + (size_t)DD * DD;
    unsigned short* To = Tk + (size_t)DD * DD;

    dim3 blk(256);
    wt_convert<<<dim3(8, 8, 3), blk, 0, stream>>>(Wq, Wk, Wo, Tq, Tk, To);
    proj_gemm_mfma<<<dim3(4, 128), blk, 0, stream>>>(q, Tq, bq, qt);
    proj_gemm_mfma<<<dim3(4, 128), blk, 0, stream>>>(k, Tk, bk, kt);
    corr_fft_v7<<<dim3(BB * HH * DEPTH), blk, 0, stream>>>(qt, kt);
    out_gemm_mfma<<<dim3(4, 128), blk, 0, stream>>>(kt, To, bo, out);
}

// Round 10
// 144.365 us; speedup vs baseline: 2.4152x; 1.0406x over previous
//
#include <hip/hip_runtime.h>
#include <hip/hip_fp16.h>
#include <float.h>
#include <math.h>

#define BB 8
#define LL 2048
#define NN 2048
#define MM 1024
#define DD 512
#define HH 8
#define DEPTH 64
#define TOPK 15
#define PIF 3.14159265358979323846f

// padded index for zr/zi/twr/twi: +1 float per 32 -> breaks power-of-2 bank aliasing
#define PD(i) ((i) + ((i) >> 5))

using f16x8 = __attribute__((ext_vector_type(8))) _Float16;
typedef __attribute__((ext_vector_type(4))) float f32x4;
typedef __attribute__((ext_vector_type(8))) unsigned short us8;
typedef __attribute__((ext_vector_type(4))) unsigned short us4;

__device__ __forceinline__ unsigned short f2h(float f) {
    return __half_as_ushort(__float2half(f));  // RNE
}
__device__ __forceinline__ float h2f(unsigned short u) {
    return (float)__builtin_bit_cast(_Float16, u);
}
__device__ __forceinline__ float2 cmul(float2 a, float2 b) {
    return make_float2(a.x * b.x - a.y * b.y, a.x * b.y + a.y * b.x);
}
__device__ __forceinline__ float2 cmulc(float2 a, float2 b) {  // a * conj(b)
    return make_float2(a.x * b.x + a.y * b.y, a.y * b.x - a.x * b.y);
}
__device__ __forceinline__ float2 cadd(float2 a, float2 b) { return make_float2(a.x + b.x, a.y + b.y); }
__device__ __forceinline__ float2 csub(float2 a, float2 b) { return make_float2(a.x - b.x, a.y - b.y); }

// XCD-aware swizzle for 512-block GEMM grids (4 col-blocks x 128 row-panels):
// co-locates the 4 col-blocks of each A-panel on one XCD so L2 serves 3 of 4 reads.
__device__ __forceinline__ void xcd_swizzle_512(int bx, int by, int& obx, int& oby) {
    int flat = by * 4 + bx;        // dispatch order (x fastest)
    int xcd = flat & 7;
    int pos = flat >> 3;
    int nid = xcd * 64 + pos;      // bijective: 512 = 8 * 64
    obx = nid & 3;
    oby = nid >> 2;
}

// ---------------- W transpose + fp32->fp16 convert (once per call) ----------------
__global__ __launch_bounds__(256) void wt_convert(const float* __restrict__ Wq,
                                                  const float* __restrict__ Wk,
                                                  const float* __restrict__ Wo,
                                                  unsigned short* __restrict__ Tq,
                                                  unsigned short* __restrict__ Tk,
                                                  unsigned short* __restrict__ To) {
    __shared__ float T[64][65];
    const float* src = blockIdx.z == 0 ? Wq : (blockIdx.z == 1 ? Wk : Wo);
    unsigned short* dst = blockIdx.z == 0 ? Tq : (blockIdx.z == 1 ? Tk : To);
    const int tid = threadIdx.x;
    const int r0 = blockIdx.y * 64, c0 = blockIdx.x * 64;
#pragma unroll
    for (int p = 0; p < 4; ++p) {
        int idx = tid + 256 * p;
        int row = idx >> 4, c4 = idx & 15;
        float4 v = *reinterpret_cast<const float4*>(&src[(size_t)(r0 + row) * DD + c0 + c4 * 4]);
        T[row][c4 * 4 + 0] = v.x;
        T[row][c4 * 4 + 1] = v.y;
        T[row][c4 * 4 + 2] = v.z;
        T[row][c4 * 4 + 3] = v.w;
    }
    __syncthreads();
#pragma unroll
    for (int p = 0; p < 4; ++p) {
        int idx = tid + 256 * p;
        int orow = idx >> 4, oc4 = idx & 15;
        us4 o;
#pragma unroll
        for (int j = 0; j < 4; ++j) o[j] = f2h(T[oc4 * 4 + j][orow]);
        *reinterpret_cast<us4*>(&dst[(size_t)(c0 + orow) * DD + r0 + oc4 * 4]) = o;
    }
}

// ---------------- projection GEMM, fp16 MFMA, OPERAND-SWAPPED (l-contiguous stores) ----------------
__global__ __launch_bounds__(256) void proj_gemm_mfma(const float* __restrict__ X,
                                                      const unsigned short* __restrict__ Wt,
                                                      const float* __restrict__ bias,
                                                      unsigned short* __restrict__ outT) {
    __shared__ unsigned short Asm[128][40];  // X tile: [l(row)][k]
    __shared__ unsigned short Bsm[128][40];  // Wt tile: [c(row)][k]
    const int tid = threadIdx.x;
    const int lane = tid & 63, wid = tid >> 6;
    const int wM = wid & 1, wN = wid >> 1;  // c-half, l-half
    const int g = lane >> 4, rl = lane & 15;
    int sbx, sby;
    xcd_swizzle_512(blockIdx.x, blockIdx.y, sbx, sby);
    const int r0 = sby * 128, c0 = sbx * 128;
    f32x4 acc[4][4];
#pragma unroll
    for (int m = 0; m < 4; ++m)
#pragma unroll
        for (int n = 0; n < 4; ++n) acc[m][n] = (f32x4){0.f, 0.f, 0.f, 0.f};

    for (int k0 = 0; k0 < DD; k0 += 32) {
        float4 av[4];
#pragma unroll
        for (int p = 0; p < 4; ++p) {
            int idx = tid + 256 * p;
            int row = idx >> 3, kq = idx & 7;
            av[p] = *reinterpret_cast<const float4*>(&X[(size_t)(r0 + row) * DD + k0 + kq * 4]);
        }
        us8 bv[2];
#pragma unroll
        for (int p = 0; p < 2; ++p) {
            int idx = tid + 256 * p;
            int row = idx >> 2, kq = idx & 3;
            bv[p] = *reinterpret_cast<const us8*>(&Wt[(size_t)(c0 + row) * DD + k0 + kq * 8]);
        }
        __syncthreads();
#pragma unroll
        for (int p = 0; p < 4; ++p) {
            int idx = tid + 256 * p;
            int row = idx >> 3, kq = idx & 7;
            us4 w;
            w[0] = f2h(av[p].x); w[1] = f2h(av[p].y); w[2] = f2h(av[p].z); w[3] = f2h(av[p].w);
            *reinterpret_cast<us4*>(&Asm[row][kq * 4]) = w;
        }
#pragma unroll
        for (int p = 0; p < 2; ++p) {
            int idx = tid + 256 * p;
            int row = idx >> 2, kq = idx & 3;
            *reinterpret_cast<us8*>(&Bsm[row][kq * 8]) = bv[p];
        }
        __syncthreads();
        f16x8 af[4], bfr[4];
#pragma unroll
        for (int m = 0; m < 4; ++m)  // M = c from Wt tile
            af[m] = *reinterpret_cast<const f16x8*>(&Bsm[wM * 64 + m * 16 + rl][g * 8]);
#pragma unroll
        for (int n = 0; n < 4; ++n)  // N = l from X tile
            bfr[n] = *reinterpret_cast<const f16x8*>(&Asm[wN * 64 + n * 16 + rl][g * 8]);
#pragma unroll
        for (int m = 0; m < 4; ++m)
#pragma unroll
            for (int n = 0; n < 4; ++n)
                acc[m][n] = __builtin_amdgcn_mfma_f32_16x16x32_f16(af[m], bfr[n], acc[m][n], 0, 0, 0);
    }

    const int b = r0 >> 11, l0 = r0 & (LL - 1);
#pragma unroll
    for (int m = 0; m < 4; ++m) {
        int cb = c0 + wM * 64 + m * 16 + g * 4;
        float4 bv4 = *reinterpret_cast<const float4*>(&bias[cb]);
        const float bja[4] = {bv4.x, bv4.y, bv4.z, bv4.w};
#pragma unroll
        for (int j = 0; j < 4; ++j) {
            int c = cb + j;
            int h = c >> 6, dd = c & 63;
            unsigned short* orow = &outT[((size_t)(b * HH + h) * DEPTH + dd) * LL];
#pragma unroll
            for (int n = 0; n < 4; ++n) {
                int l = l0 + wN * 64 + n * 16 + rl;
                orow[l] = f2h(acc[m][n][j] + bja[j]);
            }
        }
    }
}

// ---------------- correlation via FFT v7 (unchanged from R9) ----------------
__global__ __launch_bounds__(256) void corr_fft_v7(const unsigned short* __restrict__ qt,
                                                   unsigned short* __restrict__ kt) {
    __shared__ float zr[2112], zi[2112];   // 2048 + pad; reused as candidate list after inverse
    __shared__ float twr[1056], twi[1056]; // tw[j] = exp(-i*pi*j/1024), PD-padded
    __shared__ float sLB[4];
    __shared__ int cnt;
    __shared__ float corr_s[TOPK];
    __shared__ int topi_s[TOPK];
    const int tid = threadIdx.x;
    const int lane = tid & 63, wid = tid >> 6;
    const size_t base = (size_t)blockIdx.x * NN;

#define LD2(i) make_float2(zr[i], zi[i])
#define ST2(i, v) do { zr[i] = (v).x; zi[i] = (v).y; } while (0)

    {
        us8 qa = *reinterpret_cast<const us8*>(qt + base + 8 * tid);
        us8 ka = *reinterpret_cast<const us8*>(kt + base + 8 * tid);
        f16x8 qh = __builtin_bit_cast(f16x8, qa);
        f16x8 kh = __builtin_bit_cast(f16x8, ka);
        int pb = (int)(__brev((unsigned)tid) >> 24);  // brev8(tid)
        const int b3[8] = {0, 4, 2, 6, 1, 5, 3, 7};   // brev3(u)
#pragma unroll
        for (int u = 0; u < 8; ++u) {
            int pf = b3[u] * 256 + pb;  // = brev11(8*tid + u)
            zr[PD(pf)] = (float)qh[u];
            zi[PD(pf)] = (float)kh[u];
        }
#pragma unroll
        for (int v = 0; v < 4; ++v) {
            int j = tid + 256 * v;
            float sn, cs;
            __sincosf(-PIF * (float)j * (1.f / 1024.f), &sn, &cs);
            twr[PD(j)] = cs;
            twi[PD(j)] = sn;
        }
    }
    __syncthreads();

#pragma unroll
    for (int i2 = 0; i2 < 2; ++i2) {  // stages 1,2: w1=w2=1
        int q = tid + 256 * i2;
        int i0 = q << 2;
        int e0 = PD(i0), e1 = PD(i0 + 1), e2 = PD(i0 + 2), e3 = PD(i0 + 3);
        float2 a = LD2(e0), b = LD2(e1), c = LD2(e2), d = LD2(e3);
        float2 A0 = cadd(a, b), A1 = csub(a, b), A2 = cadd(c, d), A3 = csub(c, d);
        float2 t3 = make_float2(A3.y, -A3.x);  // -i*A3
        ST2(e0, cadd(A0, A2));
        ST2(e2, csub(A0, A2));
        ST2(e1, cadd(A1, t3));
        ST2(e3, csub(A1, t3));
    }
    __syncthreads();
#pragma unroll
    for (int hh = 4; hh <= 64; hh <<= 2) {
        const int step = 512 / hh;  // 128, 32, 8
#pragma unroll
        for (int i2 = 0; i2 < 2; ++i2) {
            int q = tid + 256 * i2;
            int p = q & (hh - 1);
            int i0 = ((q ^ p) << 2) | p;
            int e0 = PD(i0), e1 = PD(i0 + hh), e2 = PD(i0 + 2 * hh), e3 = PD(i0 + 3 * hh);
            float2 a = LD2(e0), b = LD2(e1), c = LD2(e2), d = LD2(e3);
            int jt = PD(p * step);
            float2 w2 = make_float2(twr[jt], twi[jt]);
            float2 w1 = make_float2(w2.x * w2.x - w2.y * w2.y, 2.f * w2.x * w2.y);
            float2 bp = cmul(b, w1), dp = cmul(d, w1);
            float2 A0 = cadd(a, bp), A1 = csub(a, bp);
            float2 A2 = cadd(c, dp), A3 = csub(c, dp);
            float2 t2 = cmul(A2, w2);
            float2 u3 = cmul(A3, w2);
            float2 t3 = make_float2(u3.y, -u3.x);  // -i*u3
            ST2(e0, cadd(A0, t2));
            ST2(e2, csub(A0, t2));
            ST2(e1, cadd(A1, t3));
            ST2(e3, csub(A1, t3));
        }
        __syncthreads();
    }
    {
        float2 z[8];
#pragma unroll
        for (int u = 0; u < 8; ++u) z[u] = LD2(PD(tid + 256 * u));
        {  // stage h=256: pairs (2a,2a+1), w = tw[4*tid]
            int j = PD(4 * tid);
            float2 wa = make_float2(twr[j], twi[j]);
#pragma unroll
            for (int a2 = 0; a2 < 4; ++a2) {
                float2 tv = cmul(z[2 * a2 + 1], wa);
                z[2 * a2 + 1] = csub(z[2 * a2], tv);
                z[2 * a2] = cadd(z[2 * a2], tv);
            }
        }
        {  // stage h=512
            int j = PD(2 * tid);
            float2 wb = make_float2(twr[j], twi[j]);
            float2 wbn = make_float2(wb.y, -wb.x);  // -i*wb
#pragma unroll
            for (int kk = 0; kk < 4; ++kk) {
                const int u0a[4] = {0, 1, 4, 5};
                int u0 = u0a[kk];
                float2 w = (kk & 1) ? wbn : wb;
                float2 tv = cmul(z[u0 + 2], w);
                z[u0 + 2] = csub(z[u0], tv);
                z[u0] = cadd(z[u0], tv);
            }
        }
        {  // stage h=1024
            int j = PD(tid);
            float2 wc = make_float2(twr[j], twi[j]);
            const float R2 = 0.70710678118654752f;
            float2 wt0 = wc;
            float2 wt1 = cmul(wc, make_float2(R2, -R2));
            float2 wt2 = make_float2(wc.y, -wc.x);  // wc*(-i)
            float2 wt3 = cmul(wc, make_float2(-R2, -R2));
            float2 tv;
            tv = cmul(z[4], wt0); z[4] = csub(z[0], tv); z[0] = cadd(z[0], tv);
            tv = cmul(z[5], wt1); z[5] = csub(z[1], tv); z[1] = cadd(z[1], tv);
            tv = cmul(z[6], wt2); z[6] = csub(z[2], tv); z[2] = cadd(z[2], tv);
            tv = cmul(z[7], wt3); z[7] = csub(z[3], tv); z[3] = cadd(z[3], tv);
        }
#pragma unroll
        for (int u = 0; u < 8; ++u) ST2(PD(tid + 256 * u), z[u]);
    }
    __syncthreads();

    {
        float2 W[4];
#pragma unroll
        for (int u = 0; u < 4; ++u) {
            int m = tid + 256 * u;
            int mf1 = (NN - m) & (NN - 1);
            float2 Zf = LD2(PD(m)), Zm = LD2(PD(mf1));
            float2 Qf = make_float2(0.5f * (Zf.x + Zm.x), 0.5f * (Zf.y - Zm.y));
            float2 Dm = make_float2(Zf.x - Zm.x, Zf.y + Zm.y);
            float2 Kf = make_float2(0.5f * Dm.y, -0.5f * Dm.x);
            float2 S1 = cmulc(Qf, Kf);
            float2 Zf2 = LD2(PD(m + MM)), Zm2 = LD2(PD(MM - m));
            float2 Qf2 = make_float2(0.5f * (Zf2.x + Zm2.x), 0.5f * (Zf2.y - Zm2.y));
            float2 Dm2 = make_float2(Zf2.x - Zm2.x, Zf2.y + Zm2.y);
            float2 Kf2 = make_float2(0.5f * Dm2.y, -0.5f * Dm2.x);
            float2 S2 = cmulc(Qf2, Kf2);
            float2 E = cadd(S1, S2), Od = csub(S1, S2);
            int jm = PD(m);
            float2 ph = make_float2(twr[jm], -twi[jm]);  // e^{+i*pi*m/1024}
            float2 T = cmul(ph, Od);
            W[u] = make_float2(E.x - T.y, E.y + T.x);  // E + i*T
        }
        int j = PD(2 * tid);
        float2 w = make_float2(twr[j], -twi[j]);
        float2 w2 = make_float2(w.x * w.x - w.y * w.y, 2.f * w.x * w.y);
        float2 S0 = cadd(W[0], W[2]);
        float2 D0 = cmul(csub(W[0], W[2]), w);
        float2 S1q = cadd(W[1], W[3]);
        float2 ff = cmul(csub(W[1], W[3]), w);
        float2 D1 = make_float2(-ff.y, ff.x);  // i*ff
        float2 o0 = cadd(S0, S1q);
        float2 o1 = cmul(csub(S0, S1q), w2);
        float2 o2 = cadd(D0, D1);
        float2 o3 = cmul(csub(D0, D1), w2);
        __syncthreads();  // all Z reads done before overwriting
        ST2(PD(tid), o0);
        ST2(PD(tid + 256), o1);
        ST2(PD(tid + 512), o2);
        ST2(PD(tid + 768), o3);
    }
    __syncthreads();

#pragma unroll
    for (int hh = 64; hh >= 4; hh >>= 2) {
        const int step = 512 / hh;  // 8, 32, 128
        int q = tid;
        int p = q & (hh - 1);
        int i0 = ((q ^ p) << 2) | p;
        int e0 = PD(i0), e1 = PD(i0 + hh), e2 = PD(i0 + 2 * hh), e3 = PD(i0 + 3 * hh);
        float2 a = LD2(e0), b = LD2(e1), c = LD2(e2), d = LD2(e3);
        int jt = PD(p * step);
        float2 w = make_float2(twr[jt], -twi[jt]);
        float2 w2 = make_float2(w.x * w.x - w.y * w.y, 2.f * w.x * w.y);
        float2 S0 = cadd(a, c);
        float2 D0 = cmul(csub(a, c), w);
        float2 S1 = cadd(b, d);
        float2 ff = cmul(csub(b, d), w);
        float2 D1 = make_float2(-ff.y, ff.x);
        ST2(e0, cadd(S0, S1));
        ST2(e1, cmul(csub(S0, S1), w2));
        ST2(e2, cadd(D0, D1));
        ST2(e3, cmul(csub(D0, D1), w2));
        __syncthreads();
    }
    float r[8];
    int tau[8];
    {
        float2 a = LD2(PD(4 * tid)), b = LD2(PD(4 * tid + 1));
        float2 c = LD2(PD(4 * tid + 2)), d = LD2(PD(4 * tid + 3));
        float2 S0 = cadd(a, c), D0 = csub(a, c);
        float2 S1 = cadd(b, d);
        float2 bd = csub(b, d);
        float2 D1 = make_float2(-bd.y, bd.x);  // i*(b-d)
        float2 z0 = cadd(S0, S1);
        float2 z1 = csub(S0, S1);
        float2 z2 = cadd(D0, D1);
        float2 z3 = csub(D0, D1);
        const int pb = (int)(__brev((unsigned)tid) >> 24);  // brev8(tid)
        const float sc = 1.0f / (float)NN;
        int m0 = pb;         // brev2(0)=0
        int m1 = 512 + pb;   // brev2(1)=2
        int m2 = 256 + pb;   // brev2(2)=1
        int m3 = 768 + pb;   // brev2(3)=3
        r[0] = z0.x * sc; tau[0] = 2 * m0;
        r[1] = z0.y * sc; tau[1] = 2 * m0 + 1;
        r[2] = z1.x * sc; tau[2] = 2 * m1;
        r[3] = z1.y * sc; tau[3] = 2 * m1 + 1;
        r[4] = z2.x * sc; tau[4] = 2 * m2;
        r[5] = z2.y * sc; tau[5] = 2 * m2 + 1;
        r[6] = z3.x * sc; tau[6] = 2 * m3;
        r[7] = z3.y * sc; tau[7] = 2 * m3 + 1;
    }

    // ---- top-15: LB prune (per-wave bitonic of lane-maxima) + gather + exact sort ----
    {
        float lmax = r[0];
#pragma unroll
        for (int u = 1; u < 8; ++u) lmax = fmaxf(lmax, r[u]);
        float sv = lmax;
#pragma unroll
        for (int k = 2; k <= 64; k <<= 1) {
#pragma unroll
            for (int j = k >> 1; j > 0; j >>= 1) {
                float ov = __shfl_xor(sv, j);
                bool lower = (lane & j) == 0;
                bool dirAsc = (lane & k) == 0;
                bool myMinKey = sv > ov;  // key = -v (descending v)
                bool keepMine = (dirAsc == lower) ? myMinKey : !myMinKey;
                sv = keepMine ? sv : ov;
            }
        }
        float LBw = __shfl(sv, 14);  // 15th largest lane-max of this wave
        if (lane == 0) sLB[wid] = LBw;
        if (tid == 0) cnt = 0;
    }
    __syncthreads();
    {
        float LB = fmaxf(fmaxf(sLB[0], sLB[1]), fmaxf(sLB[2], sLB[3]));
#pragma unroll
        for (int u = 0; u < 8; ++u) {
            if (r[u] >= LB) {
                int slot = atomicAdd(&cnt, 1);
                zr[slot] = r[u];
                zi[slot] = __int_as_float(tau[u]);
            }
        }
    }
    __syncthreads();
    const int ncand = cnt;
    if (tid < 64) {
        float cv;
        int ci;
        if (ncand <= 64) {
            cv = (lane < ncand) ? zr[lane] : -FLT_MAX;
            ci = (lane < ncand) ? __float_as_int(zi[lane]) : 0x7fffffff;
#pragma unroll
            for (int k = 2; k <= 64; k <<= 1) {
#pragma unroll
                for (int j = k >> 1; j > 0; j >>= 1) {
                    float ov = __shfl_xor(cv, j);
                    int oi = __shfl_xor(ci, j);
                    bool lower = (lane & j) == 0;
                    bool dirAsc = (lane & k) == 0;
                    bool myMinKey = (cv > ov) || (cv == ov && ci < oi);
                    bool keepMine = (dirAsc == lower) ? myMinKey : !myMinKey;
                    cv = keepMine ? cv : ov;
                    ci = keepMine ? ci : oi;
                }
            }
        } else {
            float keep_v = -FLT_MAX;
            int keep_i = 0x7fffffff;
            for (int it = 0; it < TOPK; ++it) {
                float bv = -FLT_MAX;
                int bi = 0x7fffffff, bs = 0;
                for (int s = lane; s < ncand; s += 64) {
                    float v = zr[s];
                    int ii = __float_as_int(zi[s]);
                    if (v > bv || (v == bv && ii < bi)) { bv = v; bi = ii; bs = s; }
                }
#pragma unroll
                for (int off = 32; off >= 1; off >>= 1) {
                    float ov = __shfl_xor(bv, off);
                    int oi = __shfl_xor(bi, off);
                    int os = __shfl_xor(bs, off);
                    if (ov > bv || (ov == bv && oi < bi)) { bv = ov; bi = oi; bs = os; }
                }
                if ((bs & 63) == lane) zr[bs] = -FLT_MAX;  // owner lane masks its own slot
                if (lane == it) { keep_v = bv; keep_i = bi; }
            }
            cv = keep_v;
            ci = keep_i;
        }
        float m0 = __shfl(cv, 0);
        float e = (lane < TOPK) ? expf(cv - m0) : 0.f;
        float ssum = e;
#pragma unroll
        for (int off = 32; off >= 1; off >>= 1) ssum += __shfl_xor(ssum, off);
        if (lane < TOPK) {
            corr_s[lane] = e / ssum;
            topi_s[lane] = ci;
        }
    }
    __syncthreads();

    // ---- aggregation: re-read the 4KB qt row from global (L1/L2-resident, coalesced) ----
    {
        float cw[TOPK];
        int ci[TOPK];
#pragma unroll
        for (int i = 0; i < TOPK; ++i) { cw[i] = corr_s[i]; ci[i] = topi_s[i]; }
        const unsigned short* qrow = qt + base;
#pragma unroll
        for (int u = 0; u < 8; ++u) {
            int t = tid + 256 * u;
            float acc = 0.f;
#pragma unroll
            for (int i = 0; i < TOPK; ++i)
                acc += cw[i] * h2f(qrow[(t + ci[i]) & (NN - 1)]);
            kt[base + t] = f2h(acc);
        }
    }
#undef LD2
#undef ST2
}

// ---------------- output GEMM, fp16 MFMA (XCD-swizzled) ----------------
__global__ __launch_bounds__(256) void out_gemm_mfma(const unsigned short* __restrict__ db,
                                                     const unsigned short* __restrict__ WtO,
                                                     const float* __restrict__ bias,
                                                     float* __restrict__ out) {
    __shared__ unsigned short Asm[32][132];
    __shared__ unsigned short Bsm[128][40];
    const int tid = threadIdx.x;
    const int lane = tid & 63, wid = tid >> 6;
    const int wr = wid >> 1, wc = wid & 1;
    const int g = lane >> 4, rl = lane & 15;
    int sbx, sby;
    xcd_swizzle_512(blockIdx.x, blockIdx.y, sbx, sby);
    const int r0 = sby * 128, c0 = sbx * 128;
    const int b = r0 >> 11, l0 = r0 & (LL - 1);
    f32x4 acc[4][4];
#pragma unroll
    for (int m = 0; m < 4; ++m)
#pragma unroll
        for (int n = 0; n < 4; ++n) acc[m][n] = (f32x4){0.f, 0.f, 0.f, 0.f};

    for (int k0 = 0; k0 < DD; k0 += 32) {
        us8 avv[2], bvv[2];
#pragma unroll
        for (int p = 0; p < 2; ++p) {
            int idx = tid + 256 * p;
            int kr = idx >> 4, dc = idx & 15;
            avv[p] = *reinterpret_cast<const us8*>(
                &db[(size_t)(b * DD + k0 + kr) * 2048 + l0 + dc * 8]);
        }
#pragma unroll
        for (int p = 0; p < 2; ++p) {
            int idx = tid + 256 * p;
            int row = idx >> 2, kq = idx & 3;
            bvv[p] = *reinterpret_cast<const us8*>(&WtO[(size_t)(c0 + row) * DD + k0 + kq * 8]);
        }
        __syncthreads();
#pragma unroll
        for (int p = 0; p < 2; ++p) {
            int idx = tid + 256 * p;
            int kr = idx >> 4, dc = idx & 15;
            us4 lo, hi;
#pragma unroll
            for (int j = 0; j < 4; ++j) { lo[j] = avv[p][j]; hi[j] = avv[p][j + 4]; }
            *reinterpret_cast<us4*>(&Asm[kr][dc * 8]) = lo;
            *reinterpret_cast<us4*>(&Asm[kr][dc * 8 + 4]) = hi;
        }
#pragma unroll
        for (int p = 0; p < 2; ++p) {
            int idx = tid + 256 * p;
            int row = idx >> 2, kq = idx & 3;
            *reinterpret_cast<us8*>(&Bsm[row][kq * 8]) = bvv[p];
        }
        __syncthreads();
        f16x8 af[4], bfr[4];
#pragma unroll
        for (int m = 0; m < 4; ++m) {
            int l = wr * 64 + m * 16 + rl;
            us8 t;
#pragma unroll
            for (int j = 0; j < 8; ++j) t[j] = Asm[g * 8 + j][l];
            af[m] = __builtin_bit_cast(f16x8, t);
        }
#pragma unroll
        for (int n = 0; n < 4; ++n)
            bfr[n] = *reinterpret_cast<const f16x8*>(&Bsm[wc * 64 + n * 16 + rl][g * 8]);
#pragma unroll
        for (int m = 0; m < 4; ++m)
#pragma unroll
            for (int n = 0; n < 4; ++n)
                acc[m][n] = __builtin_amdgcn_mfma_f32_16x16x32_f16(af[m], bfr[n], acc[m][n], 0, 0, 0);
    }

#pragma unroll
    for (int m = 0; m < 4; ++m) {
#pragma unroll
        for (int n = 0; n < 4; ++n) {
            int c = c0 + wc * 64 + n * 16 + rl;
            float bvv = bias[c];
            int rbase = r0 + wr * 64 + m * 16 + g * 4;
#pragma unroll
            for (int j = 0; j < 4; ++j)
                out[(size_t)(rbase + j) * DD + c] = acc[m][n][j] + bvv;
        }
    }
}

extern "C" void kernel_launch(void* const* d_in, const int* in_sizes, int n_in,
                              void* d_out, int out_size, void* d_ws, size_t ws_size,
                              hipStream_t stream) {
    const float* q = (const float*)d_in[0];
    const float* k = (const float*)d_in[1];
    const float* Wq = (const float*)d_in[3];
    const float* bq = (const float*)d_in[4];
    const float* Wk = (const float*)d_in[5];
    const float* bk = (const float*)d_in[6];
    const float* Wo = (const float*)d_in[9];
    const float* bo = (const float*)d_in[10];
    float* out = (float*)d_out;

    unsigned short* qt = (unsigned short*)d_ws;
    unsigned short* kt = qt + (size_t)BB * HH * DEPTH * LL;
    unsigned short* Tq = kt + (size_t)BB * HH * DEPTH * LL;
    unsigned short* Tk = Tq + (size_t)DD * DD;
    unsigned short* To = Tk + (size_t)DD * DD;

    dim3 blk(256);
    wt_convert<<<dim3(8, 8, 3), blk, 0, stream>>>(Wq, Wk, Wo, Tq, Tk, To);
    proj_gemm_mfma<<<dim3(4, 128), blk, 0, stream>>>(q, Tq, bq, qt);
    proj_gemm_mfma<<<dim3(4, 128), blk, 0, stream>>>(k, Tk, bk, kt);
    corr_fft_v7<<<dim3(BB * HH * DEPTH), blk, 0, stream>>>(qt, kt);
    out_gemm_mfma<<<dim3(4, 128), blk, 0, stream>>>(kt, To, bo, out);
}

// Round 11
// 125.847 us; speedup vs baseline: 2.7706x; 1.1471x over previous
//
#include <hip/hip_runtime.h>
#include <hip/hip_fp16.h>
#include <float.h>
#include <math.h>

#define BB 8
#define LL 2048
#define NN 2048
#define MM 1024
#define DD 512
#define HH 8
#define DEPTH 64
#define TOPK 15
#define PIF 3.14159265358979323846f

#define PD(i) ((i) + ((i) >> 5))

using f16x8 = __attribute__((ext_vector_type(8))) _Float16;
typedef __attribute__((ext_vector_type(4))) float f32x4;
typedef __attribute__((ext_vector_type(8))) unsigned short us8;
typedef __attribute__((ext_vector_type(4))) unsigned short us4;

__device__ __forceinline__ unsigned short f2h(float f) {
    return __half_as_ushort(__float2half(f));
}
__device__ __forceinline__ float h2f(unsigned short u) {
    return (float)__builtin_bit_cast(_Float16, u);
}
__device__ __forceinline__ float2 cmul(float2 a, float2 b) {
    return make_float2(a.x * b.x - a.y * b.y, a.x * b.y + a.y * b.x);
}
__device__ __forceinline__ float2 cmulc(float2 a, float2 b) {
    return make_float2(a.x * b.x + a.y * b.y, a.y * b.x - a.x * b.y);
}
__device__ __forceinline__ float2 cadd(float2 a, float2 b) { return make_float2(a.x + b.x, a.y + b.y); }
__device__ __forceinline__ float2 csub(float2 a, float2 b) { return make_float2(a.x - b.x, a.y - b.y); }

__device__ __forceinline__ void xcd_swizzle_512(int bx, int by, int& obx, int& oby) {
    int flat = by * 4 + bx;
    int xcd = flat & 7;
    int pos = flat >> 3;
    int nid = xcd * 64 + pos;  // bijective: 512 = 8 * 64
    obx = nid & 3;
    oby = nid >> 2;
}

// ---------------- W transpose + fp32->fp16 convert ----------------
__global__ __launch_bounds__(256) void wt_convert(const float* __restrict__ Wq,
                                                  const float* __restrict__ Wk,
                                                  const float* __restrict__ Wo,
                                                  unsigned short* __restrict__ Tq,
                                                  unsigned short* __restrict__ Tk,
                                                  unsigned short* __restrict__ To) {
    __shared__ float T[64][65];
    const float* src = blockIdx.z == 0 ? Wq : (blockIdx.z == 1 ? Wk : Wo);
    unsigned short* dst = blockIdx.z == 0 ? Tq : (blockIdx.z == 1 ? Tk : To);
    const int tid = threadIdx.x;
    const int r0 = blockIdx.y * 64, c0 = blockIdx.x * 64;
#pragma unroll
    for (int p = 0; p < 4; ++p) {
        int idx = tid + 256 * p;
        int row = idx >> 4, c4 = idx & 15;
        float4 v = *reinterpret_cast<const float4*>(&src[(size_t)(r0 + row) * DD + c0 + c4 * 4]);
        T[row][c4 * 4 + 0] = v.x;
        T[row][c4 * 4 + 1] = v.y;
        T[row][c4 * 4 + 2] = v.z;
        T[row][c4 * 4 + 3] = v.w;
    }
    __syncthreads();
#pragma unroll
    for (int p = 0; p < 4; ++p) {
        int idx = tid + 256 * p;
        int orow = idx >> 4, oc4 = idx & 15;
        us4 o;
#pragma unroll
        for (int j = 0; j < 4; ++j) o[j] = f2h(T[oc4 * 4 + j][orow]);
        *reinterpret_cast<us4*>(&dst[(size_t)(c0 + orow) * DD + r0 + oc4 * 4]) = o;
    }
}

// ---------------- MERGED projection GEMMs (z=0: q, z=1: k), operand-swapped ----------------
__global__ __launch_bounds__(256) void proj_gemm2(const float* __restrict__ Xq,
                                                  const float* __restrict__ Xk,
                                                  const unsigned short* __restrict__ Tq,
                                                  const unsigned short* __restrict__ Tk,
                                                  const float* __restrict__ bq,
                                                  const float* __restrict__ bk,
                                                  unsigned short* __restrict__ qt,
                                                  unsigned short* __restrict__ kt) {
    const float* X = blockIdx.z == 0 ? Xq : Xk;
    const unsigned short* Wt = blockIdx.z == 0 ? Tq : Tk;
    const float* bias = blockIdx.z == 0 ? bq : bk;
    unsigned short* outT = blockIdx.z == 0 ? qt : kt;

    __shared__ unsigned short Asm[128][40];  // X tile: [l][k]
    __shared__ unsigned short Bsm[128][40];  // Wt tile: [c][k]
    const int tid = threadIdx.x;
    const int lane = tid & 63, wid = tid >> 6;
    const int wM = wid & 1, wN = wid >> 1;
    const int g = lane >> 4, rl = lane & 15;
    int sbx, sby;
    xcd_swizzle_512(blockIdx.x, blockIdx.y, sbx, sby);
    const int r0 = sby * 128, c0 = sbx * 128;
    f32x4 acc[4][4];
#pragma unroll
    for (int m = 0; m < 4; ++m)
#pragma unroll
        for (int n = 0; n < 4; ++n) acc[m][n] = (f32x4){0.f, 0.f, 0.f, 0.f};

    for (int k0 = 0; k0 < DD; k0 += 32) {
        float4 av[4];
#pragma unroll
        for (int p = 0; p < 4; ++p) {
            int idx = tid + 256 * p;
            int row = idx >> 3, kq = idx & 7;
            av[p] = *reinterpret_cast<const float4*>(&X[(size_t)(r0 + row) * DD + k0 + kq * 4]);
        }
        us8 bv[2];
#pragma unroll
        for (int p = 0; p < 2; ++p) {
            int idx = tid + 256 * p;
            int row = idx >> 2, kq = idx & 3;
            bv[p] = *reinterpret_cast<const us8*>(&Wt[(size_t)(c0 + row) * DD + k0 + kq * 8]);
        }
        __syncthreads();
#pragma unroll
        for (int p = 0; p < 4; ++p) {
            int idx = tid + 256 * p;
            int row = idx >> 3, kq = idx & 7;
            us4 w;
            w[0] = f2h(av[p].x); w[1] = f2h(av[p].y); w[2] = f2h(av[p].z); w[3] = f2h(av[p].w);
            *reinterpret_cast<us4*>(&Asm[row][kq * 4]) = w;
        }
#pragma unroll
        for (int p = 0; p < 2; ++p) {
            int idx = tid + 256 * p;
            int row = idx >> 2, kq = idx & 3;
            *reinterpret_cast<us8*>(&Bsm[row][kq * 8]) = bv[p];
        }
        __syncthreads();
        f16x8 af[4], bfr[4];
#pragma unroll
        for (int m = 0; m < 4; ++m)
            af[m] = *reinterpret_cast<const f16x8*>(&Bsm[wM * 64 + m * 16 + rl][g * 8]);
#pragma unroll
        for (int n = 0; n < 4; ++n)
            bfr[n] = *reinterpret_cast<const f16x8*>(&Asm[wN * 64 + n * 16 + rl][g * 8]);
#pragma unroll
        for (int m = 0; m < 4; ++m)
#pragma unroll
            for (int n = 0; n < 4; ++n)
                acc[m][n] = __builtin_amdgcn_mfma_f32_16x16x32_f16(af[m], bfr[n], acc[m][n], 0, 0, 0);
    }

    const int b = r0 >> 11, l0 = r0 & (LL - 1);
#pragma unroll
    for (int m = 0; m < 4; ++m) {
        int cb = c0 + wM * 64 + m * 16 + g * 4;
        float4 bv4 = *reinterpret_cast<const float4*>(&bias[cb]);
        const float bja[4] = {bv4.x, bv4.y, bv4.z, bv4.w};
#pragma unroll
        for (int j = 0; j < 4; ++j) {
            int c = cb + j;
            int h = c >> 6, dd = c & 63;
            unsigned short* orow = &outT[((size_t)(b * HH + h) * DEPTH + dd) * LL];
#pragma unroll
            for (int n = 0; n < 4; ++n) {
                int l = l0 + wN * 64 + n * 16 + rl;
                orow[l] = f2h(acc[m][n][j] + bja[j]);
            }
        }
    }
}

// ---------------- correlation v8: radix-8 forward, vectorized aggregation ----------------
__global__ __launch_bounds__(256) void corr_fft_v8(const unsigned short* __restrict__ qt,
                                                   unsigned short* __restrict__ kt) {
    __shared__ float zr[2112], zi[2112];
    __shared__ float twr[1056], twi[1056];  // tw[j] = exp(-i*pi*j/1024)
    __shared__ float sLB[4];
    __shared__ int cnt;
    __shared__ float corr_s[TOPK];
    __shared__ int topi_s[TOPK];
    const int tid = threadIdx.x;
    const int lane = tid & 63, wid = tid >> 6;
    const size_t base = (size_t)blockIdx.x * NN;
    const float R2 = 0.70710678118654752f;

#define LD2(i) make_float2(zr[i], zi[i])
#define ST2(i, v) do { zr[i] = (v).x; zi[i] = (v).y; } while (0)

    // ---- load; bit-reversed scatter; twiddle init ----
    {
        us8 qa = *reinterpret_cast<const us8*>(qt + base + 8 * tid);
        us8 ka = *reinterpret_cast<const us8*>(kt + base + 8 * tid);
        f16x8 qh = __builtin_bit_cast(f16x8, qa);
        f16x8 kh = __builtin_bit_cast(f16x8, ka);
        int pb = (int)(__brev((unsigned)tid) >> 24);
        const int b3[8] = {0, 4, 2, 6, 1, 5, 3, 7};
#pragma unroll
        for (int u = 0; u < 8; ++u) {
            int pf = b3[u] * 256 + pb;
            zr[PD(pf)] = (float)qh[u];
            zi[PD(pf)] = (float)kh[u];
        }
#pragma unroll
        for (int v = 0; v < 4; ++v) {
            int j = tid + 256 * v;
            float sn, cs;
            __sincosf(-PIF * (float)j * (1.f / 1024.f), &sn, &cs);
            twr[PD(j)] = cs;
            twi[PD(j)] = sn;
        }
    }
    __syncthreads();

    // ---- forward DIT: radix-8 pass hh=1 (all twiddles trivial) ----
    {
        int i0 = tid << 3;
        float2 z[8];
#pragma unroll
        for (int u = 0; u < 8; ++u) z[u] = LD2(PD(i0 + u));
        // stage A (stride 1), w=1
#pragma unroll
        for (int a = 0; a < 4; ++a) {
            float2 tv = z[2 * a + 1];
            z[2 * a + 1] = csub(z[2 * a], tv);
            z[2 * a] = cadd(z[2 * a], tv);
        }
        // stage B (stride 2): even u0 w=1, odd u0 w=-i
        {
            const int u0a[4] = {0, 1, 4, 5};
#pragma unroll
            for (int kk = 0; kk < 4; ++kk) {
                int u0 = u0a[kk];
                float2 s = z[u0 + 2];
                float2 tv = (kk & 1) ? make_float2(s.y, -s.x) : s;
                z[u0 + 2] = csub(z[u0], tv);
                z[u0] = cadd(z[u0], tv);
            }
        }
        // stage C (stride 4): w = {1, omega, -i, -i*omega}
        {
            float2 tv;
            tv = z[4];                                              z[4] = csub(z[0], tv); z[0] = cadd(z[0], tv);
            tv = cmul(z[5], make_float2(R2, -R2));                  z[5] = csub(z[1], tv); z[1] = cadd(z[1], tv);
            { float2 s = z[6]; tv = make_float2(s.y, -s.x); }       z[6] = csub(z[2], tv); z[2] = cadd(z[2], tv);
            tv = cmul(z[7], make_float2(-R2, -R2));                 z[7] = csub(z[3], tv); z[3] = cadd(z[3], tv);
        }
#pragma unroll
        for (int u = 0; u < 8; ++u) ST2(PD(i0 + u), z[u]);
    }
    __syncthreads();

    // ---- radix-8 passes hh=8, 64 (table twiddles) ----
#pragma unroll
    for (int hh = 8; hh <= 64; hh <<= 3) {
        int p = tid & (hh - 1);
        int i0 = ((tid ^ p) << 3) | p;
        float2 z[8];
#pragma unroll
        for (int u = 0; u < 8; ++u) z[u] = LD2(PD(i0 + hh * u));
        int ja = PD(p * (1024 / hh));
        float2 wa = make_float2(twr[ja], twi[ja]);
        int jb = PD(p * (512 / hh));
        float2 wb = make_float2(twr[jb], twi[jb]);
        int jc = PD(p * (256 / hh));
        float2 wc = make_float2(twr[jc], twi[jc]);
        // stage A (stride hh)
#pragma unroll
        for (int a = 0; a < 4; ++a) {
            float2 tv = cmul(z[2 * a + 1], wa);
            z[2 * a + 1] = csub(z[2 * a], tv);
            z[2 * a] = cadd(z[2 * a], tv);
        }
        // stage B (stride 2hh)
        {
            float2 wbn = make_float2(wb.y, -wb.x);  // -i*wb
            const int u0a[4] = {0, 1, 4, 5};
#pragma unroll
            for (int kk = 0; kk < 4; ++kk) {
                int u0 = u0a[kk];
                float2 w = (kk & 1) ? wbn : wb;
                float2 tv = cmul(z[u0 + 2], w);
                z[u0 + 2] = csub(z[u0], tv);
                z[u0] = cadd(z[u0], tv);
            }
        }
        // stage C (stride 4hh): wc * omega^u0
        {
            float2 wt0 = wc;
            float2 wt1 = cmul(wc, make_float2(R2, -R2));
            float2 wt2 = make_float2(wc.y, -wc.x);
            float2 wt3 = cmul(wc, make_float2(-R2, -R2));
            float2 tv;
            tv = cmul(z[4], wt0); z[4] = csub(z[0], tv); z[0] = cadd(z[0], tv);
            tv = cmul(z[5], wt1); z[5] = csub(z[1], tv); z[1] = cadd(z[1], tv);
            tv = cmul(z[6], wt2); z[6] = csub(z[2], tv); z[2] = cadd(z[2], tv);
            tv = cmul(z[7], wt3); z[7] = csub(z[3], tv); z[3] = cadd(z[3], tv);
        }
#pragma unroll
        for (int u = 0; u < 8; ++u) ST2(PD(i0 + hh * u), z[u]);
        __syncthreads();
    }

    // ---- register radix-4 tail: stages 512, 1024 on {tid+256u} ----
    {
        float2 z[8];
#pragma unroll
        for (int u = 0; u < 8; ++u) z[u] = LD2(PD(tid + 256 * u));
        {  // stage h=512: pairs (0,2),(1,3),(4,6),(5,7); w = tw[2*tid]*(-i)^(u0&1)
            int j = PD(2 * tid);
            float2 wb = make_float2(twr[j], twi[j]);
            float2 wbn = make_float2(wb.y, -wb.x);
            const int u0a[4] = {0, 1, 4, 5};
#pragma unroll
            for (int kk = 0; kk < 4; ++kk) {
                int u0 = u0a[kk];
                float2 w = (kk & 1) ? wbn : wb;
                float2 tv = cmul(z[u0 + 2], w);
                z[u0 + 2] = csub(z[u0], tv);
                z[u0] = cadd(z[u0], tv);
            }
        }
        {  // stage h=1024: pairs (u,u+4); w = tw[tid]*omega^u
            int j = PD(tid);
            float2 wc = make_float2(twr[j], twi[j]);
            float2 wt0 = wc;
            float2 wt1 = cmul(wc, make_float2(R2, -R2));
            float2 wt2 = make_float2(wc.y, -wc.x);
            float2 wt3 = cmul(wc, make_float2(-R2, -R2));
            float2 tv;
            tv = cmul(z[4], wt0); z[4] = csub(z[0], tv); z[0] = cadd(z[0], tv);
            tv = cmul(z[5], wt1); z[5] = csub(z[1], tv); z[1] = cadd(z[1], tv);
            tv = cmul(z[6], wt2); z[6] = csub(z[2], tv); z[2] = cadd(z[2], tv);
            tv = cmul(z[7], wt3); z[7] = csub(z[3], tv); z[3] = cadd(z[3], tv);
        }
#pragma unroll
        for (int u = 0; u < 8; ++u) ST2(PD(tid + 256 * u), z[u]);
    }
    __syncthreads();

    // ---- FUSED: Hermitian unpack + S=Q*conj(K) + irfft combine + inverse quad hh=256 ----
    {
        float2 W[4];
#pragma unroll
        for (int u = 0; u < 4; ++u) {
            int m = tid + 256 * u;
            int mf1 = (NN - m) & (NN - 1);
            float2 Zf = LD2(PD(m)), Zm = LD2(PD(mf1));
            float2 Qf = make_float2(0.5f * (Zf.x + Zm.x), 0.5f * (Zf.y - Zm.y));
            float2 Dm = make_float2(Zf.x - Zm.x, Zf.y + Zm.y);
            float2 Kf = make_float2(0.5f * Dm.y, -0.5f * Dm.x);
            float2 S1 = cmulc(Qf, Kf);
            float2 Zf2 = LD2(PD(m + MM)), Zm2 = LD2(PD(MM - m));
            float2 Qf2 = make_float2(0.5f * (Zf2.x + Zm2.x), 0.5f * (Zf2.y - Zm2.y));
            float2 Dm2 = make_float2(Zf2.x - Zm2.x, Zf2.y + Zm2.y);
            float2 Kf2 = make_float2(0.5f * Dm2.y, -0.5f * Dm2.x);
            float2 S2 = cmulc(Qf2, Kf2);
            float2 E = cadd(S1, S2), Od = csub(S1, S2);
            int jm = PD(m);
            float2 ph = make_float2(twr[jm], -twi[jm]);
            float2 T = cmul(ph, Od);
            W[u] = make_float2(E.x - T.y, E.y + T.x);
        }
        int j = PD(2 * tid);
        float2 w = make_float2(twr[j], -twi[j]);
        float2 w2 = make_float2(w.x * w.x - w.y * w.y, 2.f * w.x * w.y);
        float2 S0 = cadd(W[0], W[2]);
        float2 D0 = cmul(csub(W[0], W[2]), w);
        float2 S1q = cadd(W[1], W[3]);
        float2 ff = cmul(csub(W[1], W[3]), w);
        float2 D1 = make_float2(-ff.y, ff.x);
        float2 o0 = cadd(S0, S1q);
        float2 o1 = cmul(csub(S0, S1q), w2);
        float2 o2 = cadd(D0, D1);
        float2 o3 = cmul(csub(D0, D1), w2);
        __syncthreads();
        ST2(PD(tid), o0);
        ST2(PD(tid + 256), o1);
        ST2(PD(tid + 512), o2);
        ST2(PD(tid + 768), o3);
    }
    __syncthreads();

    // ---- inverse DIF quads hh=64,16,4 ----
#pragma unroll
    for (int hh = 64; hh >= 4; hh >>= 2) {
        const int step = 512 / hh;
        int p = tid & (hh - 1);
        int i0 = ((tid ^ p) << 2) | p;
        int e0 = PD(i0), e1 = PD(i0 + hh), e2 = PD(i0 + 2 * hh), e3 = PD(i0 + 3 * hh);
        float2 a = LD2(e0), b = LD2(e1), c = LD2(e2), d = LD2(e3);
        int jt = PD(p * step);
        float2 w = make_float2(twr[jt], -twi[jt]);
        float2 w2 = make_float2(w.x * w.x - w.y * w.y, 2.f * w.x * w.y);
        float2 S0 = cadd(a, c);
        float2 D0 = cmul(csub(a, c), w);
        float2 S1 = cadd(b, d);
        float2 ff = cmul(csub(b, d), w);
        float2 D1 = make_float2(-ff.y, ff.x);
        ST2(e0, cadd(S0, S1));
        ST2(e1, cmul(csub(S0, S1), w2));
        ST2(e2, cadd(D0, D1));
        ST2(e3, cmul(csub(D0, D1), w2));
        __syncthreads();
    }
    float r[8];
    int tau[8];
    {
        float2 a = LD2(PD(4 * tid)), b = LD2(PD(4 * tid + 1));
        float2 c = LD2(PD(4 * tid + 2)), d = LD2(PD(4 * tid + 3));
        float2 S0 = cadd(a, c), D0 = csub(a, c);
        float2 S1 = cadd(b, d);
        float2 bd = csub(b, d);
        float2 D1 = make_float2(-bd.y, bd.x);
        float2 z0 = cadd(S0, S1);
        float2 z1 = csub(S0, S1);
        float2 z2 = cadd(D0, D1);
        float2 z3 = csub(D0, D1);
        const int pb = (int)(__brev((unsigned)tid) >> 24);
        const float sc = 1.0f / (float)NN;
        int m0 = pb, m1 = 512 + pb, m2 = 256 + pb, m3 = 768 + pb;
        r[0] = z0.x * sc; tau[0] = 2 * m0;
        r[1] = z0.y * sc; tau[1] = 2 * m0 + 1;
        r[2] = z1.x * sc; tau[2] = 2 * m1;
        r[3] = z1.y * sc; tau[3] = 2 * m1 + 1;
        r[4] = z2.x * sc; tau[4] = 2 * m2;
        r[5] = z2.y * sc; tau[5] = 2 * m2 + 1;
        r[6] = z3.x * sc; tau[6] = 2 * m3;
        r[7] = z3.y * sc; tau[7] = 2 * m3 + 1;
    }

    // ---- top-15: LB prune + gather + bitonic (unchanged from R9) ----
    {
        float lmax = r[0];
#pragma unroll
        for (int u = 1; u < 8; ++u) lmax = fmaxf(lmax, r[u]);
        float sv = lmax;
#pragma unroll
        for (int k = 2; k <= 64; k <<= 1) {
#pragma unroll
            for (int j = k >> 1; j > 0; j >>= 1) {
                float ov = __shfl_xor(sv, j);
                bool lower = (lane & j) == 0;
                bool dirAsc = (lane & k) == 0;
                bool myMinKey = sv > ov;
                bool keepMine = (dirAsc == lower) ? myMinKey : !myMinKey;
                sv = keepMine ? sv : ov;
            }
        }
        float LBw = __shfl(sv, 14);
        if (lane == 0) sLB[wid] = LBw;
        if (tid == 0) cnt = 0;
    }
    __syncthreads();
    {
        float LB = fmaxf(fmaxf(sLB[0], sLB[1]), fmaxf(sLB[2], sLB[3]));
#pragma unroll
        for (int u = 0; u < 8; ++u) {
            if (r[u] >= LB) {
                int slot = atomicAdd(&cnt, 1);
                zr[slot] = r[u];
                zi[slot] = __int_as_float(tau[u]);
            }
        }
    }
    __syncthreads();
    const int ncand = cnt;
    if (tid < 64) {
        float cv;
        int ci;
        if (ncand <= 64) {
            cv = (lane < ncand) ? zr[lane] : -FLT_MAX;
            ci = (lane < ncand) ? __float_as_int(zi[lane]) : 0x7fffffff;
#pragma unroll
            for (int k = 2; k <= 64; k <<= 1) {
#pragma unroll
                for (int j = k >> 1; j > 0; j >>= 1) {
                    float ov = __shfl_xor(cv, j);
                    int oi = __shfl_xor(ci, j);
                    bool lower = (lane & j) == 0;
                    bool dirAsc = (lane & k) == 0;
                    bool myMinKey = (cv > ov) || (cv == ov && ci < oi);
                    bool keepMine = (dirAsc == lower) ? myMinKey : !myMinKey;
                    cv = keepMine ? cv : ov;
                    ci = keepMine ? ci : oi;
                }
            }
        } else {
            float keep_v = -FLT_MAX;
            int keep_i = 0x7fffffff;
            for (int it = 0; it < TOPK; ++it) {
                float bv = -FLT_MAX;
                int bi = 0x7fffffff, bs = 0;
                for (int s = lane; s < ncand; s += 64) {
                    float v = zr[s];
                    int ii = __float_as_int(zi[s]);
                    if (v > bv || (v == bv && ii < bi)) { bv = v; bi = ii; bs = s; }
                }
#pragma unroll
                for (int off = 32; off >= 1; off >>= 1) {
                    float ov = __shfl_xor(bv, off);
                    int oi = __shfl_xor(bi, off);
                    int os = __shfl_xor(bs, off);
                    if (ov > bv || (ov == bv && oi < bi)) { bv = ov; bi = oi; bs = os; }
                }
                if ((bs & 63) == lane) zr[bs] = -FLT_MAX;
                if (lane == it) { keep_v = bv; keep_i = bi; }
            }
            cv = keep_v;
            ci = keep_i;
        }
        float m0 = __shfl(cv, 0);
        float e = (lane < TOPK) ? expf(cv - m0) : 0.f;
        float ssum = e;
#pragma unroll
        for (int off = 32; off >= 1; off >>= 1) ssum += __shfl_xor(ssum, off);
        if (lane < TOPK) {
            corr_s[lane] = e / ssum;
            topi_s[lane] = ci;
        }
    }
    __syncthreads();

    // ---- aggregation: 8 consecutive t per thread; 2 aligned us8 loads + uniform select ----
    {
        const unsigned short* qrow = qt + base;
        const int t0 = tid << 3;
        float acc8[8] = {0.f, 0.f, 0.f, 0.f, 0.f, 0.f, 0.f, 0.f};
        for (int i = 0; i < TOPK; ++i) {
            const float w = corr_s[i];
            const int d = topi_s[i];
            const int s = (t0 + d) & (NN - 1);
            const int a0 = s & ~7;
            const int o = s & 7;  // wave-uniform (t0 % 8 == 0, d uniform)
            us8 A = *reinterpret_cast<const us8*>(qrow + a0);
            us8 Bv = *reinterpret_cast<const us8*>(qrow + ((a0 + 8) & (NN - 1)));
            switch (o) {
#define AGG_CASE(O)                                                              \
    case O: {                                                                    \
        _Pragma("unroll") for (int j = 0; j < 8; ++j) {                          \
            unsigned short e = ((O) + j < 8) ? A[(O) + j] : Bv[(O) + j - 8];     \
            acc8[j] += w * h2f(e);                                               \
        }                                                                        \
    } break;
                AGG_CASE(0) AGG_CASE(1) AGG_CASE(2) AGG_CASE(3)
                AGG_CASE(4) AGG_CASE(5) AGG_CASE(6) AGG_CASE(7)
#undef AGG_CASE
            }
        }
        us8 o8;
#pragma unroll
        for (int j = 0; j < 8; ++j) o8[j] = f2h(acc8[j]);
        *reinterpret_cast<us8*>(kt + base + t0) = o8;
    }
#undef LD2
#undef ST2
}

// ---------------- output GEMM, fp16 MFMA (pad 134 -> conflict-free extract) ----------------
__global__ __launch_bounds__(256) void out_gemm_mfma(const unsigned short* __restrict__ db,
                                                     const unsigned short* __restrict__ WtO,
                                                     const float* __restrict__ bias,
                                                     float* __restrict__ out) {
    __shared__ unsigned short Asm[32][134];  // stride 67 dwords: extract banks all-distinct
    __shared__ unsigned short Bsm[128][40];
    const int tid = threadIdx.x;
    const int lane = tid & 63, wid = tid >> 6;
    const int wr = wid >> 1, wc = wid & 1;
    const int g = lane >> 4, rl = lane & 15;
    int sbx, sby;
    xcd_swizzle_512(blockIdx.x, blockIdx.y, sbx, sby);
    const int r0 = sby * 128, c0 = sbx * 128;
    const int b = r0 >> 11, l0 = r0 & (LL - 1);
    f32x4 acc[4][4];
#pragma unroll
    for (int m = 0; m < 4; ++m)
#pragma unroll
        for (int n = 0; n < 4; ++n) acc[m][n] = (f32x4){0.f, 0.f, 0.f, 0.f};

    for (int k0 = 0; k0 < DD; k0 += 32) {
        us8 avv[2], bvv[2];
#pragma unroll
        for (int p = 0; p < 2; ++p) {
            int idx = tid + 256 * p;
            int kr = idx >> 4, dc = idx & 15;
            avv[p] = *reinterpret_cast<const us8*>(
                &db[(size_t)(b * DD + k0 + kr) * 2048 + l0 + dc * 8]);
        }
#pragma unroll
        for (int p = 0; p < 2; ++p) {
            int idx = tid + 256 * p;
            int row = idx >> 2, kq = idx & 3;
            bvv[p] = *reinterpret_cast<const us8*>(&WtO[(size_t)(c0 + row) * DD + k0 + kq * 8]);
        }
        __syncthreads();
#pragma unroll
        for (int p = 0; p < 2; ++p) {
            int idx = tid + 256 * p;
            int kr = idx >> 4, dc = idx & 15;
            us4 lo, hi;
#pragma unroll
            for (int j = 0; j < 4; ++j) { lo[j] = avv[p][j]; hi[j] = avv[p][j + 4]; }
            *reinterpret_cast<us4*>(&Asm[kr][dc * 8]) = lo;
            *reinterpret_cast<us4*>(&Asm[kr][dc * 8 + 4]) = hi;
        }
#pragma unroll
        for (int p = 0; p < 2; ++p) {
            int idx = tid + 256 * p;
            int row = idx >> 2, kq = idx & 3;
            *reinterpret_cast<us8*>(&Bsm[row][kq * 8]) = bvv[p];
        }
        __syncthreads();
        f16x8 af[4], bfr[4];
#pragma unroll
        for (int m = 0; m < 4; ++m) {
            int l = wr * 64 + m * 16 + rl;
            us8 t;
#pragma unroll
            for (int j = 0; j < 8; ++j) t[j] = Asm[g * 8 + j][l];
            af[m] = __builtin_bit_cast(f16x8, t);
        }
#pragma unroll
        for (int n = 0; n < 4; ++n)
            bfr[n] = *reinterpret_cast<const f16x8*>(&Bsm[wc * 64 + n * 16 + rl][g * 8]);
#pragma unroll
        for (int m = 0; m < 4; ++m)
#pragma unroll
            for (int n = 0; n < 4; ++n)
                acc[m][n] = __builtin_amdgcn_mfma_f32_16x16x32_f16(af[m], bfr[n], acc[m][n], 0, 0, 0);
    }

#pragma unroll
    for (int m = 0; m < 4; ++m) {
#pragma unroll
        for (int n = 0; n < 4; ++n) {
            int c = c0 + wc * 64 + n * 16 + rl;
            float bvv = bias[c];
            int rbase = r0 + wr * 64 + m * 16 + g * 4;
#pragma unroll
            for (int j = 0; j < 4; ++j)
                out[(size_t)(rbase + j) * DD + c] = acc[m][n][j] + bvv;
        }
    }
}

extern "C" void kernel_launch(void* const* d_in, const int* in_sizes, int n_in,
                              void* d_out, int out_size, void* d_ws, size_t ws_size,
                              hipStream_t stream) {
    const float* q = (const float*)d_in[0];
    const float* k = (const float*)d_in[1];
    const float* Wq = (const float*)d_in[3];
    const float* bq = (const float*)d_in[4];
    const float* Wk = (const float*)d_in[5];
    const float* bk = (const float*)d_in[6];
    const float* Wo = (const float*)d_in[9];
    const float* bo = (const float*)d_in[10];
    float* out = (float*)d_out;

    unsigned short* qt = (unsigned short*)d_ws;
    unsigned short* kt = qt + (size_t)BB * HH * DEPTH * LL;
    unsigned short* Tq = kt + (size_t)BB * HH * DEPTH * LL;
    unsigned short* Tk = Tq + (size_t)DD * DD;
    unsigned short* To = Tk + (size_t)DD * DD;

    dim3 blk(256);
    wt_convert<<<dim3(8, 8, 3), blk, 0, stream>>>(Wq, Wk, Wo, Tq, Tk, To);
    proj_gemm2<<<dim3(4, 128, 2), blk, 0, stream>>>(q, k, Tq, Tk, bq, bk, qt, kt);
    corr_fft_v8<<<dim3(BB * HH * DEPTH), blk, 0, stream>>>(qt, kt);
    out_gemm_mfma<<<dim3(4, 128), blk, 0, stream>>>(kt, To, bo, out);
}

// Round 12
// 117.098 us; speedup vs baseline: 2.9776x; 1.0747x over previous
//
#include <hip/hip_runtime.h>
#include <hip/hip_fp16.h>
#include <float.h>
#include <math.h>

#define BB 8
#define LL 2048
#define NN 2048
#define MM 1024
#define DD 512
#define HH 8
#define DEPTH 64
#define TOPK 15
#define PIF 3.14159265358979323846f

#define PD(i) ((i) + ((i) >> 5))

using f16x8 = __attribute__((ext_vector_type(8))) _Float16;
typedef __attribute__((ext_vector_type(4))) float f32x4;
typedef __attribute__((ext_vector_type(8))) unsigned short us8;
typedef __attribute__((ext_vector_type(4))) unsigned short us4;

__device__ __forceinline__ unsigned short f2h(float f) {
    return __half_as_ushort(__float2half(f));
}
__device__ __forceinline__ float h2f(unsigned short u) {
    return (float)__builtin_bit_cast(_Float16, u);
}
__device__ __forceinline__ float2 cmul(float2 a, float2 b) {
    return make_float2(a.x * b.x - a.y * b.y, a.x * b.y + a.y * b.x);
}
__device__ __forceinline__ float2 cmulc(float2 a, float2 b) {
    return make_float2(a.x * b.x + a.y * b.y, a.y * b.x - a.x * b.y);
}
__device__ __forceinline__ float2 cadd(float2 a, float2 b) { return make_float2(a.x + b.x, a.y + b.y); }
__device__ __forceinline__ float2 csub(float2 a, float2 b) { return make_float2(a.x - b.x, a.y - b.y); }

__device__ __forceinline__ void xcd_swizzle_512(int bx, int by, int& obx, int& oby) {
    int flat = by * 4 + bx;
    int xcd = flat & 7;
    int pos = flat >> 3;
    int nid = xcd * 64 + pos;  // bijective: 512 = 8 * 64
    obx = nid & 3;
    oby = nid >> 2;
}

// ---------------- W transpose + fp32->fp16 convert ----------------
__global__ __launch_bounds__(256) void wt_convert(const float* __restrict__ Wq,
                                                  const float* __restrict__ Wk,
                                                  const float* __restrict__ Wo,
                                                  unsigned short* __restrict__ Tq,
                                                  unsigned short* __restrict__ Tk,
                                                  unsigned short* __restrict__ To) {
    __shared__ float T[64][65];
    const float* src = blockIdx.z == 0 ? Wq : (blockIdx.z == 1 ? Wk : Wo);
    unsigned short* dst = blockIdx.z == 0 ? Tq : (blockIdx.z == 1 ? Tk : To);
    const int tid = threadIdx.x;
    const int r0 = blockIdx.y * 64, c0 = blockIdx.x * 64;
#pragma unroll
    for (int p = 0; p < 4; ++p) {
        int idx = tid + 256 * p;
        int row = idx >> 4, c4 = idx & 15;
        float4 v = *reinterpret_cast<const float4*>(&src[(size_t)(r0 + row) * DD + c0 + c4 * 4]);
        T[row][c4 * 4 + 0] = v.x;
        T[row][c4 * 4 + 1] = v.y;
        T[row][c4 * 4 + 2] = v.z;
        T[row][c4 * 4 + 3] = v.w;
    }
    __syncthreads();
#pragma unroll
    for (int p = 0; p < 4; ++p) {
        int idx = tid + 256 * p;
        int orow = idx >> 4, oc4 = idx & 15;
        us4 o;
#pragma unroll
        for (int j = 0; j < 4; ++j) o[j] = f2h(T[oc4 * 4 + j][orow]);
        *reinterpret_cast<us4*>(&dst[(size_t)(c0 + orow) * DD + r0 + oc4 * 4]) = o;
    }
}

// ---------------- MERGED projection GEMMs (z=0: q, z=1: k), prefetched k-loop ----------------
__global__ __launch_bounds__(256) void proj_gemm2(const float* __restrict__ Xq,
                                                  const float* __restrict__ Xk,
                                                  const unsigned short* __restrict__ Tq,
                                                  const unsigned short* __restrict__ Tk,
                                                  const float* __restrict__ bq,
                                                  const float* __restrict__ bk,
                                                  unsigned short* __restrict__ qt,
                                                  unsigned short* __restrict__ kt) {
    const float* X = blockIdx.z == 0 ? Xq : Xk;
    const unsigned short* Wt = blockIdx.z == 0 ? Tq : Tk;
    const float* bias = blockIdx.z == 0 ? bq : bk;
    unsigned short* outT = blockIdx.z == 0 ? qt : kt;

    __shared__ unsigned short Asm[128][40];  // X tile: [l][k]
    __shared__ unsigned short Bsm[128][40];  // Wt tile: [c][k]
    const int tid = threadIdx.x;
    const int lane = tid & 63, wid = tid >> 6;
    const int wM = wid & 1, wN = wid >> 1;
    const int g = lane >> 4, rl = lane & 15;
    int sbx, sby;
    xcd_swizzle_512(blockIdx.x, blockIdx.y, sbx, sby);
    const int r0 = sby * 128, c0 = sbx * 128;
    f32x4 acc[4][4];
#pragma unroll
    for (int m = 0; m < 4; ++m)
#pragma unroll
        for (int n = 0; n < 4; ++n) acc[m][n] = (f32x4){0.f, 0.f, 0.f, 0.f};

    // prologue: load tile k0=0 into registers
    float4 av[4];
    us8 bv[2];
#pragma unroll
    for (int p = 0; p < 4; ++p) {
        int idx = tid + 256 * p;
        int row = idx >> 3, kq = idx & 7;
        av[p] = *reinterpret_cast<const float4*>(&X[(size_t)(r0 + row) * DD + kq * 4]);
    }
#pragma unroll
    for (int p = 0; p < 2; ++p) {
        int idx = tid + 256 * p;
        int row = idx >> 2, kq = idx & 3;
        bv[p] = *reinterpret_cast<const us8*>(&Wt[(size_t)(c0 + row) * DD + kq * 8]);
    }

#pragma unroll
    for (int k0 = 0; k0 < DD; k0 += 32) {
        __syncthreads();  // previous iteration's fragment reads done
#pragma unroll
        for (int p = 0; p < 4; ++p) {
            int idx = tid + 256 * p;
            int row = idx >> 3, kq = idx & 7;
            us4 w;
            w[0] = f2h(av[p].x); w[1] = f2h(av[p].y); w[2] = f2h(av[p].z); w[3] = f2h(av[p].w);
            *reinterpret_cast<us4*>(&Asm[row][kq * 4]) = w;
        }
#pragma unroll
        for (int p = 0; p < 2; ++p) {
            int idx = tid + 256 * p;
            int row = idx >> 2, kq = idx & 3;
            *reinterpret_cast<us8*>(&Bsm[row][kq * 8]) = bv[p];
        }
        // prefetch next k-tile: issued BEFORE the barrier/MFMA so HBM latency hides
        if (k0 + 32 < DD) {
#pragma unroll
            for (int p = 0; p < 4; ++p) {
                int idx = tid + 256 * p;
                int row = idx >> 3, kq = idx & 7;
                av[p] = *reinterpret_cast<const float4*>(
                    &X[(size_t)(r0 + row) * DD + (k0 + 32) + kq * 4]);
            }
#pragma unroll
            for (int p = 0; p < 2; ++p) {
                int idx = tid + 256 * p;
                int row = idx >> 2, kq = idx & 3;
                bv[p] = *reinterpret_cast<const us8*>(
                    &Wt[(size_t)(c0 + row) * DD + (k0 + 32) + kq * 8]);
            }
        }
        __syncthreads();
        f16x8 af[4], bfr[4];
#pragma unroll
        for (int m = 0; m < 4; ++m)
            af[m] = *reinterpret_cast<const f16x8*>(&Bsm[wM * 64 + m * 16 + rl][g * 8]);
#pragma unroll
        for (int n = 0; n < 4; ++n)
            bfr[n] = *reinterpret_cast<const f16x8*>(&Asm[wN * 64 + n * 16 + rl][g * 8]);
#pragma unroll
        for (int m = 0; m < 4; ++m)
#pragma unroll
            for (int n = 0; n < 4; ++n)
                acc[m][n] = __builtin_amdgcn_mfma_f32_16x16x32_f16(af[m], bfr[n], acc[m][n], 0, 0, 0);
    }

    const int b = r0 >> 11, l0 = r0 & (LL - 1);
#pragma unroll
    for (int m = 0; m < 4; ++m) {
        int cb = c0 + wM * 64 + m * 16 + g * 4;
        float4 bv4 = *reinterpret_cast<const float4*>(&bias[cb]);
        const float bja[4] = {bv4.x, bv4.y, bv4.z, bv4.w};
#pragma unroll
        for (int j = 0; j < 4; ++j) {
            int c = cb + j;
            int h = c >> 6, dd = c & 63;
            unsigned short* orow = &outT[((size_t)(b * HH + h) * DEPTH + dd) * LL];
#pragma unroll
            for (int n = 0; n < 4; ++n) {
                int l = l0 + wN * 64 + n * 16 + rl;
                orow[l] = f2h(acc[m][n][j] + bja[j]);
            }
        }
    }
}

// ---------------- correlation v8 (unchanged from R11) ----------------
__global__ __launch_bounds__(256) void corr_fft_v8(const unsigned short* __restrict__ qt,
                                                   unsigned short* __restrict__ kt) {
    __shared__ float zr[2112], zi[2112];
    __shared__ float twr[1056], twi[1056];  // tw[j] = exp(-i*pi*j/1024)
    __shared__ float sLB[4];
    __shared__ int cnt;
    __shared__ float corr_s[TOPK];
    __shared__ int topi_s[TOPK];
    const int tid = threadIdx.x;
    const int lane = tid & 63, wid = tid >> 6;
    const size_t base = (size_t)blockIdx.x * NN;
    const float R2 = 0.70710678118654752f;

#define LD2(i) make_float2(zr[i], zi[i])
#define ST2(i, v) do { zr[i] = (v).x; zi[i] = (v).y; } while (0)

    {
        us8 qa = *reinterpret_cast<const us8*>(qt + base + 8 * tid);
        us8 ka = *reinterpret_cast<const us8*>(kt + base + 8 * tid);
        f16x8 qh = __builtin_bit_cast(f16x8, qa);
        f16x8 kh = __builtin_bit_cast(f16x8, ka);
        int pb = (int)(__brev((unsigned)tid) >> 24);
        const int b3[8] = {0, 4, 2, 6, 1, 5, 3, 7};
#pragma unroll
        for (int u = 0; u < 8; ++u) {
            int pf = b3[u] * 256 + pb;
            zr[PD(pf)] = (float)qh[u];
            zi[PD(pf)] = (float)kh[u];
        }
#pragma unroll
        for (int v = 0; v < 4; ++v) {
            int j = tid + 256 * v;
            float sn, cs;
            __sincosf(-PIF * (float)j * (1.f / 1024.f), &sn, &cs);
            twr[PD(j)] = cs;
            twi[PD(j)] = sn;
        }
    }
    __syncthreads();

    // ---- forward DIT: radix-8 pass hh=1 (trivial twiddles) ----
    {
        int i0 = tid << 3;
        float2 z[8];
#pragma unroll
        for (int u = 0; u < 8; ++u) z[u] = LD2(PD(i0 + u));
#pragma unroll
        for (int a = 0; a < 4; ++a) {
            float2 tv = z[2 * a + 1];
            z[2 * a + 1] = csub(z[2 * a], tv);
            z[2 * a] = cadd(z[2 * a], tv);
        }
        {
            const int u0a[4] = {0, 1, 4, 5};
#pragma unroll
            for (int kk = 0; kk < 4; ++kk) {
                int u0 = u0a[kk];
                float2 s = z[u0 + 2];
                float2 tv = (kk & 1) ? make_float2(s.y, -s.x) : s;
                z[u0 + 2] = csub(z[u0], tv);
                z[u0] = cadd(z[u0], tv);
            }
        }
        {
            float2 tv;
            tv = z[4];                                        z[4] = csub(z[0], tv); z[0] = cadd(z[0], tv);
            tv = cmul(z[5], make_float2(R2, -R2));            z[5] = csub(z[1], tv); z[1] = cadd(z[1], tv);
            { float2 s = z[6]; tv = make_float2(s.y, -s.x); } z[6] = csub(z[2], tv); z[2] = cadd(z[2], tv);
            tv = cmul(z[7], make_float2(-R2, -R2));           z[7] = csub(z[3], tv); z[3] = cadd(z[3], tv);
        }
#pragma unroll
        for (int u = 0; u < 8; ++u) ST2(PD(i0 + u), z[u]);
    }
    __syncthreads();

    // ---- radix-8 passes hh=8, 64 ----
#pragma unroll
    for (int hh = 8; hh <= 64; hh <<= 3) {
        int p = tid & (hh - 1);
        int i0 = ((tid ^ p) << 3) | p;
        float2 z[8];
#pragma unroll
        for (int u = 0; u < 8; ++u) z[u] = LD2(PD(i0 + hh * u));
        int ja = PD(p * (1024 / hh));
        float2 wa = make_float2(twr[ja], twi[ja]);
        int jb = PD(p * (512 / hh));
        float2 wb = make_float2(twr[jb], twi[jb]);
        int jc = PD(p * (256 / hh));
        float2 wc = make_float2(twr[jc], twi[jc]);
#pragma unroll
        for (int a = 0; a < 4; ++a) {
            float2 tv = cmul(z[2 * a + 1], wa);
            z[2 * a + 1] = csub(z[2 * a], tv);
            z[2 * a] = cadd(z[2 * a], tv);
        }
        {
            float2 wbn = make_float2(wb.y, -wb.x);
            const int u0a[4] = {0, 1, 4, 5};
#pragma unroll
            for (int kk = 0; kk < 4; ++kk) {
                int u0 = u0a[kk];
                float2 w = (kk & 1) ? wbn : wb;
                float2 tv = cmul(z[u0 + 2], w);
                z[u0 + 2] = csub(z[u0], tv);
                z[u0] = cadd(z[u0], tv);
            }
        }
        {
            float2 wt0 = wc;
            float2 wt1 = cmul(wc, make_float2(R2, -R2));
            float2 wt2 = make_float2(wc.y, -wc.x);
            float2 wt3 = cmul(wc, make_float2(-R2, -R2));
            float2 tv;
            tv = cmul(z[4], wt0); z[4] = csub(z[0], tv); z[0] = cadd(z[0], tv);
            tv = cmul(z[5], wt1); z[5] = csub(z[1], tv); z[1] = cadd(z[1], tv);
            tv = cmul(z[6], wt2); z[6] = csub(z[2], tv); z[2] = cadd(z[2], tv);
            tv = cmul(z[7], wt3); z[7] = csub(z[3], tv); z[3] = cadd(z[3], tv);
        }
#pragma unroll
        for (int u = 0; u < 8; ++u) ST2(PD(i0 + hh * u), z[u]);
        __syncthreads();
    }

    // ---- register radix-4 tail: stages 512, 1024 ----
    {
        float2 z[8];
#pragma unroll
        for (int u = 0; u < 8; ++u) z[u] = LD2(PD(tid + 256 * u));
        {
            int j = PD(2 * tid);
            float2 wb = make_float2(twr[j], twi[j]);
            float2 wbn = make_float2(wb.y, -wb.x);
            const int u0a[4] = {0, 1, 4, 5};
#pragma unroll
            for (int kk = 0; kk < 4; ++kk) {
                int u0 = u0a[kk];
                float2 w = (kk & 1) ? wbn : wb;
                float2 tv = cmul(z[u0 + 2], w);
                z[u0 + 2] = csub(z[u0], tv);
                z[u0] = cadd(z[u0], tv);
            }
        }
        {
            int j = PD(tid);
            float2 wc = make_float2(twr[j], twi[j]);
            float2 wt0 = wc;
            float2 wt1 = cmul(wc, make_float2(R2, -R2));
            float2 wt2 = make_float2(wc.y, -wc.x);
            float2 wt3 = cmul(wc, make_float2(-R2, -R2));
            float2 tv;
            tv = cmul(z[4], wt0); z[4] = csub(z[0], tv); z[0] = cadd(z[0], tv);
            tv = cmul(z[5], wt1); z[5] = csub(z[1], tv); z[1] = cadd(z[1], tv);
            tv = cmul(z[6], wt2); z[6] = csub(z[2], tv); z[2] = cadd(z[2], tv);
            tv = cmul(z[7], wt3); z[7] = csub(z[3], tv); z[3] = cadd(z[3], tv);
        }
#pragma unroll
        for (int u = 0; u < 8; ++u) ST2(PD(tid + 256 * u), z[u]);
    }
    __syncthreads();

    // ---- FUSED: Hermitian unpack + S=Q*conj(K) + irfft combine + inverse quad hh=256 ----
    {
        float2 W[4];
#pragma unroll
        for (int u = 0; u < 4; ++u) {
            int m = tid + 256 * u;
            int mf1 = (NN - m) & (NN - 1);
            float2 Zf = LD2(PD(m)), Zm = LD2(PD(mf1));
            float2 Qf = make_float2(0.5f * (Zf.x + Zm.x), 0.5f * (Zf.y - Zm.y));
            float2 Dm = make_float2(Zf.x - Zm.x, Zf.y + Zm.y);
            float2 Kf = make_float2(0.5f * Dm.y, -0.5f * Dm.x);
            float2 S1 = cmulc(Qf, Kf);
            float2 Zf2 = LD2(PD(m + MM)), Zm2 = LD2(PD(MM - m));
            float2 Qf2 = make_float2(0.5f * (Zf2.x + Zm2.x), 0.5f * (Zf2.y - Zm2.y));
            float2 Dm2 = make_float2(Zf2.x - Zm2.x, Zf2.y + Zm2.y);
            float2 Kf2 = make_float2(0.5f * Dm2.y, -0.5f * Dm2.x);
            float2 S2 = cmulc(Qf2, Kf2);
            float2 E = cadd(S1, S2), Od = csub(S1, S2);
            int jm = PD(m);
            float2 ph = make_float2(twr[jm], -twi[jm]);
            float2 T = cmul(ph, Od);
            W[u] = make_float2(E.x - T.y, E.y + T.x);
        }
        int j = PD(2 * tid);
        float2 w = make_float2(twr[j], -twi[j]);
        float2 w2 = make_float2(w.x * w.x - w.y * w.y, 2.f * w.x * w.y);
        float2 S0 = cadd(W[0], W[2]);
        float2 D0 = cmul(csub(W[0], W[2]), w);
        float2 S1q = cadd(W[1], W[3]);
        float2 ff = cmul(csub(W[1], W[3]), w);
        float2 D1 = make_float2(-ff.y, ff.x);
        float2 o0 = cadd(S0, S1q);
        float2 o1 = cmul(csub(S0, S1q), w2);
        float2 o2 = cadd(D0, D1);
        float2 o3 = cmul(csub(D0, D1), w2);
        __syncthreads();
        ST2(PD(tid), o0);
        ST2(PD(tid + 256), o1);
        ST2(PD(tid + 512), o2);
        ST2(PD(tid + 768), o3);
    }
    __syncthreads();

    // ---- inverse DIF quads hh=64,16,4 ----
#pragma unroll
    for (int hh = 64; hh >= 4; hh >>= 2) {
        const int step = 512 / hh;
        int p = tid & (hh - 1);
        int i0 = ((tid ^ p) << 2) | p;
        int e0 = PD(i0), e1 = PD(i0 + hh), e2 = PD(i0 + 2 * hh), e3 = PD(i0 + 3 * hh);
        float2 a = LD2(e0), b = LD2(e1), c = LD2(e2), d = LD2(e3);
        int jt = PD(p * step);
        float2 w = make_float2(twr[jt], -twi[jt]);
        float2 w2 = make_float2(w.x * w.x - w.y * w.y, 2.f * w.x * w.y);
        float2 S0 = cadd(a, c);
        float2 D0 = cmul(csub(a, c), w);
        float2 S1 = cadd(b, d);
        float2 ff = cmul(csub(b, d), w);
        float2 D1 = make_float2(-ff.y, ff.x);
        ST2(e0, cadd(S0, S1));
        ST2(e1, cmul(csub(S0, S1), w2));
        ST2(e2, cadd(D0, D1));
        ST2(e3, cmul(csub(D0, D1), w2));
        __syncthreads();
    }
    float r[8];
    int tau[8];
    {
        float2 a = LD2(PD(4 * tid)), b = LD2(PD(4 * tid + 1));
        float2 c = LD2(PD(4 * tid + 2)), d = LD2(PD(4 * tid + 3));
        float2 S0 = cadd(a, c), D0 = csub(a, c);
        float2 S1 = cadd(b, d);
        float2 bd = csub(b, d);
        float2 D1 = make_float2(-bd.y, bd.x);
        float2 z0 = cadd(S0, S1);
        float2 z1 = csub(S0, S1);
        float2 z2 = cadd(D0, D1);
        float2 z3 = csub(D0, D1);
        const int pb = (int)(__brev((unsigned)tid) >> 24);
        const float sc = 1.0f / (float)NN;
        int m0 = pb, m1 = 512 + pb, m2 = 256 + pb, m3 = 768 + pb;
        r[0] = z0.x * sc; tau[0] = 2 * m0;
        r[1] = z0.y * sc; tau[1] = 2 * m0 + 1;
        r[2] = z1.x * sc; tau[2] = 2 * m1;
        r[3] = z1.y * sc; tau[3] = 2 * m1 + 1;
        r[4] = z2.x * sc; tau[4] = 2 * m2;
        r[5] = z2.y * sc; tau[5] = 2 * m2 + 1;
        r[6] = z3.x * sc; tau[6] = 2 * m3;
        r[7] = z3.y * sc; tau[7] = 2 * m3 + 1;
    }

    // ---- top-15: LB prune + gather + bitonic ----
    {
        float lmax = r[0];
#pragma unroll
        for (int u = 1; u < 8; ++u) lmax = fmaxf(lmax, r[u]);
        float sv = lmax;
#pragma unroll
        for (int k = 2; k <= 64; k <<= 1) {
#pragma unroll
            for (int j = k >> 1; j > 0; j >>= 1) {
                float ov = __shfl_xor(sv, j);
                bool lower = (lane & j) == 0;
                bool dirAsc = (lane & k) == 0;
                bool myMinKey = sv > ov;
                bool keepMine = (dirAsc == lower) ? myMinKey : !myMinKey;
                sv = keepMine ? sv : ov;
            }
        }
        float LBw = __shfl(sv, 14);
        if (lane == 0) sLB[wid] = LBw;
        if (tid == 0) cnt = 0;
    }
    __syncthreads();
    {
        float LB = fmaxf(fmaxf(sLB[0], sLB[1]), fmaxf(sLB[2], sLB[3]));
#pragma unroll
        for (int u = 0; u < 8; ++u) {
            if (r[u] >= LB) {
                int slot = atomicAdd(&cnt, 1);
                zr[slot] = r[u];
                zi[slot] = __int_as_float(tau[u]);
            }
        }
    }
    __syncthreads();
    const int ncand = cnt;
    if (tid < 64) {
        float cv;
        int ci;
        if (ncand <= 64) {
            cv = (lane < ncand) ? zr[lane] : -FLT_MAX;
            ci = (lane < ncand) ? __float_as_int(zi[lane]) : 0x7fffffff;
#pragma unroll
            for (int k = 2; k <= 64; k <<= 1) {
#pragma unroll
                for (int j = k >> 1; j > 0; j >>= 1) {
                    float ov = __shfl_xor(cv, j);
                    int oi = __shfl_xor(ci, j);
                    bool lower = (lane & j) == 0;
                    bool dirAsc = (lane & k) == 0;
                    bool myMinKey = (cv > ov) || (cv == ov && ci < oi);
                    bool keepMine = (dirAsc == lower) ? myMinKey : !myMinKey;
                    cv = keepMine ? cv : ov;
                    ci = keepMine ? ci : oi;
                }
            }
        } else {
            float keep_v = -FLT_MAX;
            int keep_i = 0x7fffffff;
            for (int it = 0; it < TOPK; ++it) {
                float bv = -FLT_MAX;
                int bi = 0x7fffffff, bs = 0;
                for (int s = lane; s < ncand; s += 64) {
                    float v = zr[s];
                    int ii = __float_as_int(zi[s]);
                    if (v > bv || (v == bv && ii < bi)) { bv = v; bi = ii; bs = s; }
                }
#pragma unroll
                for (int off = 32; off >= 1; off >>= 1) {
                    float ov = __shfl_xor(bv, off);
                    int oi = __shfl_xor(bi, off);
                    int os = __shfl_xor(bs, off);
                    if (ov > bv || (ov == bv && oi < bi)) { bv = ov; bi = oi; bs = os; }
                }
                if ((bs & 63) == lane) zr[bs] = -FLT_MAX;
                if (lane == it) { keep_v = bv; keep_i = bi; }
            }
            cv = keep_v;
            ci = keep_i;
        }
        float m0 = __shfl(cv, 0);
        float e = (lane < TOPK) ? expf(cv - m0) : 0.f;
        float ssum = e;
#pragma unroll
        for (int off = 32; off >= 1; off >>= 1) ssum += __shfl_xor(ssum, off);
        if (lane < TOPK) {
            corr_s[lane] = e / ssum;
            topi_s[lane] = ci;
        }
    }
    __syncthreads();

    // ---- aggregation: 8 consecutive t per thread; 2 aligned us8 loads + uniform select ----
    {
        const unsigned short* qrow = qt + base;
        const int t0 = tid << 3;
        float acc8[8] = {0.f, 0.f, 0.f, 0.f, 0.f, 0.f, 0.f, 0.f};
        for (int i = 0; i < TOPK; ++i) {
            const float w = corr_s[i];
            const int d = topi_s[i];
            const int s = (t0 + d) & (NN - 1);
            const int a0 = s & ~7;
            const int o = s & 7;  // wave-uniform
            us8 A = *reinterpret_cast<const us8*>(qrow + a0);
            us8 Bv = *reinterpret_cast<const us8*>(qrow + ((a0 + 8) & (NN - 1)));
            switch (o) {
#define AGG_CASE(O)                                                              \
    case O: {                                                                    \
        _Pragma("unroll") for (int j = 0; j < 8; ++j) {                          \
            unsigned short e = ((O) + j < 8) ? A[(O) + j] : Bv[(O) + j - 8];     \
            acc8[j] += w * h2f(e);                                               \
        }                                                                        \
    } break;
                AGG_CASE(0) AGG_CASE(1) AGG_CASE(2) AGG_CASE(3)
                AGG_CASE(4) AGG_CASE(5) AGG_CASE(6) AGG_CASE(7)
#undef AGG_CASE
            }
        }
        us8 o8;
#pragma unroll
        for (int j = 0; j < 8; ++j) o8[j] = f2h(acc8[j]);
        *reinterpret_cast<us8*>(kt + base + t0) = o8;
    }
#undef LD2
#undef ST2
}

// ---------------- output GEMM, fp16 MFMA, prefetched k-loop ----------------
__global__ __launch_bounds__(256) void out_gemm_mfma(const unsigned short* __restrict__ db,
                                                     const unsigned short* __restrict__ WtO,
                                                     const float* __restrict__ bias,
                                                     float* __restrict__ out) {
    __shared__ unsigned short Asm[32][134];  // stride 67 dwords: extract banks all-distinct
    __shared__ unsigned short Bsm[128][40];
    const int tid = threadIdx.x;
    const int lane = tid & 63, wid = tid >> 6;
    const int wr = wid >> 1, wc = wid & 1;
    const int g = lane >> 4, rl = lane & 15;
    int sbx, sby;
    xcd_swizzle_512(blockIdx.x, blockIdx.y, sbx, sby);
    const int r0 = sby * 128, c0 = sbx * 128;
    const int b = r0 >> 11, l0 = r0 & (LL - 1);
    f32x4 acc[4][4];
#pragma unroll
    for (int m = 0; m < 4; ++m)
#pragma unroll
        for (int n = 0; n < 4; ++n) acc[m][n] = (f32x4){0.f, 0.f, 0.f, 0.f};

    // prologue: load tile k0=0
    us8 avv[2], bvv[2];
#pragma unroll
    for (int p = 0; p < 2; ++p) {
        int idx = tid + 256 * p;
        int kr = idx >> 4, dc = idx & 15;
        avv[p] = *reinterpret_cast<const us8*>(&db[(size_t)(b * DD + kr) * 2048 + l0 + dc * 8]);
    }
#pragma unroll
    for (int p = 0; p < 2; ++p) {
        int idx = tid + 256 * p;
        int row = idx >> 2, kq = idx & 3;
        bvv[p] = *reinterpret_cast<const us8*>(&WtO[(size_t)(c0 + row) * DD + kq * 8]);
    }

#pragma unroll
    for (int k0 = 0; k0 < DD; k0 += 32) {
        __syncthreads();
#pragma unroll
        for (int p = 0; p < 2; ++p) {
            int idx = tid + 256 * p;
            int kr = idx >> 4, dc = idx & 15;
            us4 lo, hi;
#pragma unroll
            for (int j = 0; j < 4; ++j) { lo[j] = avv[p][j]; hi[j] = avv[p][j + 4]; }
            *reinterpret_cast<us4*>(&Asm[kr][dc * 8]) = lo;
            *reinterpret_cast<us4*>(&Asm[kr][dc * 8 + 4]) = hi;
        }
#pragma unroll
        for (int p = 0; p < 2; ++p) {
            int idx = tid + 256 * p;
            int row = idx >> 2, kq = idx & 3;
            *reinterpret_cast<us8*>(&Bsm[row][kq * 8]) = bvv[p];
        }
        // prefetch next k-tile before barrier/MFMA
        if (k0 + 32 < DD) {
#pragma unroll
            for (int p = 0; p < 2; ++p) {
                int idx = tid + 256 * p;
                int kr = idx >> 4, dc = idx & 15;
                avv[p] = *reinterpret_cast<const us8*>(
                    &db[(size_t)(b * DD + (k0 + 32) + kr) * 2048 + l0 + dc * 8]);
            }
#pragma unroll
            for (int p = 0; p < 2; ++p) {
                int idx = tid + 256 * p;
                int row = idx >> 2, kq = idx & 3;
                bvv[p] = *reinterpret_cast<const us8*>(
                    &WtO[(size_t)(c0 + row) * DD + (k0 + 32) + kq * 8]);
            }
        }
        __syncthreads();
        f16x8 af[4], bfr[4];
#pragma unroll
        for (int m = 0; m < 4; ++m) {
            int l = wr * 64 + m * 16 + rl;
            us8 t;
#pragma unroll
            for (int j = 0; j < 8; ++j) t[j] = Asm[g * 8 + j][l];
            af[m] = __builtin_bit_cast(f16x8, t);
        }
#pragma unroll
        for (int n = 0; n < 4; ++n)
            bfr[n] = *reinterpret_cast<const f16x8*>(&Bsm[wc * 64 + n * 16 + rl][g * 8]);
#pragma unroll
        for (int m = 0; m < 4; ++m)
#pragma unroll
            for (int n = 0; n < 4; ++n)
                acc[m][n] = __builtin_amdgcn_mfma_f32_16x16x32_f16(af[m], bfr[n], acc[m][n], 0, 0, 0);
    }

#pragma unroll
    for (int m = 0; m < 4; ++m) {
#pragma unroll
        for (int n = 0; n < 4; ++n) {
            int c = c0 + wc * 64 + n * 16 + rl;
            float bvv2 = bias[c];
            int rbase = r0 + wr * 64 + m * 16 + g * 4;
#pragma unroll
            for (int j = 0; j < 4; ++j)
                out[(size_t)(rbase + j) * DD + c] = acc[m][n][j] + bvv2;
        }
    }
}

extern "C" void kernel_launch(void* const* d_in, const int* in_sizes, int n_in,
                              void* d_out, int out_size, void* d_ws, size_t ws_size,
                              hipStream_t stream) {
    const float* q = (const float*)d_in[0];
    const float* k = (const float*)d_in[1];
    const float* Wq = (const float*)d_in[3];
    const float* bq = (const float*)d_in[4];
    const float* Wk = (const float*)d_in[5];
    const float* bk = (const float*)d_in[6];
    const float* Wo = (const float*)d_in[9];
    const float* bo = (const float*)d_in[10];
    float* out = (float*)d_out;

    unsigned short* qt = (unsigned short*)d_ws;
    unsigned short* kt = qt + (size_t)BB * HH * DEPTH * LL;
    unsigned short* Tq = kt + (size_t)BB * HH * DEPTH * LL;
    unsigned short* Tk = Tq + (size_t)DD * DD;
    unsigned short* To = Tk + (size_t)DD * DD;

    dim3 blk(256);
    wt_convert<<<dim3(8, 8, 3), blk, 0, stream>>>(Wq, Wk, Wo, Tq, Tk, To);
    proj_gemm2<<<dim3(4, 128, 2), blk, 0, stream>>>(q, k, Tq, Tk, bq, bk, qt, kt);
    corr_fft_v8<<<dim3(BB * HH * DEPTH), blk, 0, stream>>>(qt, kt);
    out_gemm_mfma<<<dim3(4, 128), blk, 0, stream>>>(kt, To, bo, out);
}

// Round 13
// 115.618 us; speedup vs baseline: 3.0157x; 1.0128x over previous
//
#include <hip/hip_runtime.h>
#include <hip/hip_fp16.h>
#include <float.h>
#include <math.h>

#define BB 8
#define LL 2048
#define NN 2048
#define MM 1024
#define DD 512
#define HH 8
#define DEPTH 64
#define TOPK 15
#define PIF 3.14159265358979323846f

// AoS float2 pad: +1 element per 16 -> strides 1/8 conflict-free, others 2-way (b64)
#define PD2(i) ((i) + ((i) >> 4))

using f16x8 = __attribute__((ext_vector_type(8))) _Float16;
typedef __attribute__((ext_vector_type(4))) float f32x4;
typedef __attribute__((ext_vector_type(8))) unsigned short us8;
typedef __attribute__((ext_vector_type(4))) unsigned short us4;

__device__ __forceinline__ unsigned short f2h(float f) {
    return __half_as_ushort(__float2half(f));
}
__device__ __forceinline__ float h2f(unsigned short u) {
    return (float)__builtin_bit_cast(_Float16, u);
}
__device__ __forceinline__ float2 cmul(float2 a, float2 b) {
    return make_float2(a.x * b.x - a.y * b.y, a.x * b.y + a.y * b.x);
}
__device__ __forceinline__ float2 cmulc(float2 a, float2 b) {
    return make_float2(a.x * b.x + a.y * b.y, a.y * b.x - a.x * b.y);
}
__device__ __forceinline__ float2 cadd(float2 a, float2 b) { return make_float2(a.x + b.x, a.y + b.y); }
__device__ __forceinline__ float2 csub(float2 a, float2 b) { return make_float2(a.x - b.x, a.y - b.y); }

__device__ __forceinline__ void xcd_swizzle_512(int bx, int by, int& obx, int& oby) {
    int flat = by * 4 + bx;
    int xcd = flat & 7;
    int pos = flat >> 3;
    int nid = xcd * 64 + pos;  // bijective: 512 = 8 * 64
    obx = nid & 3;
    oby = nid >> 2;
}

// ---------------- W transpose + fp32->fp16 convert ----------------
__global__ __launch_bounds__(256) void wt_convert(const float* __restrict__ Wq,
                                                  const float* __restrict__ Wk,
                                                  const float* __restrict__ Wo,
                                                  unsigned short* __restrict__ Tq,
                                                  unsigned short* __restrict__ Tk,
                                                  unsigned short* __restrict__ To) {
    __shared__ float T[64][65];
    const float* src = blockIdx.z == 0 ? Wq : (blockIdx.z == 1 ? Wk : Wo);
    unsigned short* dst = blockIdx.z == 0 ? Tq : (blockIdx.z == 1 ? Tk : To);
    const int tid = threadIdx.x;
    const int r0 = blockIdx.y * 64, c0 = blockIdx.x * 64;
#pragma unroll
    for (int p = 0; p < 4; ++p) {
        int idx = tid + 256 * p;
        int row = idx >> 4, c4 = idx & 15;
        float4 v = *reinterpret_cast<const float4*>(&src[(size_t)(r0 + row) * DD + c0 + c4 * 4]);
        T[row][c4 * 4 + 0] = v.x;
        T[row][c4 * 4 + 1] = v.y;
        T[row][c4 * 4 + 2] = v.z;
        T[row][c4 * 4 + 3] = v.w;
    }
    __syncthreads();
#pragma unroll
    for (int p = 0; p < 4; ++p) {
        int idx = tid + 256 * p;
        int orow = idx >> 4, oc4 = idx & 15;
        us4 o;
#pragma unroll
        for (int j = 0; j < 4; ++j) o[j] = f2h(T[oc4 * 4 + j][orow]);
        *reinterpret_cast<us4*>(&dst[(size_t)(c0 + orow) * DD + r0 + oc4 * 4]) = o;
    }
}

// ---------------- MERGED projection GEMMs (z=0: q, z=1: k), prefetched k-loop ----------------
__global__ __launch_bounds__(256) void proj_gemm2(const float* __restrict__ Xq,
                                                  const float* __restrict__ Xk,
                                                  const unsigned short* __restrict__ Tq,
                                                  const unsigned short* __restrict__ Tk,
                                                  const float* __restrict__ bq,
                                                  const float* __restrict__ bk,
                                                  unsigned short* __restrict__ qt,
                                                  unsigned short* __restrict__ kt) {
    const float* X = blockIdx.z == 0 ? Xq : Xk;
    const unsigned short* Wt = blockIdx.z == 0 ? Tq : Tk;
    const float* bias = blockIdx.z == 0 ? bq : bk;
    unsigned short* outT = blockIdx.z == 0 ? qt : kt;

    __shared__ unsigned short Asm[128][40];  // X tile: [l][k]
    __shared__ unsigned short Bsm[128][40];  // Wt tile: [c][k]
    const int tid = threadIdx.x;
    const int lane = tid & 63, wid = tid >> 6;
    const int wM = wid & 1, wN = wid >> 1;
    const int g = lane >> 4, rl = lane & 15;
    int sbx, sby;
    xcd_swizzle_512(blockIdx.x, blockIdx.y, sbx, sby);
    const int r0 = sby * 128, c0 = sbx * 128;
    f32x4 acc[4][4];
#pragma unroll
    for (int m = 0; m < 4; ++m)
#pragma unroll
        for (int n = 0; n < 4; ++n) acc[m][n] = (f32x4){0.f, 0.f, 0.f, 0.f};

    float4 av[4];
    us8 bv[2];
#pragma unroll
    for (int p = 0; p < 4; ++p) {
        int idx = tid + 256 * p;
        int row = idx >> 3, kq = idx & 7;
        av[p] = *reinterpret_cast<const float4*>(&X[(size_t)(r0 + row) * DD + kq * 4]);
    }
#pragma unroll
    for (int p = 0; p < 2; ++p) {
        int idx = tid + 256 * p;
        int row = idx >> 2, kq = idx & 3;
        bv[p] = *reinterpret_cast<const us8*>(&Wt[(size_t)(c0 + row) * DD + kq * 8]);
    }

#pragma unroll
    for (int k0 = 0; k0 < DD; k0 += 32) {
        __syncthreads();
#pragma unroll
        for (int p = 0; p < 4; ++p) {
            int idx = tid + 256 * p;
            int row = idx >> 3, kq = idx & 7;
            us4 w;
            w[0] = f2h(av[p].x); w[1] = f2h(av[p].y); w[2] = f2h(av[p].z); w[3] = f2h(av[p].w);
            *reinterpret_cast<us4*>(&Asm[row][kq * 4]) = w;
        }
#pragma unroll
        for (int p = 0; p < 2; ++p) {
            int idx = tid + 256 * p;
            int row = idx >> 2, kq = idx & 3;
            *reinterpret_cast<us8*>(&Bsm[row][kq * 8]) = bv[p];
        }
        if (k0 + 32 < DD) {
#pragma unroll
            for (int p = 0; p < 4; ++p) {
                int idx = tid + 256 * p;
                int row = idx >> 3, kq = idx & 7;
                av[p] = *reinterpret_cast<const float4*>(
                    &X[(size_t)(r0 + row) * DD + (k0 + 32) + kq * 4]);
            }
#pragma unroll
            for (int p = 0; p < 2; ++p) {
                int idx = tid + 256 * p;
                int row = idx >> 2, kq = idx & 3;
                bv[p] = *reinterpret_cast<const us8*>(
                    &Wt[(size_t)(c0 + row) * DD + (k0 + 32) + kq * 8]);
            }
        }
        __syncthreads();
        f16x8 af[4], bfr[4];
#pragma unroll
        for (int m = 0; m < 4; ++m)
            af[m] = *reinterpret_cast<const f16x8*>(&Bsm[wM * 64 + m * 16 + rl][g * 8]);
#pragma unroll
        for (int n = 0; n < 4; ++n)
            bfr[n] = *reinterpret_cast<const f16x8*>(&Asm[wN * 64 + n * 16 + rl][g * 8]);
#pragma unroll
        for (int m = 0; m < 4; ++m)
#pragma unroll
            for (int n = 0; n < 4; ++n)
                acc[m][n] = __builtin_amdgcn_mfma_f32_16x16x32_f16(af[m], bfr[n], acc[m][n], 0, 0, 0);
    }

    const int b = r0 >> 11, l0 = r0 & (LL - 1);
#pragma unroll
    for (int m = 0; m < 4; ++m) {
        int cb = c0 + wM * 64 + m * 16 + g * 4;
        float4 bv4 = *reinterpret_cast<const float4*>(&bias[cb]);
        const float bja[4] = {bv4.x, bv4.y, bv4.z, bv4.w};
#pragma unroll
        for (int j = 0; j < 4; ++j) {
            int c = cb + j;
            int h = c >> 6, dd = c & 63;
            unsigned short* orow = &outT[((size_t)(b * HH + h) * DEPTH + dd) * LL];
#pragma unroll
            for (int n = 0; n < 4; ++n) {
                int l = l0 + wN * 64 + n * 16 + rl;
                orow[l] = f2h(acc[m][n][j] + bja[j]);
            }
        }
    }
}

// ---------------- correlation v9: float2 AoS LDS (b64 ops), radix-8 fwd, half-size inverse ----------------
__global__ __launch_bounds__(256) void corr_fft_v9(const unsigned short* __restrict__ qt,
                                                   unsigned short* __restrict__ kt) {
    __shared__ float2 zz[2176];   // 2048 + PD2 pad, 17.4 KB; reused as candidate list
    __shared__ float2 tw2[1088];  // tw[j] = exp(-i*pi*j/1024), PD2-padded, 8.7 KB
    __shared__ float sLB[4];
    __shared__ int cnt;
    __shared__ float corr_s[TOPK];
    __shared__ int topi_s[TOPK];
    const int tid = threadIdx.x;
    const int lane = tid & 63, wid = tid >> 6;
    const size_t base = (size_t)blockIdx.x * NN;
    const float R2 = 0.70710678118654752f;

#define ZL(i) (zz[PD2(i)])
#define ZS(i, v) do { zz[PD2(i)] = (v); } while (0)
#define TW(j) (tw2[PD2(j)])

    // ---- load; bit-reversed scatter; twiddle init ----
    {
        us8 qa = *reinterpret_cast<const us8*>(qt + base + 8 * tid);
        us8 ka = *reinterpret_cast<const us8*>(kt + base + 8 * tid);
        f16x8 qh = __builtin_bit_cast(f16x8, qa);
        f16x8 kh = __builtin_bit_cast(f16x8, ka);
        int pb = (int)(__brev((unsigned)tid) >> 24);
        const int b3[8] = {0, 4, 2, 6, 1, 5, 3, 7};
#pragma unroll
        for (int u = 0; u < 8; ++u) {
            int pf = b3[u] * 256 + pb;
            ZS(pf, make_float2((float)qh[u], (float)kh[u]));
        }
#pragma unroll
        for (int v = 0; v < 4; ++v) {
            int j = tid + 256 * v;
            float sn, cs;
            __sincosf(-PIF * (float)j * (1.f / 1024.f), &sn, &cs);
            TW(j) = make_float2(cs, sn);
        }
    }
    __syncthreads();

    // ---- forward DIT: radix-8 pass hh=1 (trivial twiddles) ----
    {
        int i0 = tid << 3;
        float2 z[8];
#pragma unroll
        for (int u = 0; u < 8; ++u) z[u] = ZL(i0 + u);
#pragma unroll
        for (int a = 0; a < 4; ++a) {
            float2 tv = z[2 * a + 1];
            z[2 * a + 1] = csub(z[2 * a], tv);
            z[2 * a] = cadd(z[2 * a], tv);
        }
        {
            const int u0a[4] = {0, 1, 4, 5};
#pragma unroll
            for (int kk = 0; kk < 4; ++kk) {
                int u0 = u0a[kk];
                float2 s = z[u0 + 2];
                float2 tv = (kk & 1) ? make_float2(s.y, -s.x) : s;
                z[u0 + 2] = csub(z[u0], tv);
                z[u0] = cadd(z[u0], tv);
            }
        }
        {
            float2 tv;
            tv = z[4];                                        z[4] = csub(z[0], tv); z[0] = cadd(z[0], tv);
            tv = cmul(z[5], make_float2(R2, -R2));            z[5] = csub(z[1], tv); z[1] = cadd(z[1], tv);
            { float2 s = z[6]; tv = make_float2(s.y, -s.x); } z[6] = csub(z[2], tv); z[2] = cadd(z[2], tv);
            tv = cmul(z[7], make_float2(-R2, -R2));           z[7] = csub(z[3], tv); z[3] = cadd(z[3], tv);
        }
#pragma unroll
        for (int u = 0; u < 8; ++u) ZS(i0 + u, z[u]);
    }
    __syncthreads();

    // ---- radix-8 passes hh=8, 64 ----
#pragma unroll
    for (int hh = 8; hh <= 64; hh <<= 3) {
        int p = tid & (hh - 1);
        int i0 = ((tid ^ p) << 3) | p;
        float2 z[8];
#pragma unroll
        for (int u = 0; u < 8; ++u) z[u] = ZL(i0 + hh * u);
        float2 wa = TW(p * (1024 / hh));
        float2 wb = TW(p * (512 / hh));
        float2 wc = TW(p * (256 / hh));
#pragma unroll
        for (int a = 0; a < 4; ++a) {
            float2 tv = cmul(z[2 * a + 1], wa);
            z[2 * a + 1] = csub(z[2 * a], tv);
            z[2 * a] = cadd(z[2 * a], tv);
        }
        {
            float2 wbn = make_float2(wb.y, -wb.x);
            const int u0a[4] = {0, 1, 4, 5};
#pragma unroll
            for (int kk = 0; kk < 4; ++kk) {
                int u0 = u0a[kk];
                float2 w = (kk & 1) ? wbn : wb;
                float2 tv = cmul(z[u0 + 2], w);
                z[u0 + 2] = csub(z[u0], tv);
                z[u0] = cadd(z[u0], tv);
            }
        }
        {
            float2 wt0 = wc;
            float2 wt1 = cmul(wc, make_float2(R2, -R2));
            float2 wt2 = make_float2(wc.y, -wc.x);
            float2 wt3 = cmul(wc, make_float2(-R2, -R2));
            float2 tv;
            tv = cmul(z[4], wt0); z[4] = csub(z[0], tv); z[0] = cadd(z[0], tv);
            tv = cmul(z[5], wt1); z[5] = csub(z[1], tv); z[1] = cadd(z[1], tv);
            tv = cmul(z[6], wt2); z[6] = csub(z[2], tv); z[2] = cadd(z[2], tv);
            tv = cmul(z[7], wt3); z[7] = csub(z[3], tv); z[3] = cadd(z[3], tv);
        }
#pragma unroll
        for (int u = 0; u < 8; ++u) ZS(i0 + hh * u, z[u]);
        __syncthreads();
    }

    // ---- register radix-4 tail: stages 512, 1024 on {tid+256u} ----
    {
        float2 z[8];
#pragma unroll
        for (int u = 0; u < 8; ++u) z[u] = ZL(tid + 256 * u);
        {
            float2 wb = TW(2 * tid);
            float2 wbn = make_float2(wb.y, -wb.x);
            const int u0a[4] = {0, 1, 4, 5};
#pragma unroll
            for (int kk = 0; kk < 4; ++kk) {
                int u0 = u0a[kk];
                float2 w = (kk & 1) ? wbn : wb;
                float2 tv = cmul(z[u0 + 2], w);
                z[u0 + 2] = csub(z[u0], tv);
                z[u0] = cadd(z[u0], tv);
            }
        }
        {
            float2 wc = TW(tid);
            float2 wt0 = wc;
            float2 wt1 = cmul(wc, make_float2(R2, -R2));
            float2 wt2 = make_float2(wc.y, -wc.x);
            float2 wt3 = cmul(wc, make_float2(-R2, -R2));
            float2 tv;
            tv = cmul(z[4], wt0); z[4] = csub(z[0], tv); z[0] = cadd(z[0], tv);
            tv = cmul(z[5], wt1); z[5] = csub(z[1], tv); z[1] = cadd(z[1], tv);
            tv = cmul(z[6], wt2); z[6] = csub(z[2], tv); z[2] = cadd(z[2], tv);
            tv = cmul(z[7], wt3); z[7] = csub(z[3], tv); z[3] = cadd(z[3], tv);
        }
#pragma unroll
        for (int u = 0; u < 8; ++u) ZS(tid + 256 * u, z[u]);
    }
    __syncthreads();

    // ---- FUSED: Hermitian unpack + S=Q*conj(K) + irfft combine + inverse quad hh=256 ----
    {
        float2 W[4];
#pragma unroll
        for (int u = 0; u < 4; ++u) {
            int m = tid + 256 * u;
            int mf1 = (NN - m) & (NN - 1);
            float2 Zf = ZL(m), Zm = ZL(mf1);
            float2 Qf = make_float2(0.5f * (Zf.x + Zm.x), 0.5f * (Zf.y - Zm.y));
            float2 Dm = make_float2(Zf.x - Zm.x, Zf.y + Zm.y);
            float2 Kf = make_float2(0.5f * Dm.y, -0.5f * Dm.x);
            float2 S1 = cmulc(Qf, Kf);
            float2 Zf2 = ZL(m + MM), Zm2 = ZL(MM - m);
            float2 Qf2 = make_float2(0.5f * (Zf2.x + Zm2.x), 0.5f * (Zf2.y - Zm2.y));
            float2 Dm2 = make_float2(Zf2.x - Zm2.x, Zf2.y + Zm2.y);
            float2 Kf2 = make_float2(0.5f * Dm2.y, -0.5f * Dm2.x);
            float2 S2 = cmulc(Qf2, Kf2);
            float2 E = cadd(S1, S2), Od = csub(S1, S2);
            float2 twm = TW(m);
            float2 ph = make_float2(twm.x, -twm.y);  // e^{+i*pi*m/1024}
            float2 T = cmul(ph, Od);
            W[u] = make_float2(E.x - T.y, E.y + T.x);
        }
        float2 twj = TW(2 * tid);
        float2 w = make_float2(twj.x, -twj.y);
        float2 w2 = make_float2(w.x * w.x - w.y * w.y, 2.f * w.x * w.y);
        float2 S0 = cadd(W[0], W[2]);
        float2 D0 = cmul(csub(W[0], W[2]), w);
        float2 S1q = cadd(W[1], W[3]);
        float2 ff = cmul(csub(W[1], W[3]), w);
        float2 D1 = make_float2(-ff.y, ff.x);
        float2 o0 = cadd(S0, S1q);
        float2 o1 = cmul(csub(S0, S1q), w2);
        float2 o2 = cadd(D0, D1);
        float2 o3 = cmul(csub(D0, D1), w2);
        __syncthreads();  // all Z reads done before overwriting
        ZS(tid, o0);
        ZS(tid + 256, o1);
        ZS(tid + 512, o2);
        ZS(tid + 768, o3);
    }
    __syncthreads();

    // ---- inverse DIF quads hh=64,16,4 ----
#pragma unroll
    for (int hh = 64; hh >= 4; hh >>= 2) {
        const int step = 512 / hh;
        int p = tid & (hh - 1);
        int i0 = ((tid ^ p) << 2) | p;
        float2 a = ZL(i0), b = ZL(i0 + hh), c = ZL(i0 + 2 * hh), d = ZL(i0 + 3 * hh);
        float2 twj = TW(p * step);
        float2 w = make_float2(twj.x, -twj.y);
        float2 w2 = make_float2(w.x * w.x - w.y * w.y, 2.f * w.x * w.y);
        float2 S0 = cadd(a, c);
        float2 D0 = cmul(csub(a, c), w);
        float2 S1 = cadd(b, d);
        float2 ff = cmul(csub(b, d), w);
        float2 D1 = make_float2(-ff.y, ff.x);
        ZS(i0, cadd(S0, S1));
        ZS(i0 + hh, cmul(csub(S0, S1), w2));
        ZS(i0 + 2 * hh, cadd(D0, D1));
        ZS(i0 + 3 * hh, cmul(csub(D0, D1), w2));
        __syncthreads();
    }
    float r[8];
    int tau[8];
    {
        float2 a = ZL(4 * tid), b = ZL(4 * tid + 1);
        float2 c = ZL(4 * tid + 2), d = ZL(4 * tid + 3);
        float2 S0 = cadd(a, c), D0 = csub(a, c);
        float2 S1 = cadd(b, d);
        float2 bd = csub(b, d);
        float2 D1 = make_float2(-bd.y, bd.x);
        float2 z0 = cadd(S0, S1);
        float2 z1 = csub(S0, S1);
        float2 z2 = cadd(D0, D1);
        float2 z3 = csub(D0, D1);
        const int pb = (int)(__brev((unsigned)tid) >> 24);
        const float sc = 1.0f / (float)NN;
        int m0 = pb, m1 = 512 + pb, m2 = 256 + pb, m3 = 768 + pb;
        r[0] = z0.x * sc; tau[0] = 2 * m0;
        r[1] = z0.y * sc; tau[1] = 2 * m0 + 1;
        r[2] = z1.x * sc; tau[2] = 2 * m1;
        r[3] = z1.y * sc; tau[3] = 2 * m1 + 1;
        r[4] = z2.x * sc; tau[4] = 2 * m2;
        r[5] = z2.y * sc; tau[5] = 2 * m2 + 1;
        r[6] = z3.x * sc; tau[6] = 2 * m3;
        r[7] = z3.y * sc; tau[7] = 2 * m3 + 1;
    }

    // ---- top-15: LB prune + gather (candidate list overlays zz, raw indices) + bitonic ----
    {
        float lmax = r[0];
#pragma unroll
        for (int u = 1; u < 8; ++u) lmax = fmaxf(lmax, r[u]);
        float sv = lmax;
#pragma unroll
        for (int k = 2; k <= 64; k <<= 1) {
#pragma unroll
            for (int j = k >> 1; j > 0; j >>= 1) {
                float ov = __shfl_xor(sv, j);
                bool lower = (lane & j) == 0;
                bool dirAsc = (lane & k) == 0;
                bool myMinKey = sv > ov;
                bool keepMine = (dirAsc == lower) ? myMinKey : !myMinKey;
                sv = keepMine ? sv : ov;
            }
        }
        float LBw = __shfl(sv, 14);
        if (lane == 0) sLB[wid] = LBw;
        if (tid == 0) cnt = 0;
    }
    __syncthreads();
    {
        float LB = fmaxf(fmaxf(sLB[0], sLB[1]), fmaxf(sLB[2], sLB[3]));
#pragma unroll
        for (int u = 0; u < 8; ++u) {
            if (r[u] >= LB) {
                int slot = atomicAdd(&cnt, 1);
                zz[slot] = make_float2(r[u], __int_as_float(tau[u]));
            }
        }
    }
    __syncthreads();
    const int ncand = cnt;
    if (tid < 64) {
        float cv;
        int ci;
        if (ncand <= 64) {
            float2 cd = (lane < ncand) ? zz[lane] : make_float2(-FLT_MAX, __int_as_float(0x7fffffff));
            cv = cd.x;
            ci = __float_as_int(cd.y);
#pragma unroll
            for (int k = 2; k <= 64; k <<= 1) {
#pragma unroll
                for (int j = k >> 1; j > 0; j >>= 1) {
                    float ov = __shfl_xor(cv, j);
                    int oi = __shfl_xor(ci, j);
                    bool lower = (lane & j) == 0;
                    bool dirAsc = (lane & k) == 0;
                    bool myMinKey = (cv > ov) || (cv == ov && ci < oi);
                    bool keepMine = (dirAsc == lower) ? myMinKey : !myMinKey;
                    cv = keepMine ? cv : ov;
                    ci = keepMine ? ci : oi;
                }
            }
        } else {
            float keep_v = -FLT_MAX;
            int keep_i = 0x7fffffff;
            for (int it = 0; it < TOPK; ++it) {
                float bv = -FLT_MAX;
                int bi = 0x7fffffff, bs = 0;
                for (int s = lane; s < ncand; s += 64) {
                    float2 cd = zz[s];
                    float v = cd.x;
                    int ii = __float_as_int(cd.y);
                    if (v > bv || (v == bv && ii < bi)) { bv = v; bi = ii; bs = s; }
                }
#pragma unroll
                for (int off = 32; off >= 1; off >>= 1) {
                    float ov = __shfl_xor(bv, off);
                    int oi = __shfl_xor(bi, off);
                    int os = __shfl_xor(bs, off);
                    if (ov > bv || (ov == bv && oi < bi)) { bv = ov; bi = oi; bs = os; }
                }
                if ((bs & 63) == lane) zz[bs].x = -FLT_MAX;
                if (lane == it) { keep_v = bv; keep_i = bi; }
            }
            cv = keep_v;
            ci = keep_i;
        }
        float m0 = __shfl(cv, 0);
        float e = (lane < TOPK) ? expf(cv - m0) : 0.f;
        float ssum = e;
#pragma unroll
        for (int off = 32; off >= 1; off >>= 1) ssum += __shfl_xor(ssum, off);
        if (lane < TOPK) {
            corr_s[lane] = e / ssum;
            topi_s[lane] = ci;
        }
    }
    __syncthreads();

    // ---- aggregation: 8 consecutive t per thread; 2 aligned us8 loads + uniform select ----
    {
        const unsigned short* qrow = qt + base;
        const int t0 = tid << 3;
        float acc8[8] = {0.f, 0.f, 0.f, 0.f, 0.f, 0.f, 0.f, 0.f};
        for (int i = 0; i < TOPK; ++i) {
            const float w = corr_s[i];
            const int d = topi_s[i];
            const int s = (t0 + d) & (NN - 1);
            const int a0 = s & ~7;
            const int o = s & 7;  // wave-uniform
            us8 A = *reinterpret_cast<const us8*>(qrow + a0);
            us8 Bv = *reinterpret_cast<const us8*>(qrow + ((a0 + 8) & (NN - 1)));
            switch (o) {
#define AGG_CASE(O)                                                              \
    case O: {                                                                    \
        _Pragma("unroll") for (int j = 0; j < 8; ++j) {                          \
            unsigned short e = ((O) + j < 8) ? A[(O) + j] : Bv[(O) + j - 8];     \
            acc8[j] += w * h2f(e);                                               \
        }                                                                        \
    } break;
                AGG_CASE(0) AGG_CASE(1) AGG_CASE(2) AGG_CASE(3)
                AGG_CASE(4) AGG_CASE(5) AGG_CASE(6) AGG_CASE(7)
#undef AGG_CASE
            }
        }
        us8 o8;
#pragma unroll
        for (int j = 0; j < 8; ++j) o8[j] = f2h(acc8[j]);
        *reinterpret_cast<us8*>(kt + base + t0) = o8;
    }
#undef ZL
#undef ZS
#undef TW
}

// ---------------- output GEMM, fp16 MFMA, prefetched k-loop ----------------
__global__ __launch_bounds__(256) void out_gemm_mfma(const unsigned short* __restrict__ db,
                                                     const unsigned short* __restrict__ WtO,
                                                     const float* __restrict__ bias,
                                                     float* __restrict__ out) {
    __shared__ unsigned short Asm[32][134];
    __shared__ unsigned short Bsm[128][40];
    const int tid = threadIdx.x;
    const int lane = tid & 63, wid = tid >> 6;
    const int wr = wid >> 1, wc = wid & 1;
    const int g = lane >> 4, rl = lane & 15;
    int sbx, sby;
    xcd_swizzle_512(blockIdx.x, blockIdx.y, sbx, sby);
    const int r0 = sby * 128, c0 = sbx * 128;
    const int b = r0 >> 11, l0 = r0 & (LL - 1);
    f32x4 acc[4][4];
#pragma unroll
    for (int m = 0; m < 4; ++m)
#pragma unroll
        for (int n = 0; n < 4; ++n) acc[m][n] = (f32x4){0.f, 0.f, 0.f, 0.f};

    us8 avv[2], bvv[2];
#pragma unroll
    for (int p = 0; p < 2; ++p) {
        int idx = tid + 256 * p;
        int kr = idx >> 4, dc = idx & 15;
        avv[p] = *reinterpret_cast<const us8*>(&db[(size_t)(b * DD + kr) * 2048 + l0 + dc * 8]);
    }
#pragma unroll
    for (int p = 0; p < 2; ++p) {
        int idx = tid + 256 * p;
        int row = idx >> 2, kq = idx & 3;
        bvv[p] = *reinterpret_cast<const us8*>(&WtO[(size_t)(c0 + row) * DD + kq * 8]);
    }

#pragma unroll
    for (int k0 = 0; k0 < DD; k0 += 32) {
        __syncthreads();
#pragma unroll
        for (int p = 0; p < 2; ++p) {
            int idx = tid + 256 * p;
            int kr = idx >> 4, dc = idx & 15;
            us4 lo, hi;
#pragma unroll
            for (int j = 0; j < 4; ++j) { lo[j] = avv[p][j]; hi[j] = avv[p][j + 4]; }
            *reinterpret_cast<us4*>(&Asm[kr][dc * 8]) = lo;
            *reinterpret_cast<us4*>(&Asm[kr][dc * 8 + 4]) = hi;
        }
#pragma unroll
        for (int p = 0; p < 2; ++p) {
            int idx = tid + 256 * p;
            int row = idx >> 2, kq = idx & 3;
            *reinterpret_cast<us8*>(&Bsm[row][kq * 8]) = bvv[p];
        }
        if (k0 + 32 < DD) {
#pragma unroll
            for (int p = 0; p < 2; ++p) {
                int idx = tid + 256 * p;
                int kr = idx >> 4, dc = idx & 15;
                avv[p] = *reinterpret_cast<const us8*>(
                    &db[(size_t)(b * DD + (k0 + 32) + kr) * 2048 + l0 + dc * 8]);
            }
#pragma unroll
            for (int p = 0; p < 2; ++p) {
                int idx = tid + 256 * p;
                int row = idx >> 2, kq = idx & 3;
                bvv[p] = *reinterpret_cast<const us8*>(
                    &WtO[(size_t)(c0 + row) * DD + (k0 + 32) + kq * 8]);
            }
        }
        __syncthreads();
        f16x8 af[4], bfr[4];
#pragma unroll
        for (int m = 0; m < 4; ++m) {
            int l = wr * 64 + m * 16 + rl;
            us8 t;
#pragma unroll
            for (int j = 0; j < 8; ++j) t[j] = Asm[g * 8 + j][l];
            af[m] = __builtin_bit_cast(f16x8, t);
        }
#pragma unroll
        for (int n = 0; n < 4; ++n)
            bfr[n] = *reinterpret_cast<const f16x8*>(&Bsm[wc * 64 + n * 16 + rl][g * 8]);
#pragma unroll
        for (int m = 0; m < 4; ++m)
#pragma unroll
            for (int n = 0; n < 4; ++n)
                acc[m][n] = __builtin_amdgcn_mfma_f32_16x16x32_f16(af[m], bfr[n], acc[m][n], 0, 0, 0);
    }

#pragma unroll
    for (int m = 0; m < 4; ++m) {
#pragma unroll
        for (int n = 0; n < 4; ++n) {
            int c = c0 + wc * 64 + n * 16 + rl;
            float bvv2 = bias[c];
            int rbase = r0 + wr * 64 + m * 16 + g * 4;
#pragma unroll
            for (int j = 0; j < 4; ++j)
                out[(size_t)(rbase + j) * DD + c] = acc[m][n][j] + bvv2;
        }
    }
}

extern "C" void kernel_launch(void* const* d_in, const int* in_sizes, int n_in,
                              void* d_out, int out_size, void* d_ws, size_t ws_size,
                              hipStream_t stream) {
    const float* q = (const float*)d_in[0];
    const float* k = (const float*)d_in[1];
    const float* Wq = (const float*)d_in[3];
    const float* bq = (const float*)d_in[4];
    const float* Wk = (const float*)d_in[5];
    const float* bk = (const float*)d_in[6];
    const float* Wo = (const float*)d_in[9];
    const float* bo = (const float*)d_in[10];
    float* out = (float*)d_out;

    unsigned short* qt = (unsigned short*)d_ws;
    unsigned short* kt = qt + (size_t)BB * HH * DEPTH * LL;
    unsigned short* Tq = kt + (size_t)BB * HH * DEPTH * LL;
    unsigned short* Tk = Tq + (size_t)DD * DD;
    unsigned short* To = Tk + (size_t)DD * DD;

    dim3 blk(256);
    wt_convert<<<dim3(8, 8, 3), blk, 0, stream>>>(Wq, Wk, Wo, Tq, Tk, To);
    proj_gemm2<<<dim3(4, 128, 2), blk, 0, stream>>>(q, k, Tq, Tk, bq, bk, qt, kt);
    corr_fft_v9<<<dim3(BB * HH * DEPTH), blk, 0, stream>>>(qt, kt);
    out_gemm_mfma<<<dim3(4, 128), blk, 0, stream>>>(kt, To, bo, out);
}